// Round 7
// baseline (905.647 us; speedup 1.0000x reference)
//
#include <hip/hip_runtime.h>

#define NC 200000
#define NM 50000
#define NE 1000000
#define DF 64   // feature dim (D == H == 64)

#define SCAN_B 512
#define SCAN_T 256

#define BSHIFT 7
#define BMASK 127
#define NBC ((NC + BMASK) >> BSHIFT)   // 1563 buckets for customer dst
#define NBM ((NM + BMASK) >> BSHIFT)   // 391 buckets for merchant dst

typedef __attribute__((ext_vector_type(8))) short bf16x8;
typedef __attribute__((ext_vector_type(4))) float f32x4;
typedef __attribute__((ext_vector_type(4))) unsigned short u16x4;

// ---------------- histogram: bins[dst[e]] += 1 (int atomics) ----------------
__global__ __launch_bounds__(256) void hist_k(const int* __restrict__ dst,
                                              int* __restrict__ bins, int n_edges) {
    int tid = blockIdx.x * blockDim.x + threadIdx.x;
    for (int e = tid; e < n_edges; e += gridDim.x * blockDim.x) {
        atomicAdd(&bins[dst[e]], 1);
    }
}

// ---------------- 3-phase device-wide exclusive scan ----------------
__global__ __launch_bounds__(SCAN_T) void scan_part_k(const int* __restrict__ bins,
                                                      int* __restrict__ partials, int n) {
    __shared__ int red[SCAN_T];
    const int ch = (n + SCAN_B * SCAN_T - 1) / (SCAN_B * SCAN_T);
    const int t = threadIdx.x;
    const long base = ((long)blockIdx.x * SCAN_T + t) * ch;
    int s = 0;
    for (int i = 0; i < ch; ++i) {
        long idx = base + i;
        if (idx < n) s += bins[idx];
    }
    red[t] = s;
    __syncthreads();
    for (int off = SCAN_T / 2; off > 0; off >>= 1) {
        if (t < off) red[t] += red[t + off];
        __syncthreads();
    }
    if (t == 0) partials[blockIdx.x] = red[0];
}

__global__ __launch_bounds__(SCAN_B) void scan_mid_k(const int* __restrict__ partials,
                                                     int* __restrict__ boff,
                                                     int* __restrict__ start, int n) {
    __shared__ int s[SCAN_B];
    const int t = threadIdx.x;
    s[t] = partials[t];
    __syncthreads();
    for (int off = 1; off < SCAN_B; off <<= 1) {
        int v = 0;
        if (t >= off) v = s[t - off];
        __syncthreads();
        if (t >= off) s[t] += v;
        __syncthreads();
    }
    boff[t] = (t == 0) ? 0 : s[t - 1];
    if (t == SCAN_B - 1) start[n] = s[t];
}

__global__ __launch_bounds__(SCAN_T) void scan_fin_k(const int* __restrict__ bins,
                                                     const int* __restrict__ boff,
                                                     int* __restrict__ start, int n) {
    __shared__ int red[SCAN_T];
    const int ch = (n + SCAN_B * SCAN_T - 1) / (SCAN_B * SCAN_T);
    const int t = threadIdx.x;
    const long base = ((long)blockIdx.x * SCAN_T + t) * ch;
    int s = 0;
    for (int i = 0; i < ch; ++i) {
        long idx = base + i;
        if (idx < n) s += bins[idx];
    }
    red[t] = s;
    __syncthreads();
    for (int off = 1; off < SCAN_T; off <<= 1) {
        int v = 0;
        if (t >= off) v = red[t - off];
        __syncthreads();
        if (t >= off) red[t] += v;
        __syncthreads();
    }
    int run = boff[blockIdx.x] + ((t == 0) ? 0 : red[t - 1]);
    for (int i = 0; i < ch; ++i) {
        long idx = base + i;
        if (idx < n) {
            start[idx] = run;
            run += bins[idx];
        }
    }
}

// ---------------- bucket place pass 1: scatter packed (src<<7)|dl into bucket windows ----
// bucket offsets are the fine prefix sampled at bucket boundaries: start[b<<7].
__global__ __launch_bounds__(256) void bp1_k(const int* __restrict__ src,
                                             const int* __restrict__ dst,
                                             const int* __restrict__ start,
                                             int* __restrict__ ccur,
                                             int* __restrict__ bkt, int n_edges) {
    int tid = blockIdx.x * blockDim.x + threadIdx.x;
    for (int e = tid; e < n_edges; e += gridDim.x * blockDim.x) {
        const int d = dst[e];
        const int b = d >> BSHIFT;
        const int pos = start[b << BSHIFT] + atomicAdd(&ccur[b], 1);
        bkt[pos] = (src[e] << BSHIFT) | (d & BMASK);
    }
}

// ---------------- bucket place pass 2: LDS-cursor counting sort within bucket ----------
__global__ __launch_bounds__(256) void bp2_k(const int* __restrict__ bkt,
                                             const int* __restrict__ start,
                                             int* __restrict__ srt, int n_nodes) {
    __shared__ int lcur[BMASK + 1];
    const int b = blockIdx.x;
    const int base = b << BSHIFT;
    if (threadIdx.x <= BMASK) lcur[threadIdx.x] = 0;
    __syncthreads();
    const int e0 = start[base];
    const int e1 = start[min(base + BMASK + 1, n_nodes)];
    for (int e = e0 + threadIdx.x; e < e1; e += 256) {
        const int p = bkt[e];
        const int dl = p & BMASK;
        const int pos = start[base + dl] + atomicAdd(&lcur[dl], 1);
        srt[pos] = p >> BSHIFT;
    }
}

// ---------------- round-to-nearest bf16 helpers ----------------
__device__ __forceinline__ short bf16rn(float x) {
    unsigned u = __builtin_bit_cast(unsigned, x);
    unsigned r = u + 0x7FFFu + ((u >> 16) & 1u);
    return (short)(r >> 16);
}
__device__ __forceinline__ float bf16f(short h) {
    unsigned u = ((unsigned)(unsigned short)h) << 16;
    return __builtin_bit_cast(float, u);
}
__device__ __forceinline__ void split8(const f32x4 u, const f32x4 v,
                                       bf16x8& hi, bf16x8& lo) {
#pragma unroll
    for (int b = 0; b < 4; ++b) {
        short h = bf16rn(u[b]);
        hi[b] = h;
        lo[b] = bf16rn(u[b] - bf16f(h));
    }
#pragma unroll
    for (int b = 0; b < 4; ++b) {
        short h = bf16rn(v[b]);
        hi[4 + b] = h;
        lo[4 + b] = bf16rn(v[b] - bf16f(h));
    }
}

// ---------------- presplit: fp32 features -> bf16 hi-plane (for gathers) ----------------
__global__ __launch_bounds__(256) void presplit_k(const float* __restrict__ x,
                                                  u16x4* __restrict__ xhi, int n4) {
    int i = blockIdx.x * blockDim.x + threadIdx.x;
    const int st = gridDim.x * blockDim.x;
    for (; i < n4; i += st) {
        const f32x4 v = ((const f32x4*)x)[i];
        u16x4 o;
#pragma unroll
        for (int b = 0; b < 4; ++b) o[b] = (unsigned short)bf16rn(v[b]);
        xhi[i] = o;
    }
}

// ---------------- aggregation from bf16 hi-plane: one wave per dst node ----------------
// 4 subgroups of 16 lanes; each subgroup handles every 4th edge; lane holds 4 features.
// 4 rows (512B) in flight per wave instruction.
__global__ __launch_bounds__(256) void agg16_k(const unsigned short* __restrict__ xhi,
                                               const int* __restrict__ start,
                                               const int* __restrict__ srt,
                                               float* __restrict__ aggmean, int n_nodes) {
    const int wid = (blockIdx.x * blockDim.x + threadIdx.x) >> 6;
    const int lane = threadIdx.x & 63;
    const int nwaves = (gridDim.x * blockDim.x) >> 6;
    const int g = lane >> 4;
    const int k4 = (lane & 15) * 4;
    for (int n = wid; n < n_nodes; n += nwaves) {
        const int s0 = start[n];
        const int s1 = start[n + 1];
        f32x4 acc = {0.f, 0.f, 0.f, 0.f};
        for (int e = s0 + g; e < s1; e += 4) {
            const int s = srt[e];
            const u16x4 v = *(const u16x4*)(xhi + (long)s * DF + k4);
            acc[0] += bf16f((short)v[0]);
            acc[1] += bf16f((short)v[1]);
            acc[2] += bf16f((short)v[2]);
            acc[3] += bf16f((short)v[3]);
        }
#pragma unroll
        for (int c = 0; c < 4; ++c) {
            acc[c] += __shfl_xor(acc[c], 16);
            acc[c] += __shfl_xor(acc[c], 32);
        }
        if (g == 0) {
            const float inv = 1.0f / fmaxf((float)(s1 - s0), 1.0f);
            f32x4 m;
            m[0] = acc[0] * inv; m[1] = acc[1] * inv;
            m[2] = acc[2] * inv; m[3] = acc[3] * inv;
            *(f32x4*)(aggmean + (long)n * DF + k4) = m;
        }
    }
}

#define MFMA(a, b, c) __builtin_amdgcn_mfma_f32_16x16x32_bf16((a), (b), (c), 0, 0, 0)

#define MFMA4(ah, al, bh, bl, acc)      \
    do {                                \
        acc = MFMA(ah, bh, acc);        \
        acc = MFMA(ah, bl, acc);        \
        acc = MFMA(al, bh, acc);        \
        acc = MFMA(al, bl, acc);        \
    } while (0)

#define LOAD_W(Wl, Wr, col, g, wlh, wll, wrh, wrl)          \
    do {                                                    \
        _Pragma("unroll")                                   \
        for (int q = 0; q < 2; ++q) {                       \
            f32x4 tl0, tl1, tr0, tr1;                       \
            _Pragma("unroll")                               \
            for (int b = 0; b < 4; ++b) {                   \
                int k = 32 * q + 8 * (g) + b;               \
                tl0[b] = (Wl)[k * DF + (col)];              \
                tr0[b] = (Wr)[k * DF + (col)];              \
                tl1[b] = (Wl)[(k + 4) * DF + (col)];        \
                tr1[b] = (Wr)[(k + 4) * DF + (col)];        \
            }                                               \
            split8(tl0, tl1, wlh[q], wll[q]);               \
            split8(tr0, tr1, wrh[q], wrl[q]);               \
        }                                                   \
    } while (0)

// ---------------- dense1 (MFMA): h = relu(mean @ Wl + x @ Wr + b) ----------------
// Alias-safe (hout may alias mean): mean tile staged through LDS with barriers.
// Optionally also emits the bf16 hi-plane of h (for the layer-2 gather).
__global__ __launch_bounds__(256) void dense1_mfma(const float* __restrict__ mean,
                                                   const float* __restrict__ xdst,
                                                   const float* __restrict__ Wl,
                                                   const float* __restrict__ Wr,
                                                   const float* __restrict__ bias,
                                                   float* __restrict__ hout,
                                                   unsigned short* __restrict__ h16,
                                                   int n_nodes) {
    __shared__ float sA[16][68];
    const int t = threadIdx.x;
    const int lane = t & 63;
    const int wv = t >> 6;
    const int col = wv * 16 + (lane & 15);
    const int g = lane >> 4;

    bf16x8 wlh[2], wll[2], wrh[2], wrl[2];
    LOAD_W(Wl, Wr, col, g, wlh, wll, wrh, wrl);
    const float bv = bias[col];

    const int srow = t >> 4;
    const int sc4 = (t & 15) * 4;
    const int nrt = n_nodes >> 4;

    for (int rt = blockIdx.x; rt < nrt; rt += gridDim.x) {
        *(f32x4*)&sA[srow][sc4] =
            *(const f32x4*)(mean + ((long)rt * 16 + srow) * DF + sc4);
        const float* xrow = xdst + ((long)rt * 16 + (lane & 15)) * DF + 8 * g;
        const f32x4 xu0 = *(const f32x4*)(xrow + 0);
        const f32x4 xv0 = *(const f32x4*)(xrow + 4);
        const f32x4 xu1 = *(const f32x4*)(xrow + 32);
        const f32x4 xv1 = *(const f32x4*)(xrow + 36);
        __syncthreads();

        const int ar = lane & 15;
        const f32x4 au0 = *(const f32x4*)&sA[ar][8 * g + 0];
        const f32x4 av0 = *(const f32x4*)&sA[ar][8 * g + 4];
        const f32x4 au1 = *(const f32x4*)&sA[ar][8 * g + 32];
        const f32x4 av1 = *(const f32x4*)&sA[ar][8 * g + 36];

        f32x4 acc = {0.f, 0.f, 0.f, 0.f};
        bf16x8 h, l;
        split8(au0, av0, h, l);
        MFMA4(h, l, wlh[0], wll[0], acc);
        split8(au1, av1, h, l);
        MFMA4(h, l, wlh[1], wll[1], acc);
        split8(xu0, xv0, h, l);
        MFMA4(h, l, wrh[0], wrl[0], acc);
        split8(xu1, xv1, h, l);
        MFMA4(h, l, wrh[1], wrl[1], acc);

#pragma unroll
        for (int r = 0; r < 4; ++r) {
            const float v = fmaxf(acc[r] + bv, 0.0f);
            const long row = (long)rt * 16 + 4 * g + r;
            hout[row * DF + col] = v;
            if (h16) h16[row * DF + col] = (unsigned short)bf16rn(v);
        }
        __syncthreads();
    }
}

// ---------------- dense2 (MFMA) + fused final linear ----------------
__global__ __launch_bounds__(256) void dense2_mfma(const float* __restrict__ mean,
                                                   const float* __restrict__ hc,
                                                   const float* __restrict__ Wl,
                                                   const float* __restrict__ Wr,
                                                   const float* __restrict__ bias,
                                                   const float* __restrict__ Wlin,
                                                   const float* __restrict__ blin,
                                                   float* __restrict__ out, int n_nodes) {
    const int wglobal = (blockIdx.x * blockDim.x + threadIdx.x) >> 6;
    const int lane = threadIdx.x & 63;
    const int nwaves = (gridDim.x * blockDim.x) >> 6;
    const int ct = wglobal & 3;
    const int col = ct * 16 + (lane & 15);
    const int g = lane >> 4;

    bf16x8 wlh[2], wll[2], wrh[2], wrl[2];
    LOAD_W(Wl, Wr, col, g, wlh, wll, wrh, wrl);
    const float bv = bias[col];
    const float wl0 = Wlin[col * 2 + 0];
    const float wl1 = Wlin[col * 2 + 1];
    const float bl0 = (ct == 0) ? blin[0] : 0.0f;
    const float bl1 = (ct == 0) ? blin[1] : 0.0f;

    const int nrt = n_nodes >> 4;
    for (int rt = wglobal >> 2; rt < nrt; rt += nwaves >> 2) {
        const float* arow = mean + ((long)rt * 16 + (lane & 15)) * DF + 8 * g;
        const float* hrow = hc + ((long)rt * 16 + (lane & 15)) * DF + 8 * g;
        f32x4 acc = {0.f, 0.f, 0.f, 0.f};
        bf16x8 h, l;
        split8(*(const f32x4*)(arow + 0), *(const f32x4*)(arow + 4), h, l);
        MFMA4(h, l, wlh[0], wll[0], acc);
        split8(*(const f32x4*)(arow + 32), *(const f32x4*)(arow + 36), h, l);
        MFMA4(h, l, wlh[1], wll[1], acc);
        split8(*(const f32x4*)(hrow + 0), *(const f32x4*)(hrow + 4), h, l);
        MFMA4(h, l, wrh[0], wrl[0], acc);
        split8(*(const f32x4*)(hrow + 32), *(const f32x4*)(hrow + 36), h, l);
        MFMA4(h, l, wrh[1], wrl[1], acc);

#pragma unroll
        for (int r = 0; r < 4; ++r) {
            const float h2 = acc[r] + bv;
            float p0 = h2 * wl0;
            float p1 = h2 * wl1;
#pragma unroll
            for (int m = 1; m < 16; m <<= 1) {
                p0 += __shfl_xor(p0, m);
                p1 += __shfl_xor(p1, m);
            }
            if ((lane & 15) == 0) {
                const long node = (long)rt * 16 + 4 * g + r;
                atomicAdd(&out[node * 2 + 0], p0 + bl0);
                atomicAdd(&out[node * 2 + 1], p1 + bl1);
            }
        }
    }
}

extern "C" void kernel_launch(void* const* d_in, const int* in_sizes, int n_in,
                              void* d_out, int out_size, void* d_ws, size_t ws_size,
                              hipStream_t stream) {
    const float* x_c = (const float*)d_in[0];
    const float* x_m = (const float*)d_in[1];
    const int* cm_src = (const int*)d_in[2];
    const int* cm_dst = (const int*)d_in[3];
    const int* mc_src = (const int*)d_in[4];
    const int* mc_dst = (const int*)d_in[5];
    const float* Wl1_cm = (const float*)d_in[6];
    const float* Wr1_cm = (const float*)d_in[7];
    const float* b1_cm = (const float*)d_in[8];
    const float* Wl1_mc = (const float*)d_in[9];
    const float* Wr1_mc = (const float*)d_in[10];
    const float* b1_mc = (const float*)d_in[11];
    // layer-2 cm weights (d_in[12..14]) are dead: h2_m is unused in the reference
    const float* Wl2_mc = (const float*)d_in[15];
    const float* Wr2_mc = (const float*)d_in[16];
    const float* b2_mc = (const float*)d_in[17];
    const float* W_lin = (const float*)d_in[18];
    const float* b_lin = (const float*)d_in[19];
    float* out = (float*)d_out;

    // ---- workspace layout (~132 MB) ----
    float* ws = (float*)d_ws;
    float* agg_m = ws;                              // NM*64 f; h_m aliases (in-place, safe)
    float* agg_c = agg_m + (long)NM * DF;           // NC*64 f; bkt_cm/bkt_mc alias its head
    float* h_c = agg_c + (long)NC * DF;             // NC*64 f; xc16/xm16 alias (consumed earlier)
    unsigned short* hm16 = (unsigned short*)(h_c + (long)NC * DF);  // NM*64 ushort
    int* ip = (int*)(hm16 + (long)NM * DF);

    int* binsM = ip;                  // NM
    int* binsC = binsM + NM;          // NC
    int* ccurM = binsC + NC;          // NBM
    int* ccurC = ccurM + NBM;         // NBC
    int* startM = ccurC + NBC;        // NM+1
    int* startC = startM + (NM + 1);  // NC+1
    int* srt_cm = startC + (NC + 1);  // NE
    int* srt_mc = srt_cm + NE;        // NE
    int* partM = srt_mc + NE;
    int* boffM = partM + SCAN_B;
    int* partC = boffM + SCAN_B;
    int* boffC = partC + SCAN_B;

    // aliased scratch (consumed before their hosts are written):
    int* bkt_cm = (int*)agg_c;                      // NE ints, read by bp2 before agg16 writes agg_c
    int* bkt_mc = bkt_cm + NE;                      // NE ints
    unsigned short* xc16 = (unsigned short*)h_c;    // NC*64 ushort, read before dense1 writes h_c
    unsigned short* xm16 = xc16 + (long)NC * DF;    // NM*64 ushort

    // zero bins + bucket cursors (contiguous) and the atomic output
    hipMemsetAsync(binsM, 0, (size_t)(NM + NC + NBM + NBC) * sizeof(int), stream);
    hipMemsetAsync(out, 0, (size_t)out_size * sizeof(float), stream);

    // fine histograms + prefix (start[] doubles as bucket offsets: cstart[b] = start[b<<7])
    hist_k<<<2048, 256, 0, stream>>>(cm_dst, binsM, NE);
    hist_k<<<2048, 256, 0, stream>>>(mc_dst, binsC, NE);

    scan_part_k<<<SCAN_B, SCAN_T, 0, stream>>>(binsM, partM, NM);
    scan_mid_k<<<1, SCAN_B, 0, stream>>>(partM, boffM, startM, NM);
    scan_fin_k<<<SCAN_B, SCAN_T, 0, stream>>>(binsM, boffM, startM, NM);

    scan_part_k<<<SCAN_B, SCAN_T, 0, stream>>>(binsC, partC, NC);
    scan_mid_k<<<1, SCAN_B, 0, stream>>>(partC, boffC, startC, NC);
    scan_fin_k<<<SCAN_B, SCAN_T, 0, stream>>>(binsC, boffC, startC, NC);

    // two-phase bucket sort by destination (replaces random-scatter place_k)
    bp1_k<<<2048, 256, 0, stream>>>(cm_src, cm_dst, startM, ccurM, bkt_cm, NE);
    bp1_k<<<2048, 256, 0, stream>>>(mc_src, mc_dst, startC, ccurC, bkt_mc, NE);
    bp2_k<<<NBM, 256, 0, stream>>>(bkt_cm, startM, srt_cm, NM);
    bp2_k<<<NBC, 256, 0, stream>>>(bkt_mc, startC, srt_mc, NC);

    // bf16 hi-planes for the gathers
    presplit_k<<<2048, 256, 0, stream>>>(x_c, (u16x4*)xc16, NC * (DF / 4));
    presplit_k<<<2048, 256, 0, stream>>>(x_m, (u16x4*)xm16, NM * (DF / 4));

    // layer 1: aggregate means from bf16 planes, then MFMA dense
    agg16_k<<<(NM + 3) / 4, 256, 0, stream>>>(xc16, startM, srt_cm, agg_m, NM);
    agg16_k<<<(NC + 3) / 4, 256, 0, stream>>>(xm16, startC, srt_mc, agg_c, NC);
    dense1_mfma<<<1024, 256, 0, stream>>>(agg_m, x_m, Wl1_cm, Wr1_cm, b1_cm,
                                          agg_m /*h_m alias*/, hm16, NM);
    dense1_mfma<<<2048, 256, 0, stream>>>(agg_c, x_c, Wl1_mc, Wr1_mc, b1_mc,
                                          h_c, (unsigned short*)nullptr, NC);

    // layer 2: re-aggregate h_m (bf16 plane) over mc edges, dense2 + final linear
    agg16_k<<<(NC + 3) / 4, 256, 0, stream>>>(hm16, startC, srt_mc, agg_c, NC);
    dense2_mfma<<<2048, 256, 0, stream>>>(agg_c, h_c, Wl2_mc, Wr2_mc, b2_mc,
                                          W_lin, b_lin, out, NC);
}

// Round 8
// 500.307 us; speedup vs baseline: 1.8102x; 1.8102x over previous
//
#include <hip/hip_runtime.h>

#define NC 200000
#define NM 50000
#define NE 1000000
#define DF 64   // feature dim (D == H == 64)

#define SCAN_B 512
#define SCAN_T 256

typedef __attribute__((ext_vector_type(8))) short bf16x8;
typedef __attribute__((ext_vector_type(4))) float f32x4;
typedef __attribute__((ext_vector_type(4))) unsigned short u16x4;

// ---------------- histogram: bins[dst[e]] += 1 (int atomics) ----------------
__global__ __launch_bounds__(256) void hist_k(const int* __restrict__ dst,
                                              int* __restrict__ bins, int n_edges) {
    int tid = blockIdx.x * blockDim.x + threadIdx.x;
    for (int e = tid; e < n_edges; e += gridDim.x * blockDim.x) {
        atomicAdd(&bins[dst[e]], 1);
    }
}

// ---------------- 3-phase device-wide exclusive scan ----------------
__global__ __launch_bounds__(SCAN_T) void scan_part_k(const int* __restrict__ bins,
                                                      int* __restrict__ partials, int n) {
    __shared__ int red[SCAN_T];
    const int ch = (n + SCAN_B * SCAN_T - 1) / (SCAN_B * SCAN_T);
    const int t = threadIdx.x;
    const long base = ((long)blockIdx.x * SCAN_T + t) * ch;
    int s = 0;
    for (int i = 0; i < ch; ++i) {
        long idx = base + i;
        if (idx < n) s += bins[idx];
    }
    red[t] = s;
    __syncthreads();
    for (int off = SCAN_T / 2; off > 0; off >>= 1) {
        if (t < off) red[t] += red[t + off];
        __syncthreads();
    }
    if (t == 0) partials[blockIdx.x] = red[0];
}

__global__ __launch_bounds__(SCAN_B) void scan_mid_k(const int* __restrict__ partials,
                                                     int* __restrict__ boff,
                                                     int* __restrict__ start, int n) {
    __shared__ int s[SCAN_B];
    const int t = threadIdx.x;
    s[t] = partials[t];
    __syncthreads();
    for (int off = 1; off < SCAN_B; off <<= 1) {
        int v = 0;
        if (t >= off) v = s[t - off];
        __syncthreads();
        if (t >= off) s[t] += v;
        __syncthreads();
    }
    boff[t] = (t == 0) ? 0 : s[t - 1];
    if (t == SCAN_B - 1) start[n] = s[t];
}

__global__ __launch_bounds__(SCAN_T) void scan_fin_k(const int* __restrict__ bins,
                                                     const int* __restrict__ boff,
                                                     int* __restrict__ start, int n) {
    __shared__ int red[SCAN_T];
    const int ch = (n + SCAN_B * SCAN_T - 1) / (SCAN_B * SCAN_T);
    const int t = threadIdx.x;
    const long base = ((long)blockIdx.x * SCAN_T + t) * ch;
    int s = 0;
    for (int i = 0; i < ch; ++i) {
        long idx = base + i;
        if (idx < n) s += bins[idx];
    }
    red[t] = s;
    __syncthreads();
    for (int off = 1; off < SCAN_T; off <<= 1) {
        int v = 0;
        if (t >= off) v = red[t - off];
        __syncthreads();
        if (t >= off) red[t] += v;
        __syncthreads();
    }
    int run = boff[blockIdx.x] + ((t == 0) ? 0 : red[t - 1]);
    for (int i = 0; i < ch; ++i) {
        long idx = base + i;
        if (idx < n) {
            start[idx] = run;
            run += bins[idx];
        }
    }
}

// ---------------- placement: sorted_src[start[d] + cur[d]++] = src[e] ----------------
// fine per-dst cursors: thousands of cache lines -> no atomic line contention
__global__ __launch_bounds__(256) void place_k(const int* __restrict__ src,
                                               const int* __restrict__ dst,
                                               const int* __restrict__ start,
                                               int* __restrict__ cur,
                                               int* __restrict__ sorted_src, int n_edges) {
    int tid = blockIdx.x * blockDim.x + threadIdx.x;
    for (int e = tid; e < n_edges; e += gridDim.x * blockDim.x) {
        int d = dst[e];
        int pos = start[d] + atomicAdd(&cur[d], 1);
        sorted_src[pos] = src[e];
    }
}

// ---------------- round-to-nearest bf16 helpers ----------------
__device__ __forceinline__ short bf16rn(float x) {
    unsigned u = __builtin_bit_cast(unsigned, x);
    unsigned r = u + 0x7FFFu + ((u >> 16) & 1u);
    return (short)(r >> 16);
}
__device__ __forceinline__ float bf16f(short h) {
    unsigned u = ((unsigned)(unsigned short)h) << 16;
    return __builtin_bit_cast(float, u);
}
__device__ __forceinline__ void split8(const f32x4 u, const f32x4 v,
                                       bf16x8& hi, bf16x8& lo) {
#pragma unroll
    for (int b = 0; b < 4; ++b) {
        short h = bf16rn(u[b]);
        hi[b] = h;
        lo[b] = bf16rn(u[b] - bf16f(h));
    }
#pragma unroll
    for (int b = 0; b < 4; ++b) {
        short h = bf16rn(v[b]);
        hi[4 + b] = h;
        lo[4 + b] = bf16rn(v[b] - bf16f(h));
    }
}

// ---------------- presplit: fp32 features -> bf16 hi-plane (for gathers) ----------------
__global__ __launch_bounds__(256) void presplit_k(const float* __restrict__ x,
                                                  u16x4* __restrict__ xhi, int n4) {
    int i = blockIdx.x * blockDim.x + threadIdx.x;
    const int st = gridDim.x * blockDim.x;
    for (; i < n4; i += st) {
        const f32x4 v = ((const f32x4*)x)[i];
        u16x4 o;
#pragma unroll
        for (int b = 0; b < 4; ++b) o[b] = (unsigned short)bf16rn(v[b]);
        xhi[i] = o;
    }
}

// ---------------- aggregation from bf16 hi-plane: one wave per dst node ----------------
// 4 subgroups of 16 lanes; each subgroup handles every 4th edge; lane holds 4 features.
// 4 rows (512B) in flight per wave instruction.
__global__ __launch_bounds__(256) void agg16_k(const unsigned short* __restrict__ xhi,
                                               const int* __restrict__ start,
                                               const int* __restrict__ srt,
                                               float* __restrict__ aggmean, int n_nodes) {
    const int wid = (blockIdx.x * blockDim.x + threadIdx.x) >> 6;
    const int lane = threadIdx.x & 63;
    const int nwaves = (gridDim.x * blockDim.x) >> 6;
    const int g = lane >> 4;
    const int k4 = (lane & 15) * 4;
    for (int n = wid; n < n_nodes; n += nwaves) {
        const int s0 = start[n];
        const int s1 = start[n + 1];
        f32x4 acc = {0.f, 0.f, 0.f, 0.f};
        for (int e = s0 + g; e < s1; e += 4) {
            const int s = srt[e];
            const u16x4 v = *(const u16x4*)(xhi + (long)s * DF + k4);
            acc[0] += bf16f((short)v[0]);
            acc[1] += bf16f((short)v[1]);
            acc[2] += bf16f((short)v[2]);
            acc[3] += bf16f((short)v[3]);
        }
#pragma unroll
        for (int c = 0; c < 4; ++c) {
            acc[c] += __shfl_xor(acc[c], 16);
            acc[c] += __shfl_xor(acc[c], 32);
        }
        if (g == 0) {
            const float inv = 1.0f / fmaxf((float)(s1 - s0), 1.0f);
            f32x4 m;
            m[0] = acc[0] * inv; m[1] = acc[1] * inv;
            m[2] = acc[2] * inv; m[3] = acc[3] * inv;
            *(f32x4*)(aggmean + (long)n * DF + k4) = m;
        }
    }
}

#define MFMA(a, b, c) __builtin_amdgcn_mfma_f32_16x16x32_bf16((a), (b), (c), 0, 0, 0)

#define MFMA4(ah, al, bh, bl, acc)      \
    do {                                \
        acc = MFMA(ah, bh, acc);        \
        acc = MFMA(ah, bl, acc);        \
        acc = MFMA(al, bh, acc);        \
        acc = MFMA(al, bl, acc);        \
    } while (0)

#define LOAD_W(Wl, Wr, col, g, wlh, wll, wrh, wrl)          \
    do {                                                    \
        _Pragma("unroll")                                   \
        for (int q = 0; q < 2; ++q) {                       \
            f32x4 tl0, tl1, tr0, tr1;                       \
            _Pragma("unroll")                               \
            for (int b = 0; b < 4; ++b) {                   \
                int k = 32 * q + 8 * (g) + b;               \
                tl0[b] = (Wl)[k * DF + (col)];              \
                tr0[b] = (Wr)[k * DF + (col)];              \
                tl1[b] = (Wl)[(k + 4) * DF + (col)];        \
                tr1[b] = (Wr)[(k + 4) * DF + (col)];        \
            }                                               \
            split8(tl0, tl1, wlh[q], wll[q]);               \
            split8(tr0, tr1, wrh[q], wrl[q]);               \
        }                                                   \
    } while (0)

// ---------------- dense1 (MFMA): h = relu(mean @ Wl + x @ Wr + b) ----------------
// Alias-safe (hout may alias mean): mean tile staged through LDS with barriers.
// Optionally also emits the bf16 hi-plane of h (for the layer-2 gather).
__global__ __launch_bounds__(256) void dense1_mfma(const float* __restrict__ mean,
                                                   const float* __restrict__ xdst,
                                                   const float* __restrict__ Wl,
                                                   const float* __restrict__ Wr,
                                                   const float* __restrict__ bias,
                                                   float* __restrict__ hout,
                                                   unsigned short* __restrict__ h16,
                                                   int n_nodes) {
    __shared__ float sA[16][68];
    const int t = threadIdx.x;
    const int lane = t & 63;
    const int wv = t >> 6;
    const int col = wv * 16 + (lane & 15);
    const int g = lane >> 4;

    bf16x8 wlh[2], wll[2], wrh[2], wrl[2];
    LOAD_W(Wl, Wr, col, g, wlh, wll, wrh, wrl);
    const float bv = bias[col];

    const int srow = t >> 4;
    const int sc4 = (t & 15) * 4;
    const int nrt = n_nodes >> 4;

    for (int rt = blockIdx.x; rt < nrt; rt += gridDim.x) {
        *(f32x4*)&sA[srow][sc4] =
            *(const f32x4*)(mean + ((long)rt * 16 + srow) * DF + sc4);
        const float* xrow = xdst + ((long)rt * 16 + (lane & 15)) * DF + 8 * g;
        const f32x4 xu0 = *(const f32x4*)(xrow + 0);
        const f32x4 xv0 = *(const f32x4*)(xrow + 4);
        const f32x4 xu1 = *(const f32x4*)(xrow + 32);
        const f32x4 xv1 = *(const f32x4*)(xrow + 36);
        __syncthreads();

        const int ar = lane & 15;
        const f32x4 au0 = *(const f32x4*)&sA[ar][8 * g + 0];
        const f32x4 av0 = *(const f32x4*)&sA[ar][8 * g + 4];
        const f32x4 au1 = *(const f32x4*)&sA[ar][8 * g + 32];
        const f32x4 av1 = *(const f32x4*)&sA[ar][8 * g + 36];

        f32x4 acc = {0.f, 0.f, 0.f, 0.f};
        bf16x8 h, l;
        split8(au0, av0, h, l);
        MFMA4(h, l, wlh[0], wll[0], acc);
        split8(au1, av1, h, l);
        MFMA4(h, l, wlh[1], wll[1], acc);
        split8(xu0, xv0, h, l);
        MFMA4(h, l, wrh[0], wrl[0], acc);
        split8(xu1, xv1, h, l);
        MFMA4(h, l, wrh[1], wrl[1], acc);

#pragma unroll
        for (int r = 0; r < 4; ++r) {
            const float v = fmaxf(acc[r] + bv, 0.0f);
            const long row = (long)rt * 16 + 4 * g + r;
            hout[row * DF + col] = v;
            if (h16) h16[row * DF + col] = (unsigned short)bf16rn(v);
        }
        __syncthreads();
    }
}

// ---------------- dense2 (MFMA) + fused final linear ----------------
__global__ __launch_bounds__(256) void dense2_mfma(const float* __restrict__ mean,
                                                   const float* __restrict__ hc,
                                                   const float* __restrict__ Wl,
                                                   const float* __restrict__ Wr,
                                                   const float* __restrict__ bias,
                                                   const float* __restrict__ Wlin,
                                                   const float* __restrict__ blin,
                                                   float* __restrict__ out, int n_nodes) {
    const int wglobal = (blockIdx.x * blockDim.x + threadIdx.x) >> 6;
    const int lane = threadIdx.x & 63;
    const int nwaves = (gridDim.x * blockDim.x) >> 6;
    const int ct = wglobal & 3;
    const int col = ct * 16 + (lane & 15);
    const int g = lane >> 4;

    bf16x8 wlh[2], wll[2], wrh[2], wrl[2];
    LOAD_W(Wl, Wr, col, g, wlh, wll, wrh, wrl);
    const float bv = bias[col];
    const float wl0 = Wlin[col * 2 + 0];
    const float wl1 = Wlin[col * 2 + 1];
    const float bl0 = (ct == 0) ? blin[0] : 0.0f;
    const float bl1 = (ct == 0) ? blin[1] : 0.0f;

    const int nrt = n_nodes >> 4;
    for (int rt = wglobal >> 2; rt < nrt; rt += nwaves >> 2) {
        const float* arow = mean + ((long)rt * 16 + (lane & 15)) * DF + 8 * g;
        const float* hrow = hc + ((long)rt * 16 + (lane & 15)) * DF + 8 * g;
        f32x4 acc = {0.f, 0.f, 0.f, 0.f};
        bf16x8 h, l;
        split8(*(const f32x4*)(arow + 0), *(const f32x4*)(arow + 4), h, l);
        MFMA4(h, l, wlh[0], wll[0], acc);
        split8(*(const f32x4*)(arow + 32), *(const f32x4*)(arow + 36), h, l);
        MFMA4(h, l, wlh[1], wll[1], acc);
        split8(*(const f32x4*)(hrow + 0), *(const f32x4*)(hrow + 4), h, l);
        MFMA4(h, l, wrh[0], wrl[0], acc);
        split8(*(const f32x4*)(hrow + 32), *(const f32x4*)(hrow + 36), h, l);
        MFMA4(h, l, wrh[1], wrl[1], acc);

#pragma unroll
        for (int r = 0; r < 4; ++r) {
            const float h2 = acc[r] + bv;
            float p0 = h2 * wl0;
            float p1 = h2 * wl1;
#pragma unroll
            for (int m = 1; m < 16; m <<= 1) {
                p0 += __shfl_xor(p0, m);
                p1 += __shfl_xor(p1, m);
            }
            if ((lane & 15) == 0) {
                const long node = (long)rt * 16 + 4 * g + r;
                atomicAdd(&out[node * 2 + 0], p0 + bl0);
                atomicAdd(&out[node * 2 + 1], p1 + bl1);
            }
        }
    }
}

extern "C" void kernel_launch(void* const* d_in, const int* in_sizes, int n_in,
                              void* d_out, int out_size, void* d_ws, size_t ws_size,
                              hipStream_t stream) {
    const float* x_c = (const float*)d_in[0];
    const float* x_m = (const float*)d_in[1];
    const int* cm_src = (const int*)d_in[2];
    const int* cm_dst = (const int*)d_in[3];
    const int* mc_src = (const int*)d_in[4];
    const int* mc_dst = (const int*)d_in[5];
    const float* Wl1_cm = (const float*)d_in[6];
    const float* Wr1_cm = (const float*)d_in[7];
    const float* b1_cm = (const float*)d_in[8];
    const float* Wl1_mc = (const float*)d_in[9];
    const float* Wr1_mc = (const float*)d_in[10];
    const float* b1_mc = (const float*)d_in[11];
    // layer-2 cm weights (d_in[12..14]) are dead: h2_m is unused in the reference
    const float* Wl2_mc = (const float*)d_in[15];
    const float* Wr2_mc = (const float*)d_in[16];
    const float* b2_mc = (const float*)d_in[17];
    const float* W_lin = (const float*)d_in[18];
    const float* b_lin = (const float*)d_in[19];
    float* out = (float*)d_out;

    // ---- workspace layout ----
    float* ws = (float*)d_ws;
    float* agg_m = ws;                              // NM*64 f; h_m aliases (in-place, safe)
    float* agg_c = agg_m + (long)NM * DF;           // NC*64 f
    float* h_c = agg_c + (long)NC * DF;             // NC*64 f; xc16/xm16 alias (consumed earlier)
    unsigned short* hm16 = (unsigned short*)(h_c + (long)NC * DF);  // NM*64 ushort
    int* ip = (int*)(hm16 + (long)NM * DF);

    int* binsM = ip;                  // NM   (zeroed)
    int* binsC = binsM + NM;          // NC   (zeroed)
    int* curM = binsC + NC;           // NM   (zeroed)
    int* curC = curM + NM;            // NC   (zeroed)
    int* startM = curC + NC;          // NM+1
    int* startC = startM + (NM + 1);  // NC+1
    int* srt_cm = startC + (NC + 1);  // NE
    int* srt_mc = srt_cm + NE;        // NE
    int* partM = srt_mc + NE;
    int* boffM = partM + SCAN_B;
    int* partC = boffM + SCAN_B;
    int* boffC = partC + SCAN_B;

    // aliased scratch (consumed before their hosts are written):
    unsigned short* xc16 = (unsigned short*)h_c;    // NC*64 ushort, read before dense1 writes h_c
    unsigned short* xm16 = xc16 + (long)NC * DF;    // NM*64 ushort

    // zero bins + cursors (contiguous) and the atomic output
    hipMemsetAsync(binsM, 0, (size_t)(2 * (NM + NC)) * sizeof(int), stream);
    hipMemsetAsync(out, 0, (size_t)out_size * sizeof(float), stream);

    // fine histograms + prefix
    hist_k<<<2048, 256, 0, stream>>>(cm_dst, binsM, NE);
    hist_k<<<2048, 256, 0, stream>>>(mc_dst, binsC, NE);

    scan_part_k<<<SCAN_B, SCAN_T, 0, stream>>>(binsM, partM, NM);
    scan_mid_k<<<1, SCAN_B, 0, stream>>>(partM, boffM, startM, NM);
    scan_fin_k<<<SCAN_B, SCAN_T, 0, stream>>>(binsM, boffM, startM, NM);

    scan_part_k<<<SCAN_B, SCAN_T, 0, stream>>>(binsC, partC, NC);
    scan_mid_k<<<1, SCAN_B, 0, stream>>>(partC, boffC, startC, NC);
    scan_fin_k<<<SCAN_B, SCAN_T, 0, stream>>>(binsC, boffC, startC, NC);

    // placement with fine per-dst cursors
    place_k<<<2048, 256, 0, stream>>>(cm_src, cm_dst, startM, curM, srt_cm, NE);
    place_k<<<2048, 256, 0, stream>>>(mc_src, mc_dst, startC, curC, srt_mc, NE);

    // bf16 hi-planes for the gathers
    presplit_k<<<2048, 256, 0, stream>>>(x_c, (u16x4*)xc16, NC * (DF / 4));
    presplit_k<<<2048, 256, 0, stream>>>(x_m, (u16x4*)xm16, NM * (DF / 4));

    // layer 1: aggregate means from bf16 planes, then MFMA dense
    agg16_k<<<(NM + 3) / 4, 256, 0, stream>>>(xc16, startM, srt_cm, agg_m, NM);
    agg16_k<<<(NC + 3) / 4, 256, 0, stream>>>(xm16, startC, srt_mc, agg_c, NC);
    dense1_mfma<<<1024, 256, 0, stream>>>(agg_m, x_m, Wl1_cm, Wr1_cm, b1_cm,
                                          agg_m /*h_m alias*/, hm16, NM);
    dense1_mfma<<<2048, 256, 0, stream>>>(agg_c, x_c, Wl1_mc, Wr1_mc, b1_mc,
                                          h_c, (unsigned short*)nullptr, NC);

    // layer 2: re-aggregate h_m (bf16 plane) over mc edges, dense2 + final linear
    agg16_k<<<(NC + 3) / 4, 256, 0, stream>>>(hm16, startC, srt_mc, agg_c, NC);
    dense2_mfma<<<2048, 256, 0, stream>>>(agg_c, h_c, Wl2_mc, Wr2_mc, b2_mc,
                                          W_lin, b_lin, out, NC);
}

// Round 9
// 497.799 us; speedup vs baseline: 1.8193x; 1.0050x over previous
//
#include <hip/hip_runtime.h>

#define NC 200000
#define NM 50000
#define NE 1000000
#define DF 64   // feature dim (D == H == 64)

#define SCAN_B 512
#define SCAN_T 256

typedef __attribute__((ext_vector_type(8))) short bf16x8;
typedef __attribute__((ext_vector_type(4))) float f32x4;
typedef __attribute__((ext_vector_type(4))) unsigned short u16x4;

// ---------------- histogram: bins[dst[e]] += 1 (int atomics) ----------------
__global__ __launch_bounds__(256) void hist_k(const int* __restrict__ dst,
                                              int* __restrict__ bins, int n_edges) {
    int tid = blockIdx.x * blockDim.x + threadIdx.x;
    for (int e = tid; e < n_edges; e += gridDim.x * blockDim.x) {
        atomicAdd(&bins[dst[e]], 1);
    }
}

// ---------------- 3-phase device-wide exclusive scan ----------------
__global__ __launch_bounds__(SCAN_T) void scan_part_k(const int* __restrict__ bins,
                                                      int* __restrict__ partials, int n) {
    __shared__ int red[SCAN_T];
    const int ch = (n + SCAN_B * SCAN_T - 1) / (SCAN_B * SCAN_T);
    const int t = threadIdx.x;
    const long base = ((long)blockIdx.x * SCAN_T + t) * ch;
    int s = 0;
    for (int i = 0; i < ch; ++i) {
        long idx = base + i;
        if (idx < n) s += bins[idx];
    }
    red[t] = s;
    __syncthreads();
    for (int off = SCAN_T / 2; off > 0; off >>= 1) {
        if (t < off) red[t] += red[t + off];
        __syncthreads();
    }
    if (t == 0) partials[blockIdx.x] = red[0];
}

__global__ __launch_bounds__(SCAN_B) void scan_mid_k(const int* __restrict__ partials,
                                                     int* __restrict__ boff,
                                                     int* __restrict__ start, int n) {
    __shared__ int s[SCAN_B];
    const int t = threadIdx.x;
    s[t] = partials[t];
    __syncthreads();
    for (int off = 1; off < SCAN_B; off <<= 1) {
        int v = 0;
        if (t >= off) v = s[t - off];
        __syncthreads();
        if (t >= off) s[t] += v;
        __syncthreads();
    }
    boff[t] = (t == 0) ? 0 : s[t - 1];
    if (t == SCAN_B - 1) start[n] = s[t];
}

__global__ __launch_bounds__(SCAN_T) void scan_fin_k(const int* __restrict__ bins,
                                                     const int* __restrict__ boff,
                                                     int* __restrict__ start, int n) {
    __shared__ int red[SCAN_T];
    const int ch = (n + SCAN_B * SCAN_T - 1) / (SCAN_B * SCAN_T);
    const int t = threadIdx.x;
    const long base = ((long)blockIdx.x * SCAN_T + t) * ch;
    int s = 0;
    for (int i = 0; i < ch; ++i) {
        long idx = base + i;
        if (idx < n) s += bins[idx];
    }
    red[t] = s;
    __syncthreads();
    for (int off = 1; off < SCAN_T; off <<= 1) {
        int v = 0;
        if (t >= off) v = red[t - off];
        __syncthreads();
        if (t >= off) red[t] += v;
        __syncthreads();
    }
    int run = boff[blockIdx.x] + ((t == 0) ? 0 : red[t - 1]);
    for (int i = 0; i < ch; ++i) {
        long idx = base + i;
        if (idx < n) {
            start[idx] = run;
            run += bins[idx];
        }
    }
}

// ---------------- placement: sorted_src[start[d] + cur[d]++] = src[e] ----------------
// fine per-dst cursors: thousands of cache lines -> no atomic line contention
__global__ __launch_bounds__(256) void place_k(const int* __restrict__ src,
                                               const int* __restrict__ dst,
                                               const int* __restrict__ start,
                                               int* __restrict__ cur,
                                               int* __restrict__ sorted_src, int n_edges) {
    int tid = blockIdx.x * blockDim.x + threadIdx.x;
    for (int e = tid; e < n_edges; e += gridDim.x * blockDim.x) {
        int d = dst[e];
        int pos = start[d] + atomicAdd(&cur[d], 1);
        sorted_src[pos] = src[e];
    }
}

// ---------------- round-to-nearest bf16 helpers ----------------
__device__ __forceinline__ short bf16rn(float x) {
    unsigned u = __builtin_bit_cast(unsigned, x);
    unsigned r = u + 0x7FFFu + ((u >> 16) & 1u);
    return (short)(r >> 16);
}
__device__ __forceinline__ float bf16f(short h) {
    unsigned u = ((unsigned)(unsigned short)h) << 16;
    return __builtin_bit_cast(float, u);
}
__device__ __forceinline__ void split8(const f32x4 u, const f32x4 v,
                                       bf16x8& hi, bf16x8& lo) {
#pragma unroll
    for (int b = 0; b < 4; ++b) {
        short h = bf16rn(u[b]);
        hi[b] = h;
        lo[b] = bf16rn(u[b] - bf16f(h));
    }
#pragma unroll
    for (int b = 0; b < 4; ++b) {
        short h = bf16rn(v[b]);
        hi[4 + b] = h;
        lo[4 + b] = bf16rn(v[b] - bf16f(h));
    }
}

// ---------------- presplit: fp32 features -> bf16 hi-plane (for gathers) ----------------
__global__ __launch_bounds__(256) void presplit_k(const float* __restrict__ x,
                                                  u16x4* __restrict__ xhi, int n4) {
    int i = blockIdx.x * blockDim.x + threadIdx.x;
    const int st = gridDim.x * blockDim.x;
    for (; i < n4; i += st) {
        const f32x4 v = ((const f32x4*)x)[i];
        u16x4 o;
#pragma unroll
        for (int b = 0; b < 4; ++b) o[b] = (unsigned short)bf16rn(v[b]);
        xhi[i] = o;
    }
}

// ---------------- aggregation from bf16 hi-plane: one wave per dst node ----------------
// 4 subgroups of 16 lanes; each subgroup handles every 4th edge; lane holds 4 features.
// 4 rows (512B) in flight per wave instruction.
__global__ __launch_bounds__(256) void agg16_k(const unsigned short* __restrict__ xhi,
                                               const int* __restrict__ start,
                                               const int* __restrict__ srt,
                                               float* __restrict__ aggmean, int n_nodes) {
    const int wid = (blockIdx.x * blockDim.x + threadIdx.x) >> 6;
    const int lane = threadIdx.x & 63;
    const int nwaves = (gridDim.x * blockDim.x) >> 6;
    const int g = lane >> 4;
    const int k4 = (lane & 15) * 4;
    for (int n = wid; n < n_nodes; n += nwaves) {
        const int s0 = start[n];
        const int s1 = start[n + 1];
        f32x4 acc = {0.f, 0.f, 0.f, 0.f};
        for (int e = s0 + g; e < s1; e += 4) {
            const int s = srt[e];
            const u16x4 v = *(const u16x4*)(xhi + (long)s * DF + k4);
            acc[0] += bf16f((short)v[0]);
            acc[1] += bf16f((short)v[1]);
            acc[2] += bf16f((short)v[2]);
            acc[3] += bf16f((short)v[3]);
        }
#pragma unroll
        for (int c = 0; c < 4; ++c) {
            acc[c] += __shfl_xor(acc[c], 16);
            acc[c] += __shfl_xor(acc[c], 32);
        }
        if (g == 0) {
            const float inv = 1.0f / fmaxf((float)(s1 - s0), 1.0f);
            f32x4 m;
            m[0] = acc[0] * inv; m[1] = acc[1] * inv;
            m[2] = acc[2] * inv; m[3] = acc[3] * inv;
            *(f32x4*)(aggmean + (long)n * DF + k4) = m;
        }
    }
}

#define MFMA(a, b, c) __builtin_amdgcn_mfma_f32_16x16x32_bf16((a), (b), (c), 0, 0, 0)

#define MFMA4(ah, al, bh, bl, acc)      \
    do {                                \
        acc = MFMA(ah, bh, acc);        \
        acc = MFMA(ah, bl, acc);        \
        acc = MFMA(al, bh, acc);        \
        acc = MFMA(al, bl, acc);        \
    } while (0)

#define LOAD_W(Wl, Wr, col, g, wlh, wll, wrh, wrl)          \
    do {                                                    \
        _Pragma("unroll")                                   \
        for (int q = 0; q < 2; ++q) {                       \
            f32x4 tl0, tl1, tr0, tr1;                       \
            _Pragma("unroll")                               \
            for (int b = 0; b < 4; ++b) {                   \
                int k = 32 * q + 8 * (g) + b;               \
                tl0[b] = (Wl)[k * DF + (col)];              \
                tr0[b] = (Wr)[k * DF + (col)];              \
                tl1[b] = (Wl)[(k + 4) * DF + (col)];        \
                tr1[b] = (Wr)[(k + 4) * DF + (col)];        \
            }                                               \
            split8(tl0, tl1, wlh[q], wll[q]);               \
            split8(tr0, tr1, wrh[q], wrl[q]);               \
        }                                                   \
    } while (0)

// ---------------- dense1 (MFMA): h = relu(mean @ Wl + x @ Wr + b) ----------------
// Alias-safe (hout may alias mean): mean tile staged through LDS with barriers.
// Optionally also emits the bf16 hi-plane of h (for the layer-2 gather).
__global__ __launch_bounds__(256) void dense1_mfma(const float* __restrict__ mean,
                                                   const float* __restrict__ xdst,
                                                   const float* __restrict__ Wl,
                                                   const float* __restrict__ Wr,
                                                   const float* __restrict__ bias,
                                                   float* __restrict__ hout,
                                                   unsigned short* __restrict__ h16,
                                                   int n_nodes) {
    __shared__ float sA[16][68];
    const int t = threadIdx.x;
    const int lane = t & 63;
    const int wv = t >> 6;
    const int col = wv * 16 + (lane & 15);
    const int g = lane >> 4;

    bf16x8 wlh[2], wll[2], wrh[2], wrl[2];
    LOAD_W(Wl, Wr, col, g, wlh, wll, wrh, wrl);
    const float bv = bias[col];

    const int srow = t >> 4;
    const int sc4 = (t & 15) * 4;
    const int nrt = n_nodes >> 4;

    for (int rt = blockIdx.x; rt < nrt; rt += gridDim.x) {
        *(f32x4*)&sA[srow][sc4] =
            *(const f32x4*)(mean + ((long)rt * 16 + srow) * DF + sc4);
        const float* xrow = xdst + ((long)rt * 16 + (lane & 15)) * DF + 8 * g;
        const f32x4 xu0 = *(const f32x4*)(xrow + 0);
        const f32x4 xv0 = *(const f32x4*)(xrow + 4);
        const f32x4 xu1 = *(const f32x4*)(xrow + 32);
        const f32x4 xv1 = *(const f32x4*)(xrow + 36);
        __syncthreads();

        const int ar = lane & 15;
        const f32x4 au0 = *(const f32x4*)&sA[ar][8 * g + 0];
        const f32x4 av0 = *(const f32x4*)&sA[ar][8 * g + 4];
        const f32x4 au1 = *(const f32x4*)&sA[ar][8 * g + 32];
        const f32x4 av1 = *(const f32x4*)&sA[ar][8 * g + 36];

        f32x4 acc = {0.f, 0.f, 0.f, 0.f};
        bf16x8 h, l;
        split8(au0, av0, h, l);
        MFMA4(h, l, wlh[0], wll[0], acc);
        split8(au1, av1, h, l);
        MFMA4(h, l, wlh[1], wll[1], acc);
        split8(xu0, xv0, h, l);
        MFMA4(h, l, wrh[0], wrl[0], acc);
        split8(xu1, xv1, h, l);
        MFMA4(h, l, wrh[1], wrl[1], acc);

#pragma unroll
        for (int r = 0; r < 4; ++r) {
            const float v = fmaxf(acc[r] + bv, 0.0f);
            const long row = (long)rt * 16 + 4 * g + r;
            hout[row * DF + col] = v;
            if (h16) h16[row * DF + col] = (unsigned short)bf16rn(v);
        }
        __syncthreads();
    }
}

// ---------------- dense2 (MFMA) + fused final linear ----------------
__global__ __launch_bounds__(256) void dense2_mfma(const float* __restrict__ mean,
                                                   const float* __restrict__ hc,
                                                   const float* __restrict__ Wl,
                                                   const float* __restrict__ Wr,
                                                   const float* __restrict__ bias,
                                                   const float* __restrict__ Wlin,
                                                   const float* __restrict__ blin,
                                                   float* __restrict__ out, int n_nodes) {
    const int wglobal = (blockIdx.x * blockDim.x + threadIdx.x) >> 6;
    const int lane = threadIdx.x & 63;
    const int nwaves = (gridDim.x * blockDim.x) >> 6;
    const int ct = wglobal & 3;
    const int col = ct * 16 + (lane & 15);
    const int g = lane >> 4;

    bf16x8 wlh[2], wll[2], wrh[2], wrl[2];
    LOAD_W(Wl, Wr, col, g, wlh, wll, wrh, wrl);
    const float bv = bias[col];
    const float wl0 = Wlin[col * 2 + 0];
    const float wl1 = Wlin[col * 2 + 1];
    const float bl0 = (ct == 0) ? blin[0] : 0.0f;
    const float bl1 = (ct == 0) ? blin[1] : 0.0f;

    const int nrt = n_nodes >> 4;
    for (int rt = wglobal >> 2; rt < nrt; rt += nwaves >> 2) {
        const float* arow = mean + ((long)rt * 16 + (lane & 15)) * DF + 8 * g;
        const float* hrow = hc + ((long)rt * 16 + (lane & 15)) * DF + 8 * g;
        f32x4 acc = {0.f, 0.f, 0.f, 0.f};
        bf16x8 h, l;
        split8(*(const f32x4*)(arow + 0), *(const f32x4*)(arow + 4), h, l);
        MFMA4(h, l, wlh[0], wll[0], acc);
        split8(*(const f32x4*)(arow + 32), *(const f32x4*)(arow + 36), h, l);
        MFMA4(h, l, wlh[1], wll[1], acc);
        split8(*(const f32x4*)(hrow + 0), *(const f32x4*)(hrow + 4), h, l);
        MFMA4(h, l, wrh[0], wrl[0], acc);
        split8(*(const f32x4*)(hrow + 32), *(const f32x4*)(hrow + 36), h, l);
        MFMA4(h, l, wrh[1], wrl[1], acc);

#pragma unroll
        for (int r = 0; r < 4; ++r) {
            const float h2 = acc[r] + bv;
            float p0 = h2 * wl0;
            float p1 = h2 * wl1;
#pragma unroll
            for (int m = 1; m < 16; m <<= 1) {
                p0 += __shfl_xor(p0, m);
                p1 += __shfl_xor(p1, m);
            }
            if ((lane & 15) == 0) {
                const long node = (long)rt * 16 + 4 * g + r;
                atomicAdd(&out[node * 2 + 0], p0 + bl0);
                atomicAdd(&out[node * 2 + 1], p1 + bl1);
            }
        }
    }
}

extern "C" void kernel_launch(void* const* d_in, const int* in_sizes, int n_in,
                              void* d_out, int out_size, void* d_ws, size_t ws_size,
                              hipStream_t stream) {
    const float* x_c = (const float*)d_in[0];
    const float* x_m = (const float*)d_in[1];
    const int* cm_src = (const int*)d_in[2];
    const int* cm_dst = (const int*)d_in[3];
    const int* mc_src = (const int*)d_in[4];
    const int* mc_dst = (const int*)d_in[5];
    const float* Wl1_cm = (const float*)d_in[6];
    const float* Wr1_cm = (const float*)d_in[7];
    const float* b1_cm = (const float*)d_in[8];
    const float* Wl1_mc = (const float*)d_in[9];
    const float* Wr1_mc = (const float*)d_in[10];
    const float* b1_mc = (const float*)d_in[11];
    // layer-2 cm weights (d_in[12..14]) are dead: h2_m is unused in the reference
    const float* Wl2_mc = (const float*)d_in[15];
    const float* Wr2_mc = (const float*)d_in[16];
    const float* b2_mc = (const float*)d_in[17];
    const float* W_lin = (const float*)d_in[18];
    const float* b_lin = (const float*)d_in[19];
    float* out = (float*)d_out;

    // ---- workspace layout ----
    float* ws = (float*)d_ws;
    float* agg_m = ws;                              // NM*64 f; h_m aliases (in-place, safe)
    float* agg_c = agg_m + (long)NM * DF;           // NC*64 f
    float* h_c = agg_c + (long)NC * DF;             // NC*64 f; xc16/xm16 alias (consumed earlier)
    unsigned short* hm16 = (unsigned short*)(h_c + (long)NC * DF);  // NM*64 ushort
    int* ip = (int*)(hm16 + (long)NM * DF);

    int* binsM = ip;                  // NM   (zeroed)
    int* binsC = binsM + NM;          // NC   (zeroed)
    int* curM = binsC + NC;           // NM   (zeroed)
    int* curC = curM + NM;            // NC   (zeroed)
    int* startM = curC + NC;          // NM+1
    int* startC = startM + (NM + 1);  // NC+1
    int* srt_cm = startC + (NC + 1);  // NE
    int* srt_mc = srt_cm + NE;        // NE
    int* partM = srt_mc + NE;
    int* boffM = partM + SCAN_B;
    int* partC = boffM + SCAN_B;
    int* boffC = partC + SCAN_B;

    // aliased scratch (consumed before their hosts are written):
    unsigned short* xc16 = (unsigned short*)h_c;    // NC*64 ushort, read before dense1 writes h_c
    unsigned short* xm16 = xc16 + (long)NC * DF;    // NM*64 ushort

    // zero bins + cursors (contiguous) and the atomic output
    hipMemsetAsync(binsM, 0, (size_t)(2 * (NM + NC)) * sizeof(int), stream);
    hipMemsetAsync(out, 0, (size_t)out_size * sizeof(float), stream);

    // fine histograms + prefix
    hist_k<<<2048, 256, 0, stream>>>(cm_dst, binsM, NE);
    hist_k<<<2048, 256, 0, stream>>>(mc_dst, binsC, NE);

    scan_part_k<<<SCAN_B, SCAN_T, 0, stream>>>(binsM, partM, NM);
    scan_mid_k<<<1, SCAN_B, 0, stream>>>(partM, boffM, startM, NM);
    scan_fin_k<<<SCAN_B, SCAN_T, 0, stream>>>(binsM, boffM, startM, NM);

    scan_part_k<<<SCAN_B, SCAN_T, 0, stream>>>(binsC, partC, NC);
    scan_mid_k<<<1, SCAN_B, 0, stream>>>(partC, boffC, startC, NC);
    scan_fin_k<<<SCAN_B, SCAN_T, 0, stream>>>(binsC, boffC, startC, NC);

    // placement with fine per-dst cursors
    place_k<<<2048, 256, 0, stream>>>(cm_src, cm_dst, startM, curM, srt_cm, NE);
    place_k<<<2048, 256, 0, stream>>>(mc_src, mc_dst, startC, curC, srt_mc, NE);

    // bf16 hi-planes for the gathers
    presplit_k<<<2048, 256, 0, stream>>>(x_c, (u16x4*)xc16, NC * (DF / 4));
    presplit_k<<<2048, 256, 0, stream>>>(x_m, (u16x4*)xm16, NM * (DF / 4));

    // layer 1: aggregate means from bf16 planes, then MFMA dense
    agg16_k<<<(NM + 3) / 4, 256, 0, stream>>>(xc16, startM, srt_cm, agg_m, NM);
    agg16_k<<<(NC + 3) / 4, 256, 0, stream>>>(xm16, startC, srt_mc, agg_c, NC);
    dense1_mfma<<<1024, 256, 0, stream>>>(agg_m, x_m, Wl1_cm, Wr1_cm, b1_cm,
                                          agg_m /*h_m alias*/, hm16, NM);
    dense1_mfma<<<2048, 256, 0, stream>>>(agg_c, x_c, Wl1_mc, Wr1_mc, b1_mc,
                                          h_c, (unsigned short*)nullptr, NC);

    // layer 2: re-aggregate h_m (bf16 plane) over mc edges, dense2 + final linear
    agg16_k<<<(NC + 3) / 4, 256, 0, stream>>>(hm16, startC, srt_mc, agg_c, NC);
    dense2_mfma<<<2048, 256, 0, stream>>>(agg_c, h_c, Wl2_mc, Wr2_mc, b2_mc,
                                          W_lin, b_lin, out, NC);
}

// Round 10
// 424.793 us; speedup vs baseline: 2.1320x; 1.1719x over previous
//
#include <hip/hip_runtime.h>

#define NC 200000
#define NM 50000
#define NE 1000000
#define DF 64   // feature dim (D == H == 64)

#define SCAN_B 512
#define SCAN_T 256

#define BSH 10
#define BW 1024
#define NBM ((NM + BW - 1) >> BSH)   // 49
#define NBC ((NC + BW - 1) >> BSH)   // 196
#define CH 4096                      // edges per bsort block

typedef __attribute__((ext_vector_type(8))) short bf16x8;
typedef __attribute__((ext_vector_type(4))) float f32x4;
typedef __attribute__((ext_vector_type(4))) unsigned short u16x4;

// ---------------- histogram: bins[dst[e]] += 1 (fine cursors, no contention) ----
__global__ __launch_bounds__(256) void hist_k(const int* __restrict__ dst,
                                              int* __restrict__ bins, int n_edges) {
    int tid = blockIdx.x * blockDim.x + threadIdx.x;
    for (int e = tid; e < n_edges; e += gridDim.x * blockDim.x) {
        atomicAdd(&bins[dst[e]], 1);
    }
}

// ---------------- 3-phase device-wide exclusive scan ----------------
__global__ __launch_bounds__(SCAN_T) void scan_part_k(const int* __restrict__ bins,
                                                      int* __restrict__ partials, int n) {
    __shared__ int red[SCAN_T];
    const int ch = (n + SCAN_B * SCAN_T - 1) / (SCAN_B * SCAN_T);
    const int t = threadIdx.x;
    const long base = ((long)blockIdx.x * SCAN_T + t) * ch;
    int s = 0;
    for (int i = 0; i < ch; ++i) {
        long idx = base + i;
        if (idx < n) s += bins[idx];
    }
    red[t] = s;
    __syncthreads();
    for (int off = SCAN_T / 2; off > 0; off >>= 1) {
        if (t < off) red[t] += red[t + off];
        __syncthreads();
    }
    if (t == 0) partials[blockIdx.x] = red[0];
}

__global__ __launch_bounds__(SCAN_B) void scan_mid_k(const int* __restrict__ partials,
                                                     int* __restrict__ boff,
                                                     int* __restrict__ start, int n) {
    __shared__ int s[SCAN_B];
    const int t = threadIdx.x;
    s[t] = partials[t];
    __syncthreads();
    for (int off = 1; off < SCAN_B; off <<= 1) {
        int v = 0;
        if (t >= off) v = s[t - off];
        __syncthreads();
        if (t >= off) s[t] += v;
        __syncthreads();
    }
    boff[t] = (t == 0) ? 0 : s[t - 1];
    if (t == SCAN_B - 1) start[n] = s[t];
}

__global__ __launch_bounds__(SCAN_T) void scan_fin_k(const int* __restrict__ bins,
                                                     const int* __restrict__ boff,
                                                     int* __restrict__ start, int n) {
    __shared__ int red[SCAN_T];
    const int ch = (n + SCAN_B * SCAN_T - 1) / (SCAN_B * SCAN_T);
    const int t = threadIdx.x;
    const long base = ((long)blockIdx.x * SCAN_T + t) * ch;
    int s = 0;
    for (int i = 0; i < ch; ++i) {
        long idx = base + i;
        if (idx < n) s += bins[idx];
    }
    red[t] = s;
    __syncthreads();
    for (int off = 1; off < SCAN_T; off <<= 1) {
        int v = 0;
        if (t >= off) v = red[t - off];
        __syncthreads();
        if (t >= off) red[t] += v;
        __syncthreads();
    }
    int run = boff[blockIdx.x] + ((t == 0) ? 0 : red[t - 1]);
    for (int i = 0; i < ch; ++i) {
        long idx = base + i;
        if (idx < n) {
            start[idx] = run;
            run += bins[idx];
        }
    }
}

// ---------------- coarse cursor init: ccur[b] = start[b << BSH] ----------------
__global__ __launch_bounds__(256) void cinit_k(const int* __restrict__ start,
                                               int* __restrict__ ccur, int n_nodes, int nb) {
    const int b = blockIdx.x * blockDim.x + threadIdx.x;
    if (b < nb) ccur[b] = start[min(b << BSH, n_nodes)];
}

// ---------------- bucket sort pass 1: LDS-staged, block-aggregated cursors ----------
// Each block: 4096 edges -> LDS histogram over <=256 coarse buckets -> block scan ->
// ONE global atomic per bucket per block (no per-edge cursor contention) ->
// stage packed (src<<BSH|dl) in LDS -> flush buckets as contiguous coalesced runs.
__global__ __launch_bounds__(256) void bsort_k(const int* __restrict__ src,
                                               const int* __restrict__ dst,
                                               int* __restrict__ ccur,
                                               int* __restrict__ bkt,
                                               int n_edges, int nb) {
    __shared__ int cnt[256], pfx[256], gbase[256];
    __shared__ int stage[CH];
    const int t = threadIdx.x;
    const int e0 = blockIdx.x * CH;
    const int n = min(CH, n_edges - e0);
    cnt[t] = 0;
    __syncthreads();
    for (int i = t; i < n; i += 256) atomicAdd(&cnt[dst[e0 + i] >> BSH], 1);
    __syncthreads();
    const int myc = (t < nb) ? cnt[t] : 0;
    pfx[t] = myc;
    __syncthreads();
    for (int off = 1; off < 256; off <<= 1) {
        int add = (t >= off) ? pfx[t - off] : 0;
        __syncthreads();
        pfx[t] += add;
        __syncthreads();
    }
    const int excl = pfx[t] - myc;            // own-slot read
    if (t < nb && myc > 0) gbase[t] = atomicAdd(&ccur[t], myc);
    pfx[t] = excl;                            // own-slot write
    cnt[t] = 0;                               // reuse as placement cursor
    __syncthreads();
    for (int i = t; i < n; i += 256) {
        const int d = dst[e0 + i];
        const int b = d >> BSH;
        const int p = pfx[b] + atomicAdd(&cnt[b], 1);
        stage[p] = (src[e0 + i] << BSH) | (d & (BW - 1));
    }
    __syncthreads();
    const int wv = t >> 6, ln = t & 63;
    for (int b = wv; b < nb; b += 4) {
        const int c = cnt[b];
        if (c == 0) continue;
        const int gb = gbase[b], lo = pfx[b];
        for (int j = ln; j < c; j += 64) bkt[gb + j] = stage[lo + j];
    }
}

// ---------------- bucket sort pass 2: within-bucket counting sort (LDS cursors) ----
__global__ __launch_bounds__(256) void bp2_k(const int* __restrict__ bkt,
                                             const int* __restrict__ start,
                                             int* __restrict__ srt, int n_nodes) {
    __shared__ int lcur[BW];
    const int base = blockIdx.x << BSH;
    for (int i = threadIdx.x; i < BW; i += 256) lcur[i] = 0;
    __syncthreads();
    const int e0 = start[base];
    const int e1 = start[min(base + BW, n_nodes)];
    for (int e = e0 + threadIdx.x; e < e1; e += 256) {
        const int p = bkt[e];
        const int dl = p & (BW - 1);
        const int pos = start[base + dl] + atomicAdd(&lcur[dl], 1);
        srt[pos] = p >> BSH;
    }
}

// ---------------- round-to-nearest bf16 helpers ----------------
__device__ __forceinline__ short bf16rn(float x) {
    unsigned u = __builtin_bit_cast(unsigned, x);
    unsigned r = u + 0x7FFFu + ((u >> 16) & 1u);
    return (short)(r >> 16);
}
__device__ __forceinline__ float bf16f(short h) {
    unsigned u = ((unsigned)(unsigned short)h) << 16;
    return __builtin_bit_cast(float, u);
}
__device__ __forceinline__ void split8(const f32x4 u, const f32x4 v,
                                       bf16x8& hi, bf16x8& lo) {
#pragma unroll
    for (int b = 0; b < 4; ++b) {
        short h = bf16rn(u[b]);
        hi[b] = h;
        lo[b] = bf16rn(u[b] - bf16f(h));
    }
#pragma unroll
    for (int b = 0; b < 4; ++b) {
        short h = bf16rn(v[b]);
        hi[4 + b] = h;
        lo[4 + b] = bf16rn(v[b] - bf16f(h));
    }
}

// ---------------- presplit: fp32 features -> bf16 hi-plane (for gathers) ----------------
__global__ __launch_bounds__(256) void presplit_k(const float* __restrict__ x,
                                                  u16x4* __restrict__ xhi, int n4) {
    int i = blockIdx.x * blockDim.x + threadIdx.x;
    const int st = gridDim.x * blockDim.x;
    for (; i < n4; i += st) {
        const f32x4 v = ((const f32x4*)x)[i];
        u16x4 o;
#pragma unroll
        for (int b = 0; b < 4; ++b) o[b] = (unsigned short)bf16rn(v[b]);
        xhi[i] = o;
    }
}

// ---------------- single-plane aggregation: one wave per dst node, bf16 mean out ----
__global__ __launch_bounds__(256) void agg16_k(const unsigned short* __restrict__ xhi,
                                               const int* __restrict__ start,
                                               const int* __restrict__ srt,
                                               unsigned short* __restrict__ mean16,
                                               int n_nodes) {
    const int wid = (blockIdx.x * blockDim.x + threadIdx.x) >> 6;
    const int lane = threadIdx.x & 63;
    const int nwaves = (gridDim.x * blockDim.x) >> 6;
    const int g = lane >> 4;
    const int k4 = (lane & 15) * 4;
    for (int n = wid; n < n_nodes; n += nwaves) {
        const int s0 = start[n];
        const int s1 = start[n + 1];
        f32x4 acc = {0.f, 0.f, 0.f, 0.f};
        for (int e = s0 + g; e < s1; e += 4) {
            const int s = srt[e];
            const u16x4 v = *(const u16x4*)(xhi + (long)s * DF + k4);
#pragma unroll
            for (int c = 0; c < 4; ++c) acc[c] += bf16f((short)v[c]);
        }
#pragma unroll
        for (int c = 0; c < 4; ++c) {
            acc[c] += __shfl_xor(acc[c], 16);
            acc[c] += __shfl_xor(acc[c], 32);
        }
        if (g == 0) {
            const float inv = 1.0f / fmaxf((float)(s1 - s0), 1.0f);
            u16x4 o;
#pragma unroll
            for (int c = 0; c < 4; ++c) o[c] = (unsigned short)bf16rn(acc[c] * inv);
            *(u16x4*)(mean16 + (long)n * DF + k4) = o;
        }
    }
}

// ---------------- fused dual-plane aggregation over mc edges ----------------
// one edge sweep gathers BOTH x_m and h_m bf16 rows; two bf16 means out.
__global__ __launch_bounds__(256) void aggc2_k(const unsigned short* __restrict__ xp,
                                               const unsigned short* __restrict__ hp,
                                               const int* __restrict__ start,
                                               const int* __restrict__ srt,
                                               unsigned short* __restrict__ mx,
                                               unsigned short* __restrict__ mh, int n_nodes) {
    const int wid = (blockIdx.x * blockDim.x + threadIdx.x) >> 6;
    const int lane = threadIdx.x & 63;
    const int nwaves = (gridDim.x * blockDim.x) >> 6;
    const int g = lane >> 4;
    const int k4 = (lane & 15) * 4;
    for (int n = wid; n < n_nodes; n += nwaves) {
        const int s0 = start[n], s1 = start[n + 1];
        f32x4 ax = {0.f, 0.f, 0.f, 0.f}, ah = {0.f, 0.f, 0.f, 0.f};
        for (int e = s0 + g; e < s1; e += 4) {
            const int s = srt[e];
            const u16x4 vx = *(const u16x4*)(xp + (long)s * DF + k4);
            const u16x4 vh = *(const u16x4*)(hp + (long)s * DF + k4);
#pragma unroll
            for (int c = 0; c < 4; ++c) {
                ax[c] += bf16f((short)vx[c]);
                ah[c] += bf16f((short)vh[c]);
            }
        }
#pragma unroll
        for (int c = 0; c < 4; ++c) {
            ax[c] += __shfl_xor(ax[c], 16);
            ax[c] += __shfl_xor(ax[c], 32);
            ah[c] += __shfl_xor(ah[c], 16);
            ah[c] += __shfl_xor(ah[c], 32);
        }
        if (g == 0) {
            const float inv = 1.0f / fmaxf((float)(s1 - s0), 1.0f);
            u16x4 ox, oh;
#pragma unroll
            for (int c = 0; c < 4; ++c) {
                ox[c] = (unsigned short)bf16rn(ax[c] * inv);
                oh[c] = (unsigned short)bf16rn(ah[c] * inv);
            }
            *(u16x4*)(mx + (long)n * DF + k4) = ox;
            *(u16x4*)(mh + (long)n * DF + k4) = oh;
        }
    }
}

#define MFMA(a, b, c) __builtin_amdgcn_mfma_f32_16x16x32_bf16((a), (b), (c), 0, 0, 0)

#define MFMA4(ah, al, bh, bl, acc)      \
    do {                                \
        acc = MFMA(ah, bh, acc);        \
        acc = MFMA(ah, bl, acc);        \
        acc = MFMA(al, bh, acc);        \
        acc = MFMA(al, bl, acc);        \
    } while (0)

#define LOAD_W(Wl, Wr, col, g, wlh, wll, wrh, wrl)          \
    do {                                                    \
        _Pragma("unroll")                                   \
        for (int q = 0; q < 2; ++q) {                       \
            f32x4 tl0, tl1, tr0, tr1;                       \
            _Pragma("unroll")                               \
            for (int b = 0; b < 4; ++b) {                   \
                int k = 32 * q + 8 * (g) + b;               \
                tl0[b] = (Wl)[k * DF + (col)];              \
                tr0[b] = (Wr)[k * DF + (col)];              \
                tl1[b] = (Wl)[(k + 4) * DF + (col)];        \
                tr1[b] = (Wr)[(k + 4) * DF + (col)];        \
            }                                               \
            split8(tl0, tl1, wlh[q], wll[q]);               \
            split8(tr0, tr1, wrh[q], wrl[q]);               \
        }                                                   \
    } while (0)

// ---------------- dense1 @ NM: hm16 = bf16(relu(mean16 @ Wl + x_m @ Wr + b)) --------
// mean is a bf16 plane -> A-frags load directly, no LDS, no barrier, no alias.
__global__ __launch_bounds__(256) void dense1nm_k(const unsigned short* __restrict__ mean16,
                                                  const float* __restrict__ xdst,
                                                  const float* __restrict__ Wl,
                                                  const float* __restrict__ Wr,
                                                  const float* __restrict__ bias,
                                                  unsigned short* __restrict__ h16,
                                                  int n_nodes) {
    const int wglobal = (blockIdx.x * blockDim.x + threadIdx.x) >> 6;
    const int lane = threadIdx.x & 63;
    const int nwaves = (gridDim.x * blockDim.x) >> 6;
    const int ct = wglobal & 3;
    const int col = ct * 16 + (lane & 15);
    const int g = lane >> 4;

    bf16x8 wlh[2], wll[2], wrh[2], wrl[2];
    LOAD_W(Wl, Wr, col, g, wlh, wll, wrh, wrl);
    const float bv = bias[col];

    const int nrt = n_nodes >> 4;
    for (int rt = wglobal >> 2; rt < nrt; rt += nwaves >> 2) {
        const long rowA = (long)rt * 16 + (lane & 15);
        const bf16x8 m0 = *(const bf16x8*)(mean16 + rowA * DF + 8 * g);
        const bf16x8 m1 = *(const bf16x8*)(mean16 + rowA * DF + 32 + 8 * g);
        const float* xrow = xdst + rowA * DF + 8 * g;
        f32x4 acc = {0.f, 0.f, 0.f, 0.f};
        bf16x8 h, l;
        acc = MFMA(m0, wlh[0], acc);
        acc = MFMA(m0, wll[0], acc);
        acc = MFMA(m1, wlh[1], acc);
        acc = MFMA(m1, wll[1], acc);
        split8(*(const f32x4*)(xrow + 0), *(const f32x4*)(xrow + 4), h, l);
        MFMA4(h, l, wrh[0], wrl[0], acc);
        split8(*(const f32x4*)(xrow + 32), *(const f32x4*)(xrow + 36), h, l);
        MFMA4(h, l, wrh[1], wrl[1], acc);
#pragma unroll
        for (int r = 0; r < 4; ++r)
            h16[((long)rt * 16 + 4 * g + r) * DF + col] =
                (unsigned short)bf16rn(fmaxf(acc[r] + bv, 0.0f));
    }
}

// ---------------- fused customer dense: layer1 + layer2 + final linear ----------------
// h_c lives only in a bf16 LDS tile (never touches HBM).
__global__ __launch_bounds__(256) void densec_k(const unsigned short* __restrict__ meanx,
                                                const unsigned short* __restrict__ meanh,
                                                const float* __restrict__ xc,
                                                const float* __restrict__ Wl1,
                                                const float* __restrict__ Wr1,
                                                const float* __restrict__ b1,
                                                const float* __restrict__ Wl2,
                                                const float* __restrict__ Wr2,
                                                const float* __restrict__ b2,
                                                const float* __restrict__ Wlin,
                                                const float* __restrict__ blin,
                                                float* __restrict__ out, int n_nodes) {
    __shared__ unsigned short sH[16][72];   // pad 72: uniform bank spread for b128 reads
    const int t = threadIdx.x;
    const int lane = t & 63;
    const int wv = t >> 6;
    const int col = wv * 16 + (lane & 15);
    const int g = lane >> 4;

    bf16x8 w1lh[2], w1ll[2], w1rh[2], w1rl[2];
    LOAD_W(Wl1, Wr1, col, g, w1lh, w1ll, w1rh, w1rl);
    bf16x8 w2lh[2], w2ll[2], w2rh[2], w2rl[2];
    LOAD_W(Wl2, Wr2, col, g, w2lh, w2ll, w2rh, w2rl);
    const float bv1 = b1[col];
    const float bv2 = b2[col];
    const float wl0 = Wlin[col * 2 + 0];
    const float wl1s = Wlin[col * 2 + 1];
    const float bl0 = (wv == 0) ? blin[0] : 0.0f;
    const float bl1 = (wv == 0) ? blin[1] : 0.0f;

    const int nrt = n_nodes >> 4;
    for (int rt = blockIdx.x; rt < nrt; rt += gridDim.x) {
        const long rowA = (long)rt * 16 + (lane & 15);
        const bf16x8 mx0 = *(const bf16x8*)(meanx + rowA * DF + 8 * g);
        const bf16x8 mx1 = *(const bf16x8*)(meanx + rowA * DF + 32 + 8 * g);
        const bf16x8 mh0 = *(const bf16x8*)(meanh + rowA * DF + 8 * g);
        const bf16x8 mh1 = *(const bf16x8*)(meanh + rowA * DF + 32 + 8 * g);
        const float* xrow = xc + rowA * DF + 8 * g;

        // ---- layer 1: h_c = relu(meanx @ Wl1 + x_c @ Wr1 + b1) ----
        f32x4 acc = {0.f, 0.f, 0.f, 0.f};
        bf16x8 h, l;
        acc = MFMA(mx0, w1lh[0], acc);
        acc = MFMA(mx0, w1ll[0], acc);
        acc = MFMA(mx1, w1lh[1], acc);
        acc = MFMA(mx1, w1ll[1], acc);
        split8(*(const f32x4*)(xrow + 0), *(const f32x4*)(xrow + 4), h, l);
        MFMA4(h, l, w1rh[0], w1rl[0], acc);
        split8(*(const f32x4*)(xrow + 32), *(const f32x4*)(xrow + 36), h, l);
        MFMA4(h, l, w1rh[1], w1rl[1], acc);
#pragma unroll
        for (int r = 0; r < 4; ++r)
            sH[4 * g + r][col] = (unsigned short)bf16rn(fmaxf(acc[r] + bv1, 0.0f));
        __syncthreads();

        // ---- layer 2: h2 = meanh @ Wl2 + h_c @ Wr2 + b2 ----
        const bf16x8 hc0 = *(const bf16x8*)&sH[lane & 15][8 * g];
        const bf16x8 hc1 = *(const bf16x8*)&sH[lane & 15][32 + 8 * g];
        f32x4 a2 = {0.f, 0.f, 0.f, 0.f};
        a2 = MFMA(mh0, w2lh[0], a2);
        a2 = MFMA(mh0, w2ll[0], a2);
        a2 = MFMA(mh1, w2lh[1], a2);
        a2 = MFMA(mh1, w2ll[1], a2);
        a2 = MFMA(hc0, w2rh[0], a2);
        a2 = MFMA(hc0, w2rl[0], a2);
        a2 = MFMA(hc1, w2rh[1], a2);
        a2 = MFMA(hc1, w2rl[1], a2);

        // ---- final linear + atomic accumulate into out ----
#pragma unroll
        for (int r = 0; r < 4; ++r) {
            const float h2 = a2[r] + bv2;
            float p0 = h2 * wl0;
            float p1 = h2 * wl1s;
#pragma unroll
            for (int m = 1; m < 16; m <<= 1) {
                p0 += __shfl_xor(p0, m);
                p1 += __shfl_xor(p1, m);
            }
            if ((lane & 15) == 0) {
                const long node = (long)rt * 16 + 4 * g + r;
                atomicAdd(&out[node * 2 + 0], p0 + bl0);
                atomicAdd(&out[node * 2 + 1], p1 + bl1);
            }
        }
        __syncthreads();
    }
}

extern "C" void kernel_launch(void* const* d_in, const int* in_sizes, int n_in,
                              void* d_out, int out_size, void* d_ws, size_t ws_size,
                              hipStream_t stream) {
    const float* x_c = (const float*)d_in[0];
    const float* x_m = (const float*)d_in[1];
    const int* cm_src = (const int*)d_in[2];
    const int* cm_dst = (const int*)d_in[3];
    const int* mc_src = (const int*)d_in[4];
    const int* mc_dst = (const int*)d_in[5];
    const float* Wl1_cm = (const float*)d_in[6];
    const float* Wr1_cm = (const float*)d_in[7];
    const float* b1_cm = (const float*)d_in[8];
    const float* Wl1_mc = (const float*)d_in[9];
    const float* Wr1_mc = (const float*)d_in[10];
    const float* b1_mc = (const float*)d_in[11];
    // layer-2 cm weights (d_in[12..14]) are dead: h2_m is unused in the reference
    const float* Wl2_mc = (const float*)d_in[15];
    const float* Wr2_mc = (const float*)d_in[16];
    const float* b2_mc = (const float*)d_in[17];
    const float* W_lin = (const float*)d_in[18];
    const float* b_lin = (const float*)d_in[19];
    float* out = (float*)d_out;

    // ---- workspace layout (~110 MB) ----
    unsigned short* up = (unsigned short*)d_ws;
    unsigned short* aggm16 = up;                        // NM*64
    unsigned short* hm16 = aggm16 + (long)NM * DF;      // NM*64
    unsigned short* xm16 = hm16 + (long)NM * DF;        // NM*64
    unsigned short* xc16 = xm16 + (long)NM * DF;        // NC*64
    unsigned short* meanx16 = xc16 + (long)NC * DF;     // NC*64
    unsigned short* meanh16 = meanx16 + (long)NC * DF;  // NC*64
    int* ip = (int*)(meanh16 + (long)NC * DF);

    int* binsM = ip;                  // NM (zeroed)
    int* binsC = binsM + NM;          // NC (zeroed)
    int* startM = binsC + NC;         // NM+1
    int* startC = startM + (NM + 1);  // NC+1
    int* ccurM = startC + (NC + 1);   // NBM
    int* ccurC = ccurM + NBM;         // NBC
    int* partM = ccurC + NBC;         // SCAN_B
    int* boffM = partM + SCAN_B;
    int* partC = boffM + SCAN_B;
    int* boffC = partC + SCAN_B;
    int* srt_cm = boffC + SCAN_B;     // NE
    int* srt_mc = srt_cm + NE;        // NE
    int* bkt = srt_mc + NE;           // NE (reused by both sorts, sequentially)

    // zero fine bins + the atomic output
    hipMemsetAsync(binsM, 0, (size_t)(NM + NC) * sizeof(int), stream);
    hipMemsetAsync(out, 0, (size_t)out_size * sizeof(float), stream);

    // fine histograms + prefix
    hist_k<<<2048, 256, 0, stream>>>(cm_dst, binsM, NE);
    hist_k<<<2048, 256, 0, stream>>>(mc_dst, binsC, NE);

    scan_part_k<<<SCAN_B, SCAN_T, 0, stream>>>(binsM, partM, NM);
    scan_mid_k<<<1, SCAN_B, 0, stream>>>(partM, boffM, startM, NM);
    scan_fin_k<<<SCAN_B, SCAN_T, 0, stream>>>(binsM, boffM, startM, NM);

    scan_part_k<<<SCAN_B, SCAN_T, 0, stream>>>(binsC, partC, NC);
    scan_mid_k<<<1, SCAN_B, 0, stream>>>(partC, boffC, startC, NC);
    scan_fin_k<<<SCAN_B, SCAN_T, 0, stream>>>(binsC, boffC, startC, NC);

    // two-level bucket sort (cm then mc; bkt buffer reused sequentially)
    const int nsb = (NE + CH - 1) / CH;   // 245
    cinit_k<<<1, 256, 0, stream>>>(startM, ccurM, NM, NBM);
    cinit_k<<<1, 256, 0, stream>>>(startC, ccurC, NC, NBC);
    bsort_k<<<nsb, 256, 0, stream>>>(cm_src, cm_dst, ccurM, bkt, NE, NBM);
    bp2_k<<<NBM, 256, 0, stream>>>(bkt, startM, srt_cm, NM);
    bsort_k<<<nsb, 256, 0, stream>>>(mc_src, mc_dst, ccurC, bkt, NE, NBC);
    bp2_k<<<NBC, 256, 0, stream>>>(bkt, startC, srt_mc, NC);

    // bf16 hi-planes for the gathers
    presplit_k<<<2048, 256, 0, stream>>>(x_c, (u16x4*)xc16, NC * (DF / 4));
    presplit_k<<<2048, 256, 0, stream>>>(x_m, (u16x4*)xm16, NM * (DF / 4));

    // layer 1 @ merchants: m-mean (bf16) then dense -> hm16
    agg16_k<<<(NM + 3) / 4, 256, 0, stream>>>(xc16, startM, srt_cm, aggm16, NM);
    dense1nm_k<<<1024, 256, 0, stream>>>(aggm16, x_m, Wl1_cm, Wr1_cm, b1_cm, hm16, NM);

    // customers: fused dual aggregation (x_m-mean + h_m-mean in one edge sweep)
    aggc2_k<<<(NC + 3) / 4, 256, 0, stream>>>(xm16, hm16, startC, srt_mc,
                                              meanx16, meanh16, NC);

    // customers: fused layer1 + layer2 + final linear (h_c never hits HBM)
    densec_k<<<2048, 256, 0, stream>>>(meanx16, meanh16, x_c,
                                       Wl1_mc, Wr1_mc, b1_mc,
                                       Wl2_mc, Wr2_mc, b2_mc,
                                       W_lin, b_lin, out, NC);
}

// Round 11
// 389.356 us; speedup vs baseline: 2.3260x; 1.0910x over previous
//
#include <hip/hip_runtime.h>

#define NC 200000
#define NM 50000
#define NE 1000000
#define DF 64   // feature dim (D == H == 64)

#define SCAN_B 512
#define SCAN_T 256

#define BSH 10
#define BW 1024
#define NBM ((NM + BW - 1) >> BSH)   // 49
#define NBC ((NC + BW - 1) >> BSH)   // 196
#define CH 4096                      // edges per bsort block

typedef __attribute__((ext_vector_type(8))) short bf16x8;
typedef __attribute__((ext_vector_type(4))) float f32x4;
typedef __attribute__((ext_vector_type(4))) unsigned short u16x4;

// ---------------- histogram: bins[dst[e]] += 1 (fine counters: ~6K lines, no contention) ----
__global__ __launch_bounds__(256) void hist_k(const int* __restrict__ dst,
                                              int* __restrict__ bins, int n_edges) {
    int tid = blockIdx.x * blockDim.x + threadIdx.x;
    for (int e = tid; e < n_edges; e += gridDim.x * blockDim.x) {
        atomicAdd(&bins[dst[e]], 1);
    }
}

// ---------------- 3-phase device-wide exclusive scan ----------------
__global__ __launch_bounds__(SCAN_T) void scan_part_k(const int* __restrict__ bins,
                                                      int* __restrict__ partials, int n) {
    __shared__ int red[SCAN_T];
    const int ch = (n + SCAN_B * SCAN_T - 1) / (SCAN_B * SCAN_T);
    const int t = threadIdx.x;
    const long base = ((long)blockIdx.x * SCAN_T + t) * ch;
    int s = 0;
    for (int i = 0; i < ch; ++i) {
        long idx = base + i;
        if (idx < n) s += bins[idx];
    }
    red[t] = s;
    __syncthreads();
    for (int off = SCAN_T / 2; off > 0; off >>= 1) {
        if (t < off) red[t] += red[t + off];
        __syncthreads();
    }
    if (t == 0) partials[blockIdx.x] = red[0];
}

__global__ __launch_bounds__(SCAN_B) void scan_mid_k(const int* __restrict__ partials,
                                                     int* __restrict__ boff,
                                                     int* __restrict__ start, int n) {
    __shared__ int s[SCAN_B];
    const int t = threadIdx.x;
    s[t] = partials[t];
    __syncthreads();
    for (int off = 1; off < SCAN_B; off <<= 1) {
        int v = 0;
        if (t >= off) v = s[t - off];
        __syncthreads();
        if (t >= off) s[t] += v;
        __syncthreads();
    }
    boff[t] = (t == 0) ? 0 : s[t - 1];
    if (t == SCAN_B - 1) start[n] = s[t];
}

__global__ __launch_bounds__(SCAN_T) void scan_fin_k(const int* __restrict__ bins,
                                                     const int* __restrict__ boff,
                                                     int* __restrict__ start, int n) {
    __shared__ int red[SCAN_T];
    const int ch = (n + SCAN_B * SCAN_T - 1) / (SCAN_B * SCAN_T);
    const int t = threadIdx.x;
    const long base = ((long)blockIdx.x * SCAN_T + t) * ch;
    int s = 0;
    for (int i = 0; i < ch; ++i) {
        long idx = base + i;
        if (idx < n) s += bins[idx];
    }
    red[t] = s;
    __syncthreads();
    for (int off = 1; off < SCAN_T; off <<= 1) {
        int v = 0;
        if (t >= off) v = red[t - off];
        __syncthreads();
        if (t >= off) red[t] += v;
        __syncthreads();
    }
    int run = boff[blockIdx.x] + ((t == 0) ? 0 : red[t - 1]);
    for (int i = 0; i < ch; ++i) {
        long idx = base + i;
        if (idx < n) {
            start[idx] = run;
            run += bins[idx];
        }
    }
}

// ---------------- coarse cursor init: ccur[b] = start[b << BSH] ----------------
__global__ __launch_bounds__(256) void cinit_k(const int* __restrict__ start,
                                               int* __restrict__ ccur, int n_nodes, int nb) {
    const int b = blockIdx.x * blockDim.x + threadIdx.x;
    if (b < nb) ccur[b] = start[min(b << BSH, n_nodes)];
}

// ---------------- bucket sort pass 1: LDS-staged, block-aggregated cursors ----------
__global__ __launch_bounds__(256) void bsort_k(const int* __restrict__ src,
                                               const int* __restrict__ dst,
                                               int* __restrict__ ccur,
                                               int* __restrict__ bkt,
                                               int n_edges, int nb) {
    __shared__ int cnt[256], pfx[256], gbase[256];
    __shared__ int stage[CH];
    const int t = threadIdx.x;
    const int e0 = blockIdx.x * CH;
    const int n = min(CH, n_edges - e0);
    cnt[t] = 0;
    __syncthreads();
    for (int i = t; i < n; i += 256) atomicAdd(&cnt[dst[e0 + i] >> BSH], 1);
    __syncthreads();
    const int myc = (t < nb) ? cnt[t] : 0;
    pfx[t] = myc;
    __syncthreads();
    for (int off = 1; off < 256; off <<= 1) {
        int add = (t >= off) ? pfx[t - off] : 0;
        __syncthreads();
        pfx[t] += add;
        __syncthreads();
    }
    const int excl = pfx[t] - myc;
    if (t < nb && myc > 0) gbase[t] = atomicAdd(&ccur[t], myc);
    pfx[t] = excl;
    cnt[t] = 0;
    __syncthreads();
    for (int i = t; i < n; i += 256) {
        const int d = dst[e0 + i];
        const int b = d >> BSH;
        const int p = pfx[b] + atomicAdd(&cnt[b], 1);
        stage[p] = (src[e0 + i] << BSH) | (d & (BW - 1));
    }
    __syncthreads();
    const int wv = t >> 6, ln = t & 63;
    for (int b = wv; b < nb; b += 4) {
        const int c = cnt[b];
        if (c == 0) continue;
        const int gb = gbase[b], lo = pfx[b];
        for (int j = ln; j < c; j += 64) bkt[gb + j] = stage[lo + j];
    }
}

// ---------------- bucket sort pass 2: within-bucket counting sort (LDS cursors) ----
__global__ __launch_bounds__(256) void bp2_k(const int* __restrict__ bkt,
                                             const int* __restrict__ start,
                                             int* __restrict__ srt, int n_nodes) {
    __shared__ int lcur[BW];
    const int base = blockIdx.x << BSH;
    for (int i = threadIdx.x; i < BW; i += 256) lcur[i] = 0;
    __syncthreads();
    const int e0 = start[base];
    const int e1 = start[min(base + BW, n_nodes)];
    for (int e = e0 + threadIdx.x; e < e1; e += 256) {
        const int p = bkt[e];
        const int dl = p & (BW - 1);
        const int pos = start[base + dl] + atomicAdd(&lcur[dl], 1);
        srt[pos] = p >> BSH;
    }
}

// ---------------- round-to-nearest bf16 helpers ----------------
__device__ __forceinline__ short bf16rn(float x) {
    unsigned u = __builtin_bit_cast(unsigned, x);
    unsigned r = u + 0x7FFFu + ((u >> 16) & 1u);
    return (short)(r >> 16);
}
__device__ __forceinline__ float bf16f(short h) {
    unsigned u = ((unsigned)(unsigned short)h) << 16;
    return __builtin_bit_cast(float, u);
}
__device__ __forceinline__ void split8(const f32x4 u, const f32x4 v,
                                       bf16x8& hi, bf16x8& lo) {
#pragma unroll
    for (int b = 0; b < 4; ++b) {
        short h = bf16rn(u[b]);
        hi[b] = h;
        lo[b] = bf16rn(u[b] - bf16f(h));
    }
#pragma unroll
    for (int b = 0; b < 4; ++b) {
        short h = bf16rn(v[b]);
        hi[4 + b] = h;
        lo[4 + b] = bf16rn(v[b] - bf16f(h));
    }
}

// ---------------- presplit: fp32 features -> bf16 hi-plane ----------------
__global__ __launch_bounds__(256) void presplit_k(const float* __restrict__ x,
                                                  u16x4* __restrict__ xhi, int n4) {
    int i = blockIdx.x * blockDim.x + threadIdx.x;
    const int st = gridDim.x * blockDim.x;
    for (; i < n4; i += st) {
        const f32x4 v = ((const f32x4*)x)[i];
        u16x4 o;
#pragma unroll
        for (int b = 0; b < 4; ++b) o[b] = (unsigned short)bf16rn(v[b]);
        xhi[i] = o;
    }
}

// ---------------- single-plane aggregation: one wave per dst node, bf16 mean out ----
__global__ __launch_bounds__(256) void agg16_k(const unsigned short* __restrict__ xhi,
                                               const int* __restrict__ start,
                                               const int* __restrict__ srt,
                                               unsigned short* __restrict__ mean16,
                                               int n_nodes) {
    const int wid = (blockIdx.x * blockDim.x + threadIdx.x) >> 6;
    const int lane = threadIdx.x & 63;
    const int nwaves = (gridDim.x * blockDim.x) >> 6;
    const int g = lane >> 4;
    const int k4 = (lane & 15) * 4;
    for (int n = wid; n < n_nodes; n += nwaves) {
        const int s0 = start[n];
        const int s1 = start[n + 1];
        f32x4 acc = {0.f, 0.f, 0.f, 0.f};
        for (int e = s0 + g; e < s1; e += 4) {
            const int s = srt[e];
            const u16x4 v = *(const u16x4*)(xhi + (long)s * DF + k4);
#pragma unroll
            for (int c = 0; c < 4; ++c) acc[c] += bf16f((short)v[c]);
        }
#pragma unroll
        for (int c = 0; c < 4; ++c) {
            acc[c] += __shfl_xor(acc[c], 16);
            acc[c] += __shfl_xor(acc[c], 32);
        }
        if (g == 0) {
            const float inv = 1.0f / fmaxf((float)(s1 - s0), 1.0f);
            u16x4 o;
#pragma unroll
            for (int c = 0; c < 4; ++c) o[c] = (unsigned short)bf16rn(acc[c] * inv);
            *(u16x4*)(mean16 + (long)n * DF + k4) = o;
        }
    }
}

// ---------------- fused dual-plane aggregation over mc edges ----------------
__global__ __launch_bounds__(256) void aggc2_k(const unsigned short* __restrict__ xp,
                                               const unsigned short* __restrict__ hp,
                                               const int* __restrict__ start,
                                               const int* __restrict__ srt,
                                               unsigned short* __restrict__ mx,
                                               unsigned short* __restrict__ mh, int n_nodes) {
    const int wid = (blockIdx.x * blockDim.x + threadIdx.x) >> 6;
    const int lane = threadIdx.x & 63;
    const int nwaves = (gridDim.x * blockDim.x) >> 6;
    const int g = lane >> 4;
    const int k4 = (lane & 15) * 4;
    for (int n = wid; n < n_nodes; n += nwaves) {
        const int s0 = start[n], s1 = start[n + 1];
        f32x4 ax = {0.f, 0.f, 0.f, 0.f}, ah = {0.f, 0.f, 0.f, 0.f};
        for (int e = s0 + g; e < s1; e += 4) {
            const int s = srt[e];
            const u16x4 vx = *(const u16x4*)(xp + (long)s * DF + k4);
            const u16x4 vh = *(const u16x4*)(hp + (long)s * DF + k4);
#pragma unroll
            for (int c = 0; c < 4; ++c) {
                ax[c] += bf16f((short)vx[c]);
                ah[c] += bf16f((short)vh[c]);
            }
        }
#pragma unroll
        for (int c = 0; c < 4; ++c) {
            ax[c] += __shfl_xor(ax[c], 16);
            ax[c] += __shfl_xor(ax[c], 32);
            ah[c] += __shfl_xor(ah[c], 16);
            ah[c] += __shfl_xor(ah[c], 32);
        }
        if (g == 0) {
            const float inv = 1.0f / fmaxf((float)(s1 - s0), 1.0f);
            u16x4 ox, oh;
#pragma unroll
            for (int c = 0; c < 4; ++c) {
                ox[c] = (unsigned short)bf16rn(ax[c] * inv);
                oh[c] = (unsigned short)bf16rn(ah[c] * inv);
            }
            *(u16x4*)(mx + (long)n * DF + k4) = ox;
            *(u16x4*)(mh + (long)n * DF + k4) = oh;
        }
    }
}

#define MFMA(a, b, c) __builtin_amdgcn_mfma_f32_16x16x32_bf16((a), (b), (c), 0, 0, 0)

#define LOAD_W(Wl, Wr, col, g, wlh, wll, wrh, wrl)          \
    do {                                                    \
        _Pragma("unroll")                                   \
        for (int q = 0; q < 2; ++q) {                       \
            f32x4 tl0, tl1, tr0, tr1;                       \
            _Pragma("unroll")                               \
            for (int b = 0; b < 4; ++b) {                   \
                int k = 32 * q + 8 * (g) + b;               \
                tl0[b] = (Wl)[k * DF + (col)];              \
                tr0[b] = (Wr)[k * DF + (col)];              \
                tl1[b] = (Wl)[(k + 4) * DF + (col)];        \
                tr1[b] = (Wr)[(k + 4) * DF + (col)];        \
            }                                               \
            split8(tl0, tl1, wlh[q], wll[q]);               \
            split8(tr0, tr1, wrh[q], wrl[q]);               \
        }                                                   \
    } while (0)

// ---------------- dense1 @ NM: hm16 = bf16(relu(mean16 @ Wl + xm16 @ Wr + b)) --------
// all-bf16 operands: direct fragment loads, no LDS, no barrier.
__global__ __launch_bounds__(256) void dense1nm_k(const unsigned short* __restrict__ mean16,
                                                  const unsigned short* __restrict__ xm16,
                                                  const float* __restrict__ Wl,
                                                  const float* __restrict__ Wr,
                                                  const float* __restrict__ bias,
                                                  unsigned short* __restrict__ h16,
                                                  int n_nodes) {
    const int wglobal = (blockIdx.x * blockDim.x + threadIdx.x) >> 6;
    const int lane = threadIdx.x & 63;
    const int nwaves = (gridDim.x * blockDim.x) >> 6;
    const int ct = wglobal & 3;
    const int col = ct * 16 + (lane & 15);
    const int g = lane >> 4;

    bf16x8 wlh[2], wll[2], wrh[2], wrl[2];
    LOAD_W(Wl, Wr, col, g, wlh, wll, wrh, wrl);
    const float bv = bias[col];

    const int nrt = n_nodes >> 4;
    for (int rt = wglobal >> 2; rt < nrt; rt += nwaves >> 2) {
        const long rowA = (long)rt * 16 + (lane & 15);
        const bf16x8 m0 = *(const bf16x8*)(mean16 + rowA * DF + 8 * g);
        const bf16x8 m1 = *(const bf16x8*)(mean16 + rowA * DF + 32 + 8 * g);
        const bf16x8 x0 = *(const bf16x8*)(xm16 + rowA * DF + 8 * g);
        const bf16x8 x1 = *(const bf16x8*)(xm16 + rowA * DF + 32 + 8 * g);
        f32x4 acc = {0.f, 0.f, 0.f, 0.f};
        acc = MFMA(m0, wlh[0], acc);
        acc = MFMA(m0, wll[0], acc);
        acc = MFMA(m1, wlh[1], acc);
        acc = MFMA(m1, wll[1], acc);
        acc = MFMA(x0, wrh[0], acc);
        acc = MFMA(x0, wrl[0], acc);
        acc = MFMA(x1, wrh[1], acc);
        acc = MFMA(x1, wrl[1], acc);
#pragma unroll
        for (int r = 0; r < 4; ++r)
            h16[((long)rt * 16 + 4 * g + r) * DF + col] =
                (unsigned short)bf16rn(fmaxf(acc[r] + bv, 0.0f));
    }
}

// ---------------- fused customer dense: layer1 + layer2 + final linear ----------------
// h_c lives only in a bf16 LDS tile; final-linear partials reduced through LDS and
// written with ONE coalesced float2 store per node (no global atomics).
__global__ __launch_bounds__(256) void densec_k(const unsigned short* __restrict__ meanx,
                                                const unsigned short* __restrict__ meanh,
                                                const unsigned short* __restrict__ xc,
                                                const float* __restrict__ Wl1,
                                                const float* __restrict__ Wr1,
                                                const float* __restrict__ b1,
                                                const float* __restrict__ Wl2,
                                                const float* __restrict__ Wr2,
                                                const float* __restrict__ b2,
                                                const float* __restrict__ Wlin,
                                                const float* __restrict__ blin,
                                                float* __restrict__ out, int n_nodes) {
    __shared__ unsigned short sH[16][72];
    __shared__ float sOut[4][16][2];
    const int t = threadIdx.x;
    const int lane = t & 63;
    const int wv = t >> 6;
    const int col = wv * 16 + (lane & 15);
    const int g = lane >> 4;

    bf16x8 w1lh[2], w1ll[2], w1rh[2], w1rl[2];
    LOAD_W(Wl1, Wr1, col, g, w1lh, w1ll, w1rh, w1rl);
    bf16x8 w2lh[2], w2ll[2], w2rh[2], w2rl[2];
    LOAD_W(Wl2, Wr2, col, g, w2lh, w2ll, w2rh, w2rl);
    const float bv1 = b1[col];
    const float bv2 = b2[col];
    const float wl0 = Wlin[col * 2 + 0];
    const float wl1s = Wlin[col * 2 + 1];
    const float bl0 = blin[0];
    const float bl1 = blin[1];

    const int nrt = n_nodes >> 4;
    for (int rt = blockIdx.x; rt < nrt; rt += gridDim.x) {
        const long rowA = (long)rt * 16 + (lane & 15);
        const bf16x8 mx0 = *(const bf16x8*)(meanx + rowA * DF + 8 * g);
        const bf16x8 mx1 = *(const bf16x8*)(meanx + rowA * DF + 32 + 8 * g);
        const bf16x8 mh0 = *(const bf16x8*)(meanh + rowA * DF + 8 * g);
        const bf16x8 mh1 = *(const bf16x8*)(meanh + rowA * DF + 32 + 8 * g);
        const bf16x8 xc0 = *(const bf16x8*)(xc + rowA * DF + 8 * g);
        const bf16x8 xc1 = *(const bf16x8*)(xc + rowA * DF + 32 + 8 * g);

        // ---- layer 1: h_c = relu(meanx @ Wl1 + x_c @ Wr1 + b1) ----
        f32x4 acc = {0.f, 0.f, 0.f, 0.f};
        acc = MFMA(mx0, w1lh[0], acc);
        acc = MFMA(mx0, w1ll[0], acc);
        acc = MFMA(mx1, w1lh[1], acc);
        acc = MFMA(mx1, w1ll[1], acc);
        acc = MFMA(xc0, w1rh[0], acc);
        acc = MFMA(xc0, w1rl[0], acc);
        acc = MFMA(xc1, w1rh[1], acc);
        acc = MFMA(xc1, w1rl[1], acc);
#pragma unroll
        for (int r = 0; r < 4; ++r)
            sH[4 * g + r][col] = (unsigned short)bf16rn(fmaxf(acc[r] + bv1, 0.0f));
        __syncthreads();

        // ---- layer 2: h2 = meanh @ Wl2 + h_c @ Wr2 + b2 ----
        const bf16x8 hc0 = *(const bf16x8*)&sH[lane & 15][8 * g];
        const bf16x8 hc1 = *(const bf16x8*)&sH[lane & 15][32 + 8 * g];
        f32x4 a2 = {0.f, 0.f, 0.f, 0.f};
        a2 = MFMA(mh0, w2lh[0], a2);
        a2 = MFMA(mh0, w2ll[0], a2);
        a2 = MFMA(mh1, w2lh[1], a2);
        a2 = MFMA(mh1, w2ll[1], a2);
        a2 = MFMA(hc0, w2rh[0], a2);
        a2 = MFMA(hc0, w2rl[0], a2);
        a2 = MFMA(hc1, w2rh[1], a2);
        a2 = MFMA(hc1, w2rl[1], a2);

        // ---- final linear: per-wave 16-col partial -> LDS -> cross-wave sum ----
#pragma unroll
        for (int r = 0; r < 4; ++r) {
            const float h2 = a2[r] + bv2;
            float p0 = h2 * wl0;
            float p1 = h2 * wl1s;
#pragma unroll
            for (int m = 1; m < 16; m <<= 1) {
                p0 += __shfl_xor(p0, m);
                p1 += __shfl_xor(p1, m);
            }
            if ((lane & 15) == 0) {
                sOut[wv][4 * g + r][0] = p0;
                sOut[wv][4 * g + r][1] = p1;
            }
        }
        __syncthreads();
        if (t < 16) {
            const long node = (long)rt * 16 + t;
            const float o0 = sOut[0][t][0] + sOut[1][t][0] + sOut[2][t][0] + sOut[3][t][0] + bl0;
            const float o1 = sOut[0][t][1] + sOut[1][t][1] + sOut[2][t][1] + sOut[3][t][1] + bl1;
            float2 o = {o0, o1};
            *(float2*)(out + node * 2) = o;
        }
        __syncthreads();
    }
}

extern "C" void kernel_launch(void* const* d_in, const int* in_sizes, int n_in,
                              void* d_out, int out_size, void* d_ws, size_t ws_size,
                              hipStream_t stream) {
    const float* x_c = (const float*)d_in[0];
    const float* x_m = (const float*)d_in[1];
    const int* cm_src = (const int*)d_in[2];
    const int* cm_dst = (const int*)d_in[3];
    const int* mc_src = (const int*)d_in[4];
    const int* mc_dst = (const int*)d_in[5];
    const float* Wl1_cm = (const float*)d_in[6];
    const float* Wr1_cm = (const float*)d_in[7];
    const float* b1_cm = (const float*)d_in[8];
    const float* Wl1_mc = (const float*)d_in[9];
    const float* Wr1_mc = (const float*)d_in[10];
    const float* b1_mc = (const float*)d_in[11];
    // layer-2 cm weights (d_in[12..14]) are dead: h2_m is unused in the reference
    const float* Wl2_mc = (const float*)d_in[15];
    const float* Wr2_mc = (const float*)d_in[16];
    const float* b2_mc = (const float*)d_in[17];
    const float* W_lin = (const float*)d_in[18];
    const float* b_lin = (const float*)d_in[19];
    float* out = (float*)d_out;

    // ---- workspace layout (~110 MB) ----
    unsigned short* up = (unsigned short*)d_ws;
    unsigned short* aggm16 = up;                        // NM*64
    unsigned short* hm16 = aggm16 + (long)NM * DF;      // NM*64
    unsigned short* xm16 = hm16 + (long)NM * DF;        // NM*64
    unsigned short* xc16 = xm16 + (long)NM * DF;        // NC*64
    unsigned short* meanx16 = xc16 + (long)NC * DF;     // NC*64
    unsigned short* meanh16 = meanx16 + (long)NC * DF;  // NC*64
    int* ip = (int*)(meanh16 + (long)NC * DF);

    int* binsM = ip;                  // NM (zeroed)
    int* binsC = binsM + NM;          // NC (zeroed)
    int* startM = binsC + NC;         // NM+1
    int* startC = startM + (NM + 1);  // NC+1
    int* ccurM = startC + (NC + 1);   // NBM
    int* ccurC = ccurM + NBM;         // NBC
    int* partM = ccurC + NBC;         // SCAN_B
    int* boffM = partM + SCAN_B;
    int* partC = boffM + SCAN_B;
    int* boffC = partC + SCAN_B;
    int* srt_cm = boffC + SCAN_B;     // NE
    int* srt_mc = srt_cm + NE;        // NE
    int* bkt = srt_mc + NE;           // NE (reused by both sorts, sequentially)

    // zero fine bins (out no longer needs zeroing: densec stores cover it fully)
    hipMemsetAsync(binsM, 0, (size_t)(NM + NC) * sizeof(int), stream);

    // fine histograms + prefix
    hist_k<<<2048, 256, 0, stream>>>(cm_dst, binsM, NE);
    hist_k<<<2048, 256, 0, stream>>>(mc_dst, binsC, NE);

    scan_part_k<<<SCAN_B, SCAN_T, 0, stream>>>(binsM, partM, NM);
    scan_mid_k<<<1, SCAN_B, 0, stream>>>(partM, boffM, startM, NM);
    scan_fin_k<<<SCAN_B, SCAN_T, 0, stream>>>(binsM, boffM, startM, NM);

    scan_part_k<<<SCAN_B, SCAN_T, 0, stream>>>(binsC, partC, NC);
    scan_mid_k<<<1, SCAN_B, 0, stream>>>(partC, boffC, startC, NC);
    scan_fin_k<<<SCAN_B, SCAN_T, 0, stream>>>(binsC, boffC, startC, NC);

    // two-level bucket sort (cm then mc; bkt buffer reused sequentially)
    const int nsb = (NE + CH - 1) / CH;   // 245
    cinit_k<<<1, 256, 0, stream>>>(startM, ccurM, NM, NBM);
    cinit_k<<<1, 256, 0, stream>>>(startC, ccurC, NC, NBC);
    bsort_k<<<nsb, 256, 0, stream>>>(cm_src, cm_dst, ccurM, bkt, NE, NBM);
    bp2_k<<<NBM, 256, 0, stream>>>(bkt, startM, srt_cm, NM);
    bsort_k<<<nsb, 256, 0, stream>>>(mc_src, mc_dst, ccurC, bkt, NE, NBC);
    bp2_k<<<NBC, 256, 0, stream>>>(bkt, startC, srt_mc, NC);

    // bf16 hi-planes for the gathers and dense operands
    presplit_k<<<2048, 256, 0, stream>>>(x_c, (u16x4*)xc16, NC * (DF / 4));
    presplit_k<<<2048, 256, 0, stream>>>(x_m, (u16x4*)xm16, NM * (DF / 4));

    // layer 1 @ merchants: m-mean (bf16) then dense -> hm16
    agg16_k<<<(NM + 3) / 4, 256, 0, stream>>>(xc16, startM, srt_cm, aggm16, NM);
    dense1nm_k<<<1024, 256, 0, stream>>>(aggm16, xm16, Wl1_cm, Wr1_cm, b1_cm, hm16, NM);

    // customers: fused dual aggregation (x_m-mean + h_m-mean in one edge sweep)
    aggc2_k<<<(NC + 3) / 4, 256, 0, stream>>>(xm16, hm16, startC, srt_mc,
                                              meanx16, meanh16, NC);

    // customers: fused layer1 + layer2 + final linear (h_c never hits HBM, no atomics)
    densec_k<<<2048, 256, 0, stream>>>(meanx16, meanh16, xc16,
                                       Wl1_mc, Wr1_mc, b1_mc,
                                       Wl2_mc, Wr2_mc, b2_mc,
                                       W_lin, b_lin, out, NC);
}

// Round 12
// 318.108 us; speedup vs baseline: 2.8470x; 1.2240x over previous
//
#include <hip/hip_runtime.h>

#define NC 200000
#define NM 50000
#define NE 1000000
#define DF 64   // feature dim (D == H == 64)

#define SCAN_B 512
#define SCAN_T 256

#define BSH 10
#define BW 1024
#define NBM ((NM + BW - 1) >> BSH)   // 49
#define NBC ((NC + BW - 1) >> BSH)   // 196
#define CH 4096                      // edges per bsort block

typedef __attribute__((ext_vector_type(8))) short bf16x8;
typedef __attribute__((ext_vector_type(4))) float f32x4;
typedef __attribute__((ext_vector_type(4))) unsigned short u16x4;

// ---------------- merged histogram: both edge types in one launch ----------------
__global__ __launch_bounds__(256) void hist2_k(const int* __restrict__ cm_dst,
                                               const int* __restrict__ mc_dst,
                                               int* __restrict__ binsM,
                                               int* __restrict__ binsC) {
    int tid = blockIdx.x * blockDim.x + threadIdx.x;
    const int st = gridDim.x * blockDim.x;
    for (int e = tid; e < 2 * NE; e += st) {
        if (e < NE) atomicAdd(&binsM[cm_dst[e]], 1);
        else        atomicAdd(&binsC[mc_dst[e - NE]], 1);
    }
}

// ---------------- merged 3-phase device-wide exclusive scan (both arrays) ----------
__global__ __launch_bounds__(SCAN_T) void scan_part2_k(const int* __restrict__ binsM,
                                                       const int* __restrict__ binsC,
                                                       int* __restrict__ partM,
                                                       int* __restrict__ partC) {
    __shared__ int red[SCAN_T];
    const int side = (blockIdx.x >= SCAN_B);
    const int blk = blockIdx.x - side * SCAN_B;
    const int* bins = side ? binsC : binsM;
    int* partials = side ? partC : partM;
    const int n = side ? NC : NM;
    const int ch = (n + SCAN_B * SCAN_T - 1) / (SCAN_B * SCAN_T);
    const int t = threadIdx.x;
    const long base = ((long)blk * SCAN_T + t) * ch;
    int s = 0;
    for (int i = 0; i < ch; ++i) {
        long idx = base + i;
        if (idx < n) s += bins[idx];
    }
    red[t] = s;
    __syncthreads();
    for (int off = SCAN_T / 2; off > 0; off >>= 1) {
        if (t < off) red[t] += red[t + off];
        __syncthreads();
    }
    if (t == 0) partials[blk] = red[0];
}

__global__ __launch_bounds__(SCAN_B) void scan_mid2_k(const int* __restrict__ partM,
                                                      const int* __restrict__ partC,
                                                      int* __restrict__ boffM,
                                                      int* __restrict__ boffC,
                                                      int* __restrict__ startM,
                                                      int* __restrict__ startC) {
    __shared__ int s[SCAN_B];
    const int side = blockIdx.x;
    const int* partials = side ? partC : partM;
    int* boff = side ? boffC : boffM;
    int* start = side ? startC : startM;
    const int n = side ? NC : NM;
    const int t = threadIdx.x;
    s[t] = partials[t];
    __syncthreads();
    for (int off = 1; off < SCAN_B; off <<= 1) {
        int v = 0;
        if (t >= off) v = s[t - off];
        __syncthreads();
        if (t >= off) s[t] += v;
        __syncthreads();
    }
    boff[t] = (t == 0) ? 0 : s[t - 1];
    if (t == SCAN_B - 1) start[n] = s[t];
}

__global__ __launch_bounds__(SCAN_T) void scan_fin2_k(const int* __restrict__ binsM,
                                                      const int* __restrict__ binsC,
                                                      const int* __restrict__ boffM,
                                                      const int* __restrict__ boffC,
                                                      int* __restrict__ startM,
                                                      int* __restrict__ startC) {
    __shared__ int red[SCAN_T];
    const int side = (blockIdx.x >= SCAN_B);
    const int blk = blockIdx.x - side * SCAN_B;
    const int* bins = side ? binsC : binsM;
    const int* boff = side ? boffC : boffM;
    int* start = side ? startC : startM;
    const int n = side ? NC : NM;
    const int ch = (n + SCAN_B * SCAN_T - 1) / (SCAN_B * SCAN_T);
    const int t = threadIdx.x;
    const long base = ((long)blk * SCAN_T + t) * ch;
    int s = 0;
    for (int i = 0; i < ch; ++i) {
        long idx = base + i;
        if (idx < n) s += bins[idx];
    }
    red[t] = s;
    __syncthreads();
    for (int off = 1; off < SCAN_T; off <<= 1) {
        int v = 0;
        if (t >= off) v = red[t - off];
        __syncthreads();
        if (t >= off) red[t] += v;
        __syncthreads();
    }
    int run = boff[blk] + ((t == 0) ? 0 : red[t - 1]);
    for (int i = 0; i < ch; ++i) {
        long idx = base + i;
        if (idx < n) {
            start[idx] = run;
            run += bins[idx];
        }
    }
}

// ---------------- merged coarse cursor init ----------------
__global__ __launch_bounds__(256) void cinit2_k(const int* __restrict__ startM,
                                                const int* __restrict__ startC,
                                                int* __restrict__ ccurM,
                                                int* __restrict__ ccurC) {
    const int t = threadIdx.x;
    if (t < NBM) ccurM[t] = startM[min(t << BSH, NM)];
    if (t < NBC) ccurC[t] = startC[min(t << BSH, NC)];
}

// ---------------- merged bucket sort pass 1 (both edge lists) ----------------
__global__ __launch_bounds__(256) void bsort2_k(const int* __restrict__ cm_src,
                                                const int* __restrict__ cm_dst,
                                                const int* __restrict__ mc_src,
                                                const int* __restrict__ mc_dst,
                                                int* __restrict__ ccurM,
                                                int* __restrict__ ccurC,
                                                int* __restrict__ bktM,
                                                int* __restrict__ bktC, int nsb) {
    __shared__ int cnt[256], pfx[256], gbase[256];
    __shared__ int stage[CH];
    const int side = (blockIdx.x >= nsb);
    const int blk = blockIdx.x - side * nsb;
    const int* src = side ? mc_src : cm_src;
    const int* dst = side ? mc_dst : cm_dst;
    int* ccur = side ? ccurC : ccurM;
    int* bkt = side ? bktC : bktM;
    const int nb = side ? NBC : NBM;

    const int t = threadIdx.x;
    const int e0 = blk * CH;
    const int n = min(CH, NE - e0);
    cnt[t] = 0;
    __syncthreads();
    for (int i = t; i < n; i += 256) atomicAdd(&cnt[dst[e0 + i] >> BSH], 1);
    __syncthreads();
    const int myc = (t < nb) ? cnt[t] : 0;
    pfx[t] = myc;
    __syncthreads();
    for (int off = 1; off < 256; off <<= 1) {
        int add = (t >= off) ? pfx[t - off] : 0;
        __syncthreads();
        pfx[t] += add;
        __syncthreads();
    }
    const int excl = pfx[t] - myc;
    if (t < nb && myc > 0) gbase[t] = atomicAdd(&ccur[t], myc);
    pfx[t] = excl;
    cnt[t] = 0;
    __syncthreads();
    for (int i = t; i < n; i += 256) {
        const int d = dst[e0 + i];
        const int b = d >> BSH;
        const int p = pfx[b] + atomicAdd(&cnt[b], 1);
        stage[p] = (src[e0 + i] << BSH) | (d & (BW - 1));
    }
    __syncthreads();
    const int wv = t >> 6, ln = t & 63;
    for (int b = wv; b < nb; b += 4) {
        const int c = cnt[b];
        if (c == 0) continue;
        const int gb = gbase[b], lo = pfx[b];
        for (int j = ln; j < c; j += 64) bkt[gb + j] = stage[lo + j];
    }
}

// ---------------- merged bucket sort pass 2 ----------------
__global__ __launch_bounds__(256) void bp22_k(const int* __restrict__ bktM,
                                              const int* __restrict__ startM,
                                              int* __restrict__ srtM,
                                              const int* __restrict__ bktC,
                                              const int* __restrict__ startC,
                                              int* __restrict__ srtC) {
    __shared__ int lcur[BW];
    const int side = (blockIdx.x >= NBM);
    const int blk = blockIdx.x - side * NBM;
    const int* bkt = side ? bktC : bktM;
    const int* start = side ? startC : startM;
    int* srt = side ? srtC : srtM;
    const int n_nodes = side ? NC : NM;

    const int base = blk << BSH;
    for (int i = threadIdx.x; i < BW; i += 256) lcur[i] = 0;
    __syncthreads();
    const int e0 = start[base];
    const int e1 = start[min(base + BW, n_nodes)];
    for (int e = e0 + threadIdx.x; e < e1; e += 256) {
        const int p = bkt[e];
        const int dl = p & (BW - 1);
        const int pos = start[base + dl] + atomicAdd(&lcur[dl], 1);
        srt[pos] = p >> BSH;
    }
}

// ---------------- round-to-nearest bf16 helpers ----------------
__device__ __forceinline__ short bf16rn(float x) {
    unsigned u = __builtin_bit_cast(unsigned, x);
    unsigned r = u + 0x7FFFu + ((u >> 16) & 1u);
    return (short)(r >> 16);
}
__device__ __forceinline__ float bf16f(short h) {
    unsigned u = ((unsigned)(unsigned short)h) << 16;
    return __builtin_bit_cast(float, u);
}
__device__ __forceinline__ void split8(const f32x4 u, const f32x4 v,
                                       bf16x8& hi, bf16x8& lo) {
#pragma unroll
    for (int b = 0; b < 4; ++b) {
        short h = bf16rn(u[b]);
        hi[b] = h;
        lo[b] = bf16rn(u[b] - bf16f(h));
    }
#pragma unroll
    for (int b = 0; b < 4; ++b) {
        short h = bf16rn(v[b]);
        hi[4 + b] = h;
        lo[4 + b] = bf16rn(v[b] - bf16f(h));
    }
}

// ---------------- merged presplit: both feature arrays -> bf16 hi-planes ----------
__global__ __launch_bounds__(256) void presplit2_k(const float* __restrict__ x_c,
                                                   const float* __restrict__ x_m,
                                                   u16x4* __restrict__ xc16,
                                                   u16x4* __restrict__ xm16) {
    const int NC4 = NC * (DF / 4);
    const int NT4 = (NC + NM) * (DF / 4);
    int i = blockIdx.x * blockDim.x + threadIdx.x;
    const int st = gridDim.x * blockDim.x;
    for (; i < NT4; i += st) {
        const bool mc = (i < NC4);
        const int j = mc ? i : i - NC4;
        const f32x4 v = mc ? ((const f32x4*)x_c)[j] : ((const f32x4*)x_m)[j];
        u16x4 o;
#pragma unroll
        for (int b = 0; b < 4; ++b) o[b] = (unsigned short)bf16rn(v[b]);
        if (mc) xc16[j] = o;
        else    xm16[j] = o;
    }
}

// ---------------- single-plane aggregation: 16-lane subgroup per node ----------------
// lane owns 4 features; serial edge loop (4-way unrolled); no cross-lane reduce.
__global__ __launch_bounds__(256) void agg16_k(const unsigned short* __restrict__ xhi,
                                               const int* __restrict__ start,
                                               const int* __restrict__ srt,
                                               unsigned short* __restrict__ mean16,
                                               int n_nodes) {
    const int sgid = (blockIdx.x * blockDim.x + threadIdx.x) >> 4;
    const int nsg = (gridDim.x * blockDim.x) >> 4;
    const int k4 = (threadIdx.x & 15) * 4;
    for (int n = sgid; n < n_nodes; n += nsg) {
        const int s0 = start[n], s1 = start[n + 1];
        f32x4 a0 = {0.f, 0.f, 0.f, 0.f}, a1 = {0.f, 0.f, 0.f, 0.f};
        f32x4 a2 = {0.f, 0.f, 0.f, 0.f}, a3 = {0.f, 0.f, 0.f, 0.f};
        int e = s0;
        for (; e + 3 < s1; e += 4) {
            const int i0 = srt[e + 0], i1 = srt[e + 1];
            const int i2 = srt[e + 2], i3 = srt[e + 3];
            const u16x4 v0 = *(const u16x4*)(xhi + (long)i0 * DF + k4);
            const u16x4 v1 = *(const u16x4*)(xhi + (long)i1 * DF + k4);
            const u16x4 v2 = *(const u16x4*)(xhi + (long)i2 * DF + k4);
            const u16x4 v3 = *(const u16x4*)(xhi + (long)i3 * DF + k4);
#pragma unroll
            for (int c = 0; c < 4; ++c) {
                a0[c] += bf16f((short)v0[c]);
                a1[c] += bf16f((short)v1[c]);
                a2[c] += bf16f((short)v2[c]);
                a3[c] += bf16f((short)v3[c]);
            }
        }
        for (; e < s1; ++e) {
            const int i0 = srt[e];
            const u16x4 v0 = *(const u16x4*)(xhi + (long)i0 * DF + k4);
#pragma unroll
            for (int c = 0; c < 4; ++c) a0[c] += bf16f((short)v0[c]);
        }
        const float inv = 1.0f / fmaxf((float)(s1 - s0), 1.0f);
        u16x4 o;
#pragma unroll
        for (int c = 0; c < 4; ++c)
            o[c] = (unsigned short)bf16rn(((a0[c] + a1[c]) + (a2[c] + a3[c])) * inv);
        *(u16x4*)(mean16 + (long)n * DF + k4) = o;
    }
}

// ---------------- dual-plane aggregation: 16-lane subgroup per node ----------------
__global__ __launch_bounds__(256) void aggc2_k(const unsigned short* __restrict__ xp,
                                               const unsigned short* __restrict__ hp,
                                               const int* __restrict__ start,
                                               const int* __restrict__ srt,
                                               unsigned short* __restrict__ mx,
                                               unsigned short* __restrict__ mh, int n_nodes) {
    const int sgid = (blockIdx.x * blockDim.x + threadIdx.x) >> 4;
    const int nsg = (gridDim.x * blockDim.x) >> 4;
    const int k4 = (threadIdx.x & 15) * 4;
    for (int n = sgid; n < n_nodes; n += nsg) {
        const int s0 = start[n], s1 = start[n + 1];
        f32x4 ax0 = {0.f, 0.f, 0.f, 0.f}, ah0 = {0.f, 0.f, 0.f, 0.f};
        f32x4 ax1 = {0.f, 0.f, 0.f, 0.f}, ah1 = {0.f, 0.f, 0.f, 0.f};
        int e = s0;
        for (; e + 1 < s1; e += 2) {
            const int iA = srt[e], iB = srt[e + 1];
            const u16x4 vxA = *(const u16x4*)(xp + (long)iA * DF + k4);
            const u16x4 vhA = *(const u16x4*)(hp + (long)iA * DF + k4);
            const u16x4 vxB = *(const u16x4*)(xp + (long)iB * DF + k4);
            const u16x4 vhB = *(const u16x4*)(hp + (long)iB * DF + k4);
#pragma unroll
            for (int c = 0; c < 4; ++c) {
                ax0[c] += bf16f((short)vxA[c]);
                ah0[c] += bf16f((short)vhA[c]);
                ax1[c] += bf16f((short)vxB[c]);
                ah1[c] += bf16f((short)vhB[c]);
            }
        }
        if (e < s1) {
            const int iA = srt[e];
            const u16x4 vxA = *(const u16x4*)(xp + (long)iA * DF + k4);
            const u16x4 vhA = *(const u16x4*)(hp + (long)iA * DF + k4);
#pragma unroll
            for (int c = 0; c < 4; ++c) {
                ax0[c] += bf16f((short)vxA[c]);
                ah0[c] += bf16f((short)vhA[c]);
            }
        }
        const float inv = 1.0f / fmaxf((float)(s1 - s0), 1.0f);
        u16x4 ox, oh;
#pragma unroll
        for (int c = 0; c < 4; ++c) {
            ox[c] = (unsigned short)bf16rn((ax0[c] + ax1[c]) * inv);
            oh[c] = (unsigned short)bf16rn((ah0[c] + ah1[c]) * inv);
        }
        *(u16x4*)(mx + (long)n * DF + k4) = ox;
        *(u16x4*)(mh + (long)n * DF + k4) = oh;
    }
}

#define MFMA(a, b, c) __builtin_amdgcn_mfma_f32_16x16x32_bf16((a), (b), (c), 0, 0, 0)

#define LOAD_W(Wl, Wr, col, g, wlh, wll, wrh, wrl)          \
    do {                                                    \
        _Pragma("unroll")                                   \
        for (int q = 0; q < 2; ++q) {                       \
            f32x4 tl0, tl1, tr0, tr1;                       \
            _Pragma("unroll")                               \
            for (int b = 0; b < 4; ++b) {                   \
                int k = 32 * q + 8 * (g) + b;               \
                tl0[b] = (Wl)[k * DF + (col)];              \
                tr0[b] = (Wr)[k * DF + (col)];              \
                tl1[b] = (Wl)[(k + 4) * DF + (col)];        \
                tr1[b] = (Wr)[(k + 4) * DF + (col)];        \
            }                                               \
            split8(tl0, tl1, wlh[q], wll[q]);               \
            split8(tr0, tr1, wrh[q], wrl[q]);               \
        }                                                   \
    } while (0)

// ---------------- dense1 @ NM: hm16 = bf16(relu(mean16 @ Wl + xm16 @ Wr + b)) --------
__global__ __launch_bounds__(256) void dense1nm_k(const unsigned short* __restrict__ mean16,
                                                  const unsigned short* __restrict__ xm16,
                                                  const float* __restrict__ Wl,
                                                  const float* __restrict__ Wr,
                                                  const float* __restrict__ bias,
                                                  unsigned short* __restrict__ h16,
                                                  int n_nodes) {
    const int wglobal = (blockIdx.x * blockDim.x + threadIdx.x) >> 6;
    const int lane = threadIdx.x & 63;
    const int nwaves = (gridDim.x * blockDim.x) >> 6;
    const int ct = wglobal & 3;
    const int col = ct * 16 + (lane & 15);
    const int g = lane >> 4;

    bf16x8 wlh[2], wll[2], wrh[2], wrl[2];
    LOAD_W(Wl, Wr, col, g, wlh, wll, wrh, wrl);
    const float bv = bias[col];

    const int nrt = n_nodes >> 4;
    for (int rt = wglobal >> 2; rt < nrt; rt += nwaves >> 2) {
        const long rowA = (long)rt * 16 + (lane & 15);
        const bf16x8 m0 = *(const bf16x8*)(mean16 + rowA * DF + 8 * g);
        const bf16x8 m1 = *(const bf16x8*)(mean16 + rowA * DF + 32 + 8 * g);
        const bf16x8 x0 = *(const bf16x8*)(xm16 + rowA * DF + 8 * g);
        const bf16x8 x1 = *(const bf16x8*)(xm16 + rowA * DF + 32 + 8 * g);
        f32x4 acc = {0.f, 0.f, 0.f, 0.f};
        acc = MFMA(m0, wlh[0], acc);
        acc = MFMA(m0, wll[0], acc);
        acc = MFMA(m1, wlh[1], acc);
        acc = MFMA(m1, wll[1], acc);
        acc = MFMA(x0, wrh[0], acc);
        acc = MFMA(x0, wrl[0], acc);
        acc = MFMA(x1, wrh[1], acc);
        acc = MFMA(x1, wrl[1], acc);
#pragma unroll
        for (int r = 0; r < 4; ++r)
            h16[((long)rt * 16 + 4 * g + r) * DF + col] =
                (unsigned short)bf16rn(fmaxf(acc[r] + bv, 0.0f));
    }
}

// ---------------- fused customer dense: layer1 + layer2 + final linear ----------------
__global__ __launch_bounds__(256) void densec_k(const unsigned short* __restrict__ meanx,
                                                const unsigned short* __restrict__ meanh,
                                                const unsigned short* __restrict__ xc,
                                                const float* __restrict__ Wl1,
                                                const float* __restrict__ Wr1,
                                                const float* __restrict__ b1,
                                                const float* __restrict__ Wl2,
                                                const float* __restrict__ Wr2,
                                                const float* __restrict__ b2,
                                                const float* __restrict__ Wlin,
                                                const float* __restrict__ blin,
                                                float* __restrict__ out, int n_nodes) {
    __shared__ unsigned short sH[16][72];
    __shared__ float sOut[4][16][2];
    const int t = threadIdx.x;
    const int lane = t & 63;
    const int wv = t >> 6;
    const int col = wv * 16 + (lane & 15);
    const int g = lane >> 4;

    bf16x8 w1lh[2], w1ll[2], w1rh[2], w1rl[2];
    LOAD_W(Wl1, Wr1, col, g, w1lh, w1ll, w1rh, w1rl);
    bf16x8 w2lh[2], w2ll[2], w2rh[2], w2rl[2];
    LOAD_W(Wl2, Wr2, col, g, w2lh, w2ll, w2rh, w2rl);
    const float bv1 = b1[col];
    const float bv2 = b2[col];
    const float wl0 = Wlin[col * 2 + 0];
    const float wl1s = Wlin[col * 2 + 1];
    const float bl0 = blin[0];
    const float bl1 = blin[1];

    const int nrt = n_nodes >> 4;
    for (int rt = blockIdx.x; rt < nrt; rt += gridDim.x) {
        const long rowA = (long)rt * 16 + (lane & 15);
        const bf16x8 mx0 = *(const bf16x8*)(meanx + rowA * DF + 8 * g);
        const bf16x8 mx1 = *(const bf16x8*)(meanx + rowA * DF + 32 + 8 * g);
        const bf16x8 mh0 = *(const bf16x8*)(meanh + rowA * DF + 8 * g);
        const bf16x8 mh1 = *(const bf16x8*)(meanh + rowA * DF + 32 + 8 * g);
        const bf16x8 xc0 = *(const bf16x8*)(xc + rowA * DF + 8 * g);
        const bf16x8 xc1 = *(const bf16x8*)(xc + rowA * DF + 32 + 8 * g);

        // ---- layer 1: h_c = relu(meanx @ Wl1 + x_c @ Wr1 + b1) ----
        f32x4 acc = {0.f, 0.f, 0.f, 0.f};
        acc = MFMA(mx0, w1lh[0], acc);
        acc = MFMA(mx0, w1ll[0], acc);
        acc = MFMA(mx1, w1lh[1], acc);
        acc = MFMA(mx1, w1ll[1], acc);
        acc = MFMA(xc0, w1rh[0], acc);
        acc = MFMA(xc0, w1rl[0], acc);
        acc = MFMA(xc1, w1rh[1], acc);
        acc = MFMA(xc1, w1rl[1], acc);
#pragma unroll
        for (int r = 0; r < 4; ++r)
            sH[4 * g + r][col] = (unsigned short)bf16rn(fmaxf(acc[r] + bv1, 0.0f));
        __syncthreads();

        // ---- layer 2: h2 = meanh @ Wl2 + h_c @ Wr2 + b2 ----
        const bf16x8 hc0 = *(const bf16x8*)&sH[lane & 15][8 * g];
        const bf16x8 hc1 = *(const bf16x8*)&sH[lane & 15][32 + 8 * g];
        f32x4 a2 = {0.f, 0.f, 0.f, 0.f};
        a2 = MFMA(mh0, w2lh[0], a2);
        a2 = MFMA(mh0, w2ll[0], a2);
        a2 = MFMA(mh1, w2lh[1], a2);
        a2 = MFMA(mh1, w2ll[1], a2);
        a2 = MFMA(hc0, w2rh[0], a2);
        a2 = MFMA(hc0, w2rl[0], a2);
        a2 = MFMA(hc1, w2rh[1], a2);
        a2 = MFMA(hc1, w2rl[1], a2);

        // ---- final linear: per-wave partials -> LDS -> one float2 store per node ----
#pragma unroll
        for (int r = 0; r < 4; ++r) {
            const float h2 = a2[r] + bv2;
            float p0 = h2 * wl0;
            float p1 = h2 * wl1s;
#pragma unroll
            for (int m = 1; m < 16; m <<= 1) {
                p0 += __shfl_xor(p0, m);
                p1 += __shfl_xor(p1, m);
            }
            if ((lane & 15) == 0) {
                sOut[wv][4 * g + r][0] = p0;
                sOut[wv][4 * g + r][1] = p1;
            }
        }
        __syncthreads();
        if (t < 16) {
            const long node = (long)rt * 16 + t;
            const float o0 = sOut[0][t][0] + sOut[1][t][0] + sOut[2][t][0] + sOut[3][t][0] + bl0;
            const float o1 = sOut[0][t][1] + sOut[1][t][1] + sOut[2][t][1] + sOut[3][t][1] + bl1;
            float2 o = {o0, o1};
            *(float2*)(out + node * 2) = o;
        }
        __syncthreads();
    }
}

extern "C" void kernel_launch(void* const* d_in, const int* in_sizes, int n_in,
                              void* d_out, int out_size, void* d_ws, size_t ws_size,
                              hipStream_t stream) {
    const float* x_c = (const float*)d_in[0];
    const float* x_m = (const float*)d_in[1];
    const int* cm_src = (const int*)d_in[2];
    const int* cm_dst = (const int*)d_in[3];
    const int* mc_src = (const int*)d_in[4];
    const int* mc_dst = (const int*)d_in[5];
    const float* Wl1_cm = (const float*)d_in[6];
    const float* Wr1_cm = (const float*)d_in[7];
    const float* b1_cm = (const float*)d_in[8];
    const float* Wl1_mc = (const float*)d_in[9];
    const float* Wr1_mc = (const float*)d_in[10];
    const float* b1_mc = (const float*)d_in[11];
    // layer-2 cm weights (d_in[12..14]) are dead: h2_m is unused in the reference
    const float* Wl2_mc = (const float*)d_in[15];
    const float* Wr2_mc = (const float*)d_in[16];
    const float* b2_mc = (const float*)d_in[17];
    const float* W_lin = (const float*)d_in[18];
    const float* b_lin = (const float*)d_in[19];
    float* out = (float*)d_out;

    // ---- workspace layout (~117 MB) ----
    unsigned short* up = (unsigned short*)d_ws;
    unsigned short* aggm16 = up;                        // NM*64
    unsigned short* hm16 = aggm16 + (long)NM * DF;      // NM*64
    unsigned short* xm16 = hm16 + (long)NM * DF;        // NM*64
    unsigned short* xc16 = xm16 + (long)NM * DF;        // NC*64
    unsigned short* meanx16 = xc16 + (long)NC * DF;     // NC*64
    unsigned short* meanh16 = meanx16 + (long)NC * DF;  // NC*64
    int* ip = (int*)(meanh16 + (long)NC * DF);

    int* binsM = ip;                  // NM (zeroed)
    int* binsC = binsM + NM;          // NC (zeroed)
    int* startM = binsC + NC;         // NM+1
    int* startC = startM + (NM + 1);  // NC+1
    int* ccurM = startC + (NC + 1);   // NBM
    int* ccurC = ccurM + NBM;         // NBC
    int* partM = ccurC + NBC;         // SCAN_B
    int* boffM = partM + SCAN_B;
    int* partC = boffM + SCAN_B;
    int* boffC = partC + SCAN_B;
    int* srt_cm = boffC + SCAN_B;     // NE
    int* srt_mc = srt_cm + NE;        // NE
    int* bktM = srt_mc + NE;          // NE
    int* bktC = bktM + NE;            // NE

    // zero fine bins
    hipMemsetAsync(binsM, 0, (size_t)(NM + NC) * sizeof(int), stream);

    // merged histogram + merged scans
    hist2_k<<<2048, 256, 0, stream>>>(cm_dst, mc_dst, binsM, binsC);
    scan_part2_k<<<2 * SCAN_B, SCAN_T, 0, stream>>>(binsM, binsC, partM, partC);
    scan_mid2_k<<<2, SCAN_B, 0, stream>>>(partM, partC, boffM, boffC, startM, startC);
    scan_fin2_k<<<2 * SCAN_B, SCAN_T, 0, stream>>>(binsM, binsC, boffM, boffC, startM, startC);

    // merged two-level bucket sort
    const int nsb = (NE + CH - 1) / CH;   // 245
    cinit2_k<<<1, 256, 0, stream>>>(startM, startC, ccurM, ccurC);
    bsort2_k<<<2 * nsb, 256, 0, stream>>>(cm_src, cm_dst, mc_src, mc_dst,
                                          ccurM, ccurC, bktM, bktC, nsb);
    bp22_k<<<NBM + NBC, 256, 0, stream>>>(bktM, startM, srt_cm, bktC, startC, srt_mc);

    // merged bf16 presplit
    presplit2_k<<<2048, 256, 0, stream>>>(x_c, x_m, (u16x4*)xc16, (u16x4*)xm16);

    // layer 1 @ merchants: m-mean (bf16) then dense -> hm16
    agg16_k<<<NM / 16, 256, 0, stream>>>(xc16, startM, srt_cm, aggm16, NM);
    dense1nm_k<<<1024, 256, 0, stream>>>(aggm16, xm16, Wl1_cm, Wr1_cm, b1_cm, hm16, NM);

    // customers: fused dual aggregation (x_m-mean + h_m-mean in one edge sweep)
    aggc2_k<<<NC / 16, 256, 0, stream>>>(xm16, hm16, startC, srt_mc,
                                         meanx16, meanh16, NC);

    // customers: fused layer1 + layer2 + final linear
    densec_k<<<2048, 256, 0, stream>>>(meanx16, meanh16, xc16,
                                       Wl1_mc, Wr1_mc, b1_mc,
                                       Wl2_mc, Wr2_mc, b2_mc,
                                       W_lin, b_lin, out, NC);
}

// Round 13
// 271.486 us; speedup vs baseline: 3.3359x; 1.1717x over previous
//
#include <hip/hip_runtime.h>

#define NC 200000
#define NM 50000
#define NE 1000000
#define DF 64   // feature dim (D == H == 64)

#define BSH 10
#define BW 1024
#define NBM ((NM + BW - 1) >> BSH)   // 49
#define NBC ((NC + BW - 1) >> BSH)   // 196
#define CH 4096                      // edges per chunk block
#define NSB ((NE + CH - 1) / CH)     // 245

typedef __attribute__((ext_vector_type(8))) short bf16x8;
typedef __attribute__((ext_vector_type(4))) float f32x4;
typedef __attribute__((ext_vector_type(4))) unsigned short u16x4;

// ---------------- coarse histogram: per-block LDS hist -> partial array (NO atomics) ----
__global__ __launch_bounds__(256) void chist2_k(const int* __restrict__ cm_dst,
                                                const int* __restrict__ mc_dst,
                                                int* __restrict__ pmM,
                                                int* __restrict__ pmC) {
    __shared__ int cnt[256];
    const int side = (blockIdx.x >= NSB);
    const int blk = blockIdx.x - side * NSB;
    const int* dst = side ? mc_dst : cm_dst;
    int* pm = side ? pmC : pmM;
    const int nb = side ? NBC : NBM;
    const int t = threadIdx.x;
    cnt[t] = 0;
    __syncthreads();
    const int e0 = blk * CH;
    const int n = min(CH, NE - e0);
    for (int i = t; i < n; i += 256) atomicAdd(&cnt[dst[e0 + i] >> BSH], 1);
    __syncthreads();
    if (t < nb) pm[(long)blk * nb + t] = cnt[t];
}

// ---------------- coarse reduce+scan (one tiny block): cstart + ccur init ----------
__global__ __launch_bounds__(256) void cscan2_k(const int* __restrict__ pmM,
                                                const int* __restrict__ pmC,
                                                int* __restrict__ cstartM,
                                                int* __restrict__ cstartC,
                                                int* __restrict__ ccurM,
                                                int* __restrict__ ccurC) {
    __shared__ int tot[256];
    const int t = threadIdx.x;
    // ---- cm side (NBM buckets) ----
    int s = 0;
    if (t < NBM)
        for (int b = 0; b < NSB; ++b) s += pmM[(long)b * NBM + t];
    tot[t] = s;
    __syncthreads();
    for (int off = 1; off < 256; off <<= 1) {
        int v = (t >= off) ? tot[t - off] : 0;
        __syncthreads();
        tot[t] += v;
        __syncthreads();
    }
    if (t < NBM) {
        const int excl = tot[t] - s;
        cstartM[t] = excl;
        ccurM[t] = excl;
    }
    if (t == NBM - 1) cstartM[NBM] = tot[t];
    __syncthreads();
    // ---- mc side (NBC buckets) ----
    int s2 = 0;
    if (t < NBC)
        for (int b = 0; b < NSB; ++b) s2 += pmC[(long)b * NBC + t];
    tot[t] = s2;
    __syncthreads();
    for (int off = 1; off < 256; off <<= 1) {
        int v = (t >= off) ? tot[t - off] : 0;
        __syncthreads();
        tot[t] += v;
        __syncthreads();
    }
    if (t < NBC) {
        const int excl = tot[t] - s2;
        cstartC[t] = excl;
        ccurC[t] = excl;
    }
    if (t == NBC - 1) cstartC[NBC] = tot[t];
}

// ---------------- bucket sort pass 1: LDS-staged, block-aggregated cursors ----------
__global__ __launch_bounds__(256) void bsort2_k(const int* __restrict__ cm_src,
                                                const int* __restrict__ cm_dst,
                                                const int* __restrict__ mc_src,
                                                const int* __restrict__ mc_dst,
                                                int* __restrict__ ccurM,
                                                int* __restrict__ ccurC,
                                                int* __restrict__ bktM,
                                                int* __restrict__ bktC) {
    __shared__ int cnt[256], pfx[256], gbase[256];
    __shared__ int stage[CH];
    const int side = (blockIdx.x >= NSB);
    const int blk = blockIdx.x - side * NSB;
    const int* src = side ? mc_src : cm_src;
    const int* dst = side ? mc_dst : cm_dst;
    int* ccur = side ? ccurC : ccurM;
    int* bkt = side ? bktC : bktM;
    const int nb = side ? NBC : NBM;

    const int t = threadIdx.x;
    const int e0 = blk * CH;
    const int n = min(CH, NE - e0);
    cnt[t] = 0;
    __syncthreads();
    for (int i = t; i < n; i += 256) atomicAdd(&cnt[dst[e0 + i] >> BSH], 1);
    __syncthreads();
    const int myc = (t < nb) ? cnt[t] : 0;
    pfx[t] = myc;
    __syncthreads();
    for (int off = 1; off < 256; off <<= 1) {
        int add = (t >= off) ? pfx[t - off] : 0;
        __syncthreads();
        pfx[t] += add;
        __syncthreads();
    }
    const int excl = pfx[t] - myc;
    if (t < nb && myc > 0) gbase[t] = atomicAdd(&ccur[t], myc);
    pfx[t] = excl;
    cnt[t] = 0;
    __syncthreads();
    for (int i = t; i < n; i += 256) {
        const int d = dst[e0 + i];
        const int b = d >> BSH;
        const int p = pfx[b] + atomicAdd(&cnt[b], 1);
        stage[p] = (src[e0 + i] << BSH) | (d & (BW - 1));
    }
    __syncthreads();
    const int wv = t >> 6, ln = t & 63;
    for (int b = wv; b < nb; b += 4) {
        const int c = cnt[b];
        if (c == 0) continue;
        const int gb = gbase[b], lo = pfx[b];
        for (int j = ln; j < c; j += 64) bkt[gb + j] = stage[lo + j];
    }
}

// ---------------- bucket sort pass 2 + fine-offset construction ----------------
// Per bucket: LDS fine histogram of 1024 local dsts -> LDS scan -> write fine start[]
// (coalesced, no atomics) -> place edges via LDS cursors.
__global__ __launch_bounds__(256) void bp22_k(const int* __restrict__ bktM,
                                              const int* __restrict__ cstartM,
                                              int* __restrict__ startM,
                                              int* __restrict__ srtM,
                                              const int* __restrict__ bktC,
                                              const int* __restrict__ cstartC,
                                              int* __restrict__ startC,
                                              int* __restrict__ srtC) {
    __shared__ int lcur[BW];
    __shared__ int sums[256];
    const int side = (blockIdx.x >= NBM);
    const int blk = blockIdx.x - side * NBM;
    const int* bkt = side ? bktC : bktM;
    const int* cstart = side ? cstartC : cstartM;
    int* start = side ? startC : startM;
    int* srt = side ? srtC : srtM;
    const int n_nodes = side ? NC : NM;
    const int base = blk << BSH;
    const int t = threadIdx.x;

    const int e0 = cstart[blk];
    const int e1 = cstart[blk + 1];

    for (int i = t; i < BW; i += 256) lcur[i] = 0;
    __syncthreads();
    for (int e = e0 + t; e < e1; e += 256) atomicAdd(&lcur[bkt[e] & (BW - 1)], 1);
    __syncthreads();

    // exclusive scan of 1024 counts (4 per thread + 256-wide Hillis-Steele)
    const int c0 = lcur[4 * t + 0], c1 = lcur[4 * t + 1];
    const int c2 = lcur[4 * t + 2], c3 = lcur[4 * t + 3];
    sums[t] = c0 + c1 + c2 + c3;
    __syncthreads();
    for (int off = 1; off < 256; off <<= 1) {
        int v = (t >= off) ? sums[t - off] : 0;
        __syncthreads();
        sums[t] += v;
        __syncthreads();
    }
    const int p0 = e0 + ((t == 0) ? 0 : sums[t - 1]);
    const int p1 = p0 + c0, p2 = p1 + c1, p3 = p2 + c2;
    lcur[4 * t + 0] = p0;
    lcur[4 * t + 1] = p1;
    lcur[4 * t + 2] = p2;
    lcur[4 * t + 3] = p3;
    // fine start[] written coalesced, no atomics
    if (base + 4 * t + 0 < n_nodes) start[base + 4 * t + 0] = p0;
    if (base + 4 * t + 1 < n_nodes) start[base + 4 * t + 1] = p1;
    if (base + 4 * t + 2 < n_nodes) start[base + 4 * t + 2] = p2;
    if (base + 4 * t + 3 < n_nodes) start[base + 4 * t + 3] = p3;
    if (t == 0 && base + BW >= n_nodes) start[n_nodes] = e1;
    __syncthreads();

    for (int e = e0 + t; e < e1; e += 256) {
        const int p = bkt[e];
        const int pos = atomicAdd(&lcur[p & (BW - 1)], 1);
        srt[pos] = p >> BSH;
    }
}

// ---------------- round-to-nearest bf16 helpers ----------------
__device__ __forceinline__ short bf16rn(float x) {
    unsigned u = __builtin_bit_cast(unsigned, x);
    unsigned r = u + 0x7FFFu + ((u >> 16) & 1u);
    return (short)(r >> 16);
}
__device__ __forceinline__ float bf16f(short h) {
    unsigned u = ((unsigned)(unsigned short)h) << 16;
    return __builtin_bit_cast(float, u);
}
__device__ __forceinline__ void split8(const f32x4 u, const f32x4 v,
                                       bf16x8& hi, bf16x8& lo) {
#pragma unroll
    for (int b = 0; b < 4; ++b) {
        short h = bf16rn(u[b]);
        hi[b] = h;
        lo[b] = bf16rn(u[b] - bf16f(h));
    }
#pragma unroll
    for (int b = 0; b < 4; ++b) {
        short h = bf16rn(v[b]);
        hi[4 + b] = h;
        lo[4 + b] = bf16rn(v[b] - bf16f(h));
    }
}

// ---------------- merged presplit: both feature arrays -> bf16 hi-planes ----------
__global__ __launch_bounds__(256) void presplit2_k(const float* __restrict__ x_c,
                                                   const float* __restrict__ x_m,
                                                   u16x4* __restrict__ xc16,
                                                   u16x4* __restrict__ xm16) {
    const int NC4 = NC * (DF / 4);
    const int NT4 = (NC + NM) * (DF / 4);
    int i = blockIdx.x * blockDim.x + threadIdx.x;
    const int st = gridDim.x * blockDim.x;
    for (; i < NT4; i += st) {
        const bool mc = (i < NC4);
        const int j = mc ? i : i - NC4;
        const f32x4 v = mc ? ((const f32x4*)x_c)[j] : ((const f32x4*)x_m)[j];
        u16x4 o;
#pragma unroll
        for (int b = 0; b < 4; ++b) o[b] = (unsigned short)bf16rn(v[b]);
        if (mc) xc16[j] = o;
        else    xm16[j] = o;
    }
}

// ---------------- single-plane aggregation: 16-lane subgroup per node ----------------
__global__ __launch_bounds__(256) void agg16_k(const unsigned short* __restrict__ xhi,
                                               const int* __restrict__ start,
                                               const int* __restrict__ srt,
                                               unsigned short* __restrict__ mean16,
                                               int n_nodes) {
    const int sgid = (blockIdx.x * blockDim.x + threadIdx.x) >> 4;
    const int nsg = (gridDim.x * blockDim.x) >> 4;
    const int k4 = (threadIdx.x & 15) * 4;
    for (int n = sgid; n < n_nodes; n += nsg) {
        const int s0 = start[n], s1 = start[n + 1];
        f32x4 a0 = {0.f, 0.f, 0.f, 0.f}, a1 = {0.f, 0.f, 0.f, 0.f};
        f32x4 a2 = {0.f, 0.f, 0.f, 0.f}, a3 = {0.f, 0.f, 0.f, 0.f};
        int e = s0;
        for (; e + 3 < s1; e += 4) {
            const int i0 = srt[e + 0], i1 = srt[e + 1];
            const int i2 = srt[e + 2], i3 = srt[e + 3];
            const u16x4 v0 = *(const u16x4*)(xhi + (long)i0 * DF + k4);
            const u16x4 v1 = *(const u16x4*)(xhi + (long)i1 * DF + k4);
            const u16x4 v2 = *(const u16x4*)(xhi + (long)i2 * DF + k4);
            const u16x4 v3 = *(const u16x4*)(xhi + (long)i3 * DF + k4);
#pragma unroll
            for (int c = 0; c < 4; ++c) {
                a0[c] += bf16f((short)v0[c]);
                a1[c] += bf16f((short)v1[c]);
                a2[c] += bf16f((short)v2[c]);
                a3[c] += bf16f((short)v3[c]);
            }
        }
        for (; e < s1; ++e) {
            const int i0 = srt[e];
            const u16x4 v0 = *(const u16x4*)(xhi + (long)i0 * DF + k4);
#pragma unroll
            for (int c = 0; c < 4; ++c) a0[c] += bf16f((short)v0[c]);
        }
        const float inv = 1.0f / fmaxf((float)(s1 - s0), 1.0f);
        u16x4 o;
#pragma unroll
        for (int c = 0; c < 4; ++c)
            o[c] = (unsigned short)bf16rn(((a0[c] + a1[c]) + (a2[c] + a3[c])) * inv);
        *(u16x4*)(mean16 + (long)n * DF + k4) = o;
    }
}

// ---------------- dual-plane aggregation: 16-lane subgroup per node ----------------
__global__ __launch_bounds__(256) void aggc2_k(const unsigned short* __restrict__ xp,
                                               const unsigned short* __restrict__ hp,
                                               const int* __restrict__ start,
                                               const int* __restrict__ srt,
                                               unsigned short* __restrict__ mx,
                                               unsigned short* __restrict__ mh, int n_nodes) {
    const int sgid = (blockIdx.x * blockDim.x + threadIdx.x) >> 4;
    const int nsg = (gridDim.x * blockDim.x) >> 4;
    const int k4 = (threadIdx.x & 15) * 4;
    for (int n = sgid; n < n_nodes; n += nsg) {
        const int s0 = start[n], s1 = start[n + 1];
        f32x4 ax0 = {0.f, 0.f, 0.f, 0.f}, ah0 = {0.f, 0.f, 0.f, 0.f};
        f32x4 ax1 = {0.f, 0.f, 0.f, 0.f}, ah1 = {0.f, 0.f, 0.f, 0.f};
        int e = s0;
        for (; e + 1 < s1; e += 2) {
            const int iA = srt[e], iB = srt[e + 1];
            const u16x4 vxA = *(const u16x4*)(xp + (long)iA * DF + k4);
            const u16x4 vhA = *(const u16x4*)(hp + (long)iA * DF + k4);
            const u16x4 vxB = *(const u16x4*)(xp + (long)iB * DF + k4);
            const u16x4 vhB = *(const u16x4*)(hp + (long)iB * DF + k4);
#pragma unroll
            for (int c = 0; c < 4; ++c) {
                ax0[c] += bf16f((short)vxA[c]);
                ah0[c] += bf16f((short)vhA[c]);
                ax1[c] += bf16f((short)vxB[c]);
                ah1[c] += bf16f((short)vhB[c]);
            }
        }
        if (e < s1) {
            const int iA = srt[e];
            const u16x4 vxA = *(const u16x4*)(xp + (long)iA * DF + k4);
            const u16x4 vhA = *(const u16x4*)(hp + (long)iA * DF + k4);
#pragma unroll
            for (int c = 0; c < 4; ++c) {
                ax0[c] += bf16f((short)vxA[c]);
                ah0[c] += bf16f((short)vhA[c]);
            }
        }
        const float inv = 1.0f / fmaxf((float)(s1 - s0), 1.0f);
        u16x4 ox, oh;
#pragma unroll
        for (int c = 0; c < 4; ++c) {
            ox[c] = (unsigned short)bf16rn((ax0[c] + ax1[c]) * inv);
            oh[c] = (unsigned short)bf16rn((ah0[c] + ah1[c]) * inv);
        }
        *(u16x4*)(mx + (long)n * DF + k4) = ox;
        *(u16x4*)(mh + (long)n * DF + k4) = oh;
    }
}

#define MFMA(a, b, c) __builtin_amdgcn_mfma_f32_16x16x32_bf16((a), (b), (c), 0, 0, 0)

#define LOAD_W(Wl, Wr, col, g, wlh, wll, wrh, wrl)          \
    do {                                                    \
        _Pragma("unroll")                                   \
        for (int q = 0; q < 2; ++q) {                       \
            f32x4 tl0, tl1, tr0, tr1;                       \
            _Pragma("unroll")                               \
            for (int b = 0; b < 4; ++b) {                   \
                int k = 32 * q + 8 * (g) + b;               \
                tl0[b] = (Wl)[k * DF + (col)];              \
                tr0[b] = (Wr)[k * DF + (col)];              \
                tl1[b] = (Wl)[(k + 4) * DF + (col)];        \
                tr1[b] = (Wr)[(k + 4) * DF + (col)];        \
            }                                               \
            split8(tl0, tl1, wlh[q], wll[q]);               \
            split8(tr0, tr1, wrh[q], wrl[q]);               \
        }                                                   \
    } while (0)

// ---------------- dense1 @ NM: hm16 = bf16(relu(mean16 @ Wl + xm16 @ Wr + b)) --------
__global__ __launch_bounds__(256) void dense1nm_k(const unsigned short* __restrict__ mean16,
                                                  const unsigned short* __restrict__ xm16,
                                                  const float* __restrict__ Wl,
                                                  const float* __restrict__ Wr,
                                                  const float* __restrict__ bias,
                                                  unsigned short* __restrict__ h16,
                                                  int n_nodes) {
    const int wglobal = (blockIdx.x * blockDim.x + threadIdx.x) >> 6;
    const int lane = threadIdx.x & 63;
    const int nwaves = (gridDim.x * blockDim.x) >> 6;
    const int ct = wglobal & 3;
    const int col = ct * 16 + (lane & 15);
    const int g = lane >> 4;

    bf16x8 wlh[2], wll[2], wrh[2], wrl[2];
    LOAD_W(Wl, Wr, col, g, wlh, wll, wrh, wrl);
    const float bv = bias[col];

    const int nrt = n_nodes >> 4;
    for (int rt = wglobal >> 2; rt < nrt; rt += nwaves >> 2) {
        const long rowA = (long)rt * 16 + (lane & 15);
        const bf16x8 m0 = *(const bf16x8*)(mean16 + rowA * DF + 8 * g);
        const bf16x8 m1 = *(const bf16x8*)(mean16 + rowA * DF + 32 + 8 * g);
        const bf16x8 x0 = *(const bf16x8*)(xm16 + rowA * DF + 8 * g);
        const bf16x8 x1 = *(const bf16x8*)(xm16 + rowA * DF + 32 + 8 * g);
        f32x4 acc = {0.f, 0.f, 0.f, 0.f};
        acc = MFMA(m0, wlh[0], acc);
        acc = MFMA(m0, wll[0], acc);
        acc = MFMA(m1, wlh[1], acc);
        acc = MFMA(m1, wll[1], acc);
        acc = MFMA(x0, wrh[0], acc);
        acc = MFMA(x0, wrl[0], acc);
        acc = MFMA(x1, wrh[1], acc);
        acc = MFMA(x1, wrl[1], acc);
#pragma unroll
        for (int r = 0; r < 4; ++r)
            h16[((long)rt * 16 + 4 * g + r) * DF + col] =
                (unsigned short)bf16rn(fmaxf(acc[r] + bv, 0.0f));
    }
}

// ---------------- fused customer dense: layer1 + layer2 + final linear ----------------
__global__ __launch_bounds__(256) void densec_k(const unsigned short* __restrict__ meanx,
                                                const unsigned short* __restrict__ meanh,
                                                const unsigned short* __restrict__ xc,
                                                const float* __restrict__ Wl1,
                                                const float* __restrict__ Wr1,
                                                const float* __restrict__ b1,
                                                const float* __restrict__ Wl2,
                                                const float* __restrict__ Wr2,
                                                const float* __restrict__ b2,
                                                const float* __restrict__ Wlin,
                                                const float* __restrict__ blin,
                                                float* __restrict__ out, int n_nodes) {
    __shared__ unsigned short sH[16][72];
    __shared__ float sOut[4][16][2];
    const int t = threadIdx.x;
    const int lane = t & 63;
    const int wv = t >> 6;
    const int col = wv * 16 + (lane & 15);
    const int g = lane >> 4;

    bf16x8 w1lh[2], w1ll[2], w1rh[2], w1rl[2];
    LOAD_W(Wl1, Wr1, col, g, w1lh, w1ll, w1rh, w1rl);
    bf16x8 w2lh[2], w2ll[2], w2rh[2], w2rl[2];
    LOAD_W(Wl2, Wr2, col, g, w2lh, w2ll, w2rh, w2rl);
    const float bv1 = b1[col];
    const float bv2 = b2[col];
    const float wl0 = Wlin[col * 2 + 0];
    const float wl1s = Wlin[col * 2 + 1];
    const float bl0 = blin[0];
    const float bl1 = blin[1];

    const int nrt = n_nodes >> 4;
    for (int rt = blockIdx.x; rt < nrt; rt += gridDim.x) {
        const long rowA = (long)rt * 16 + (lane & 15);
        const bf16x8 mx0 = *(const bf16x8*)(meanx + rowA * DF + 8 * g);
        const bf16x8 mx1 = *(const bf16x8*)(meanx + rowA * DF + 32 + 8 * g);
        const bf16x8 mh0 = *(const bf16x8*)(meanh + rowA * DF + 8 * g);
        const bf16x8 mh1 = *(const bf16x8*)(meanh + rowA * DF + 32 + 8 * g);
        const bf16x8 xc0 = *(const bf16x8*)(xc + rowA * DF + 8 * g);
        const bf16x8 xc1 = *(const bf16x8*)(xc + rowA * DF + 32 + 8 * g);

        // ---- layer 1: h_c = relu(meanx @ Wl1 + x_c @ Wr1 + b1) ----
        f32x4 acc = {0.f, 0.f, 0.f, 0.f};
        acc = MFMA(mx0, w1lh[0], acc);
        acc = MFMA(mx0, w1ll[0], acc);
        acc = MFMA(mx1, w1lh[1], acc);
        acc = MFMA(mx1, w1ll[1], acc);
        acc = MFMA(xc0, w1rh[0], acc);
        acc = MFMA(xc0, w1rl[0], acc);
        acc = MFMA(xc1, w1rh[1], acc);
        acc = MFMA(xc1, w1rl[1], acc);
#pragma unroll
        for (int r = 0; r < 4; ++r)
            sH[4 * g + r][col] = (unsigned short)bf16rn(fmaxf(acc[r] + bv1, 0.0f));
        __syncthreads();

        // ---- layer 2: h2 = meanh @ Wl2 + h_c @ Wr2 + b2 ----
        const bf16x8 hc0 = *(const bf16x8*)&sH[lane & 15][8 * g];
        const bf16x8 hc1 = *(const bf16x8*)&sH[lane & 15][32 + 8 * g];
        f32x4 a2 = {0.f, 0.f, 0.f, 0.f};
        a2 = MFMA(mh0, w2lh[0], a2);
        a2 = MFMA(mh0, w2ll[0], a2);
        a2 = MFMA(mh1, w2lh[1], a2);
        a2 = MFMA(mh1, w2ll[1], a2);
        a2 = MFMA(hc0, w2rh[0], a2);
        a2 = MFMA(hc0, w2rl[0], a2);
        a2 = MFMA(hc1, w2rh[1], a2);
        a2 = MFMA(hc1, w2rl[1], a2);

        // ---- final linear: per-wave partials -> LDS -> one float2 store per node ----
#pragma unroll
        for (int r = 0; r < 4; ++r) {
            const float h2 = a2[r] + bv2;
            float p0 = h2 * wl0;
            float p1 = h2 * wl1s;
#pragma unroll
            for (int m = 1; m < 16; m <<= 1) {
                p0 += __shfl_xor(p0, m);
                p1 += __shfl_xor(p1, m);
            }
            if ((lane & 15) == 0) {
                sOut[wv][4 * g + r][0] = p0;
                sOut[wv][4 * g + r][1] = p1;
            }
        }
        __syncthreads();
        if (t < 16) {
            const long node = (long)rt * 16 + t;
            const float o0 = sOut[0][t][0] + sOut[1][t][0] + sOut[2][t][0] + sOut[3][t][0] + bl0;
            const float o1 = sOut[0][t][1] + sOut[1][t][1] + sOut[2][t][1] + sOut[3][t][1] + bl1;
            float2 o = {o0, o1};
            *(float2*)(out + node * 2) = o;
        }
        __syncthreads();
    }
}

extern "C" void kernel_launch(void* const* d_in, const int* in_sizes, int n_in,
                              void* d_out, int out_size, void* d_ws, size_t ws_size,
                              hipStream_t stream) {
    const float* x_c = (const float*)d_in[0];
    const float* x_m = (const float*)d_in[1];
    const int* cm_src = (const int*)d_in[2];
    const int* cm_dst = (const int*)d_in[3];
    const int* mc_src = (const int*)d_in[4];
    const int* mc_dst = (const int*)d_in[5];
    const float* Wl1_cm = (const float*)d_in[6];
    const float* Wr1_cm = (const float*)d_in[7];
    const float* b1_cm = (const float*)d_in[8];
    const float* Wl1_mc = (const float*)d_in[9];
    const float* Wr1_mc = (const float*)d_in[10];
    const float* b1_mc = (const float*)d_in[11];
    // layer-2 cm weights (d_in[12..14]) are dead: h2_m is unused in the reference
    const float* Wl2_mc = (const float*)d_in[15];
    const float* Wr2_mc = (const float*)d_in[16];
    const float* b2_mc = (const float*)d_in[17];
    const float* W_lin = (const float*)d_in[18];
    const float* b_lin = (const float*)d_in[19];
    float* out = (float*)d_out;

    // ---- workspace layout (~117 MB) ----
    unsigned short* up = (unsigned short*)d_ws;
    unsigned short* aggm16 = up;                        // NM*64
    unsigned short* hm16 = aggm16 + (long)NM * DF;      // NM*64
    unsigned short* xm16 = hm16 + (long)NM * DF;        // NM*64
    unsigned short* xc16 = xm16 + (long)NM * DF;        // NC*64
    unsigned short* meanx16 = xc16 + (long)NC * DF;     // NC*64
    unsigned short* meanh16 = meanx16 + (long)NC * DF;  // NC*64
    int* ip = (int*)(meanh16 + (long)NC * DF);

    int* startM = ip;                 // NM+1 (written by bp22)
    int* startC = startM + (NM + 1);  // NC+1 (written by bp22)
    int* cstartM = startC + (NC + 1); // NBM+1
    int* cstartC = cstartM + (NBM + 1); // NBC+1
    int* ccurM = cstartC + (NBC + 1); // NBM
    int* ccurC = ccurM + NBM;         // NBC
    int* pmM = ccurC + NBC;           // NSB*NBM partial coarse hists
    int* pmC = pmM + NSB * NBM;       // NSB*NBC
    int* srt_cm = pmC + NSB * NBC;    // NE
    int* srt_mc = srt_cm + NE;        // NE
    int* bktM = srt_mc + NE;          // NE
    int* bktC = bktM + NE;            // NE

    // coarse hist (no global atomics) -> coarse scan -> bucket sort -> fine offsets
    chist2_k<<<2 * NSB, 256, 0, stream>>>(cm_dst, mc_dst, pmM, pmC);
    cscan2_k<<<1, 256, 0, stream>>>(pmM, pmC, cstartM, cstartC, ccurM, ccurC);
    bsort2_k<<<2 * NSB, 256, 0, stream>>>(cm_src, cm_dst, mc_src, mc_dst,
                                          ccurM, ccurC, bktM, bktC);
    bp22_k<<<NBM + NBC, 256, 0, stream>>>(bktM, cstartM, startM, srt_cm,
                                          bktC, cstartC, startC, srt_mc);

    // merged bf16 presplit
    presplit2_k<<<2048, 256, 0, stream>>>(x_c, x_m, (u16x4*)xc16, (u16x4*)xm16);

    // layer 1 @ merchants: m-mean (bf16) then dense -> hm16
    agg16_k<<<NM / 16, 256, 0, stream>>>(xc16, startM, srt_cm, aggm16, NM);
    dense1nm_k<<<1024, 256, 0, stream>>>(aggm16, xm16, Wl1_cm, Wr1_cm, b1_cm, hm16, NM);

    // customers: fused dual aggregation (x_m-mean + h_m-mean in one edge sweep)
    aggc2_k<<<NC / 16, 256, 0, stream>>>(xm16, hm16, startC, srt_mc,
                                         meanx16, meanh16, NC);

    // customers: fused layer1 + layer2 + final linear
    densec_k<<<2048, 256, 0, stream>>>(meanx16, meanh16, xc16,
                                       Wl1_mc, Wr1_mc, b1_mc,
                                       Wl2_mc, Wr2_mc, b2_mc,
                                       W_lin, b_lin, out, NC);
}

// Round 14
// 266.149 us; speedup vs baseline: 3.4028x; 1.0201x over previous
//
#include <hip/hip_runtime.h>

#define NC 200000
#define NM 50000
#define NE 1000000
#define DF 64   // feature dim (D == H == 64)

#define BSH 10
#define BW 1024
#define NBM ((NM + BW - 1) >> BSH)   // 49
#define NBC ((NC + BW - 1) >> BSH)   // 196
#define CH 4096                      // edges per chunk block
#define NSB ((NE + CH - 1) / CH)     // 245
#define PSB 1024                     // presplit blocks inside prep_k

typedef __attribute__((ext_vector_type(8))) short bf16x8;
typedef __attribute__((ext_vector_type(4))) float f32x4;
typedef __attribute__((ext_vector_type(4))) unsigned short u16x4;

// ---------------- round-to-nearest bf16 helpers ----------------
__device__ __forceinline__ short bf16rn(float x) {
    unsigned u = __builtin_bit_cast(unsigned, x);
    unsigned r = u + 0x7FFFu + ((u >> 16) & 1u);
    return (short)(r >> 16);
}
__device__ __forceinline__ float bf16f(short h) {
    unsigned u = ((unsigned)(unsigned short)h) << 16;
    return __builtin_bit_cast(float, u);
}
__device__ __forceinline__ void split8(const f32x4 u, const f32x4 v,
                                       bf16x8& hi, bf16x8& lo) {
#pragma unroll
    for (int b = 0; b < 4; ++b) {
        short h = bf16rn(u[b]);
        hi[b] = h;
        lo[b] = bf16rn(u[b] - bf16f(h));
    }
#pragma unroll
    for (int b = 0; b < 4; ++b) {
        short h = bf16rn(v[b]);
        hi[4 + b] = h;
        lo[4 + b] = bf16rn(v[b] - bf16f(h));
    }
}

// ---------------- wave-wide inclusive scan (64 lanes, no barriers) ----------------
__device__ __forceinline__ int wscan_incl(int v, int lane) {
#pragma unroll
    for (int off = 1; off < 64; off <<= 1) {
        int y = __shfl_up(v, off);
        if (lane >= off) v += y;
    }
    return v;
}

// ---------------- prep: coarse histograms (no global atomics) + bf16 presplit ------
__global__ __launch_bounds__(256) void prep_k(const int* __restrict__ cm_dst,
                                              const int* __restrict__ mc_dst,
                                              int* __restrict__ pmM,
                                              int* __restrict__ pmC,
                                              const float* __restrict__ x_c,
                                              const float* __restrict__ x_m,
                                              u16x4* __restrict__ xc16,
                                              u16x4* __restrict__ xm16) {
    __shared__ int cnt[256];
    const int t = threadIdx.x;
    if (blockIdx.x < 2 * NSB) {
        const int side = (blockIdx.x >= NSB);
        const int blk = blockIdx.x - side * NSB;
        const int* dst = side ? mc_dst : cm_dst;
        int* pm = side ? pmC : pmM;
        const int nb = side ? NBC : NBM;
        cnt[t] = 0;
        __syncthreads();
        const int e0 = blk * CH;
        const int n = min(CH, NE - e0);
        for (int i = t; i < n; i += 256) atomicAdd(&cnt[dst[e0 + i] >> BSH], 1);
        __syncthreads();
        if (t < nb) pm[(long)blk * nb + t] = cnt[t];
    } else {
        const int blk = blockIdx.x - 2 * NSB;
        const int NC4 = NC * (DF / 4);
        const int NT4 = (NC + NM) * (DF / 4);
        const int st = PSB * 256;
        for (int i = blk * 256 + t; i < NT4; i += st) {
            const bool isc = (i < NC4);
            const int j = isc ? i : i - NC4;
            const f32x4 v = isc ? ((const f32x4*)x_c)[j] : ((const f32x4*)x_m)[j];
            u16x4 o;
#pragma unroll
            for (int b = 0; b < 4; ++b) o[b] = (unsigned short)bf16rn(v[b]);
            if (isc) xc16[j] = o;
            else     xm16[j] = o;
        }
    }
}

// ---------------- coarse reduce+scan (one tiny block): cstart + ccur init ----------
__global__ __launch_bounds__(256) void cscan2_k(const int* __restrict__ pmM,
                                                const int* __restrict__ pmC,
                                                int* __restrict__ cstartM,
                                                int* __restrict__ cstartC,
                                                int* __restrict__ ccurM,
                                                int* __restrict__ ccurC) {
    __shared__ int wsum[4];
    const int t = threadIdx.x, lane = t & 63, wv = t >> 6;
    // cm side
    int s = 0;
    if (t < NBM)
        for (int b = 0; b < NSB; ++b) s += pmM[(long)b * NBM + t];
    int incl = wscan_incl(s, lane);
    if (lane == 63) wsum[wv] = incl;
    __syncthreads();
    int wadd = 0;
#pragma unroll
    for (int w = 0; w < 4; ++w) wadd += (w < wv) ? wsum[w] : 0;
    const int tot = incl + wadd;
    if (t < NBM) { cstartM[t] = tot - s; ccurM[t] = tot - s; }
    if (t == NBM - 1) cstartM[NBM] = tot;
    __syncthreads();
    // mc side
    int s2 = 0;
    if (t < NBC)
        for (int b = 0; b < NSB; ++b) s2 += pmC[(long)b * NBC + t];
    int incl2 = wscan_incl(s2, lane);
    if (lane == 63) wsum[wv] = incl2;
    __syncthreads();
    int wadd2 = 0;
#pragma unroll
    for (int w = 0; w < 4; ++w) wadd2 += (w < wv) ? wsum[w] : 0;
    const int tot2 = incl2 + wadd2;
    if (t < NBC) { cstartC[t] = tot2 - s2; ccurC[t] = tot2 - s2; }
    if (t == NBC - 1) cstartC[NBC] = tot2;
}

// ---------------- bucket sort pass 1: LDS-staged, block-aggregated cursors ----------
__global__ __launch_bounds__(256) void bsort2_k(const int* __restrict__ cm_src,
                                                const int* __restrict__ cm_dst,
                                                const int* __restrict__ mc_src,
                                                const int* __restrict__ mc_dst,
                                                int* __restrict__ ccurM,
                                                int* __restrict__ ccurC,
                                                int* __restrict__ bktM,
                                                int* __restrict__ bktC) {
    __shared__ int cnt[256], pfx[256], gbase[256];
    __shared__ int wsum[4];
    __shared__ int stage[CH];
    const int side = (blockIdx.x >= NSB);
    const int blk = blockIdx.x - side * NSB;
    const int* src = side ? mc_src : cm_src;
    const int* dst = side ? mc_dst : cm_dst;
    int* ccur = side ? ccurC : ccurM;
    int* bkt = side ? bktC : bktM;
    const int nb = side ? NBC : NBM;

    const int t = threadIdx.x, lane = t & 63, wv = t >> 6;
    const int e0 = blk * CH;
    const int n = min(CH, NE - e0);
    cnt[t] = 0;
    __syncthreads();
    for (int i = t; i < n; i += 256) atomicAdd(&cnt[dst[e0 + i] >> BSH], 1);
    __syncthreads();
    const int myc = (t < nb) ? cnt[t] : 0;
    int incl = wscan_incl(myc, lane);
    if (lane == 63) wsum[wv] = incl;
    __syncthreads();
    int wadd = 0;
#pragma unroll
    for (int w = 0; w < 4; ++w) wadd += (w < wv) ? wsum[w] : 0;
    const int excl = wadd + incl - myc;
    if (t < nb && myc > 0) gbase[t] = atomicAdd(&ccur[t], myc);
    pfx[t] = excl;
    cnt[t] = 0;
    __syncthreads();
    for (int i = t; i < n; i += 256) {
        const int d = dst[e0 + i];
        const int b = d >> BSH;
        const int p = pfx[b] + atomicAdd(&cnt[b], 1);
        stage[p] = (src[e0 + i] << BSH) | (d & (BW - 1));
    }
    __syncthreads();
    for (int b = wv; b < nb; b += 4) {
        const int c = cnt[b];
        if (c == 0) continue;
        const int gb = gbase[b], lo = pfx[b];
        for (int j = lane; j < c; j += 64) bkt[gb + j] = stage[lo + j];
    }
}

// ---------------- bucket sort pass 2 + fine-offset construction ----------------
__global__ __launch_bounds__(256) void bp22_k(const int* __restrict__ bktM,
                                              const int* __restrict__ cstartM,
                                              int* __restrict__ startM,
                                              int* __restrict__ srtM,
                                              const int* __restrict__ bktC,
                                              const int* __restrict__ cstartC,
                                              int* __restrict__ startC,
                                              int* __restrict__ srtC) {
    __shared__ int lcur[BW];
    __shared__ int wsum[4];
    const int side = (blockIdx.x >= NBM);
    const int blk = blockIdx.x - side * NBM;
    const int* bkt = side ? bktC : bktM;
    const int* cstart = side ? cstartC : cstartM;
    int* start = side ? startC : startM;
    int* srt = side ? srtC : srtM;
    const int n_nodes = side ? NC : NM;
    const int base = blk << BSH;
    const int t = threadIdx.x, lane = t & 63, wv = t >> 6;

    const int e0 = cstart[blk];
    const int e1 = cstart[blk + 1];

    for (int i = t; i < BW; i += 256) lcur[i] = 0;
    __syncthreads();
    for (int e = e0 + t; e < e1; e += 256) atomicAdd(&lcur[bkt[e] & (BW - 1)], 1);
    __syncthreads();

    const int c0 = lcur[4 * t + 0], c1 = lcur[4 * t + 1];
    const int c2 = lcur[4 * t + 2], c3 = lcur[4 * t + 3];
    const int local = c0 + c1 + c2 + c3;
    int incl = wscan_incl(local, lane);
    if (lane == 63) wsum[wv] = incl;
    __syncthreads();
    int wadd = 0;
#pragma unroll
    for (int w = 0; w < 4; ++w) wadd += (w < wv) ? wsum[w] : 0;
    const int p0 = e0 + wadd + incl - local;
    const int p1 = p0 + c0, p2 = p1 + c1, p3 = p2 + c2;
    lcur[4 * t + 0] = p0;
    lcur[4 * t + 1] = p1;
    lcur[4 * t + 2] = p2;
    lcur[4 * t + 3] = p3;
    if (base + 4 * t + 0 < n_nodes) start[base + 4 * t + 0] = p0;
    if (base + 4 * t + 1 < n_nodes) start[base + 4 * t + 1] = p1;
    if (base + 4 * t + 2 < n_nodes) start[base + 4 * t + 2] = p2;
    if (base + 4 * t + 3 < n_nodes) start[base + 4 * t + 3] = p3;
    if (t == 0 && base + BW >= n_nodes) start[n_nodes] = e1;
    __syncthreads();

    for (int e = e0 + t; e < e1; e += 256) {
        const int p = bkt[e];
        const int pos = atomicAdd(&lcur[p & (BW - 1)], 1);
        srt[pos] = p >> BSH;
    }
}

// ---------------- single-plane aggregation: 16-lane subgroup per node ----------------
__global__ __launch_bounds__(256) void agg16_k(const unsigned short* __restrict__ xhi,
                                               const int* __restrict__ start,
                                               const int* __restrict__ srt,
                                               unsigned short* __restrict__ mean16,
                                               int n_nodes) {
    const int sgid = (blockIdx.x * blockDim.x + threadIdx.x) >> 4;
    const int nsg = (gridDim.x * blockDim.x) >> 4;
    const int k4 = (threadIdx.x & 15) * 4;
    for (int n = sgid; n < n_nodes; n += nsg) {
        const int s0 = start[n], s1 = start[n + 1];
        f32x4 a0 = {0.f, 0.f, 0.f, 0.f}, a1 = {0.f, 0.f, 0.f, 0.f};
        f32x4 a2 = {0.f, 0.f, 0.f, 0.f}, a3 = {0.f, 0.f, 0.f, 0.f};
        int e = s0;
        for (; e + 3 < s1; e += 4) {
            const int i0 = srt[e + 0], i1 = srt[e + 1];
            const int i2 = srt[e + 2], i3 = srt[e + 3];
            const u16x4 v0 = *(const u16x4*)(xhi + (long)i0 * DF + k4);
            const u16x4 v1 = *(const u16x4*)(xhi + (long)i1 * DF + k4);
            const u16x4 v2 = *(const u16x4*)(xhi + (long)i2 * DF + k4);
            const u16x4 v3 = *(const u16x4*)(xhi + (long)i3 * DF + k4);
#pragma unroll
            for (int c = 0; c < 4; ++c) {
                a0[c] += bf16f((short)v0[c]);
                a1[c] += bf16f((short)v1[c]);
                a2[c] += bf16f((short)v2[c]);
                a3[c] += bf16f((short)v3[c]);
            }
        }
        for (; e < s1; ++e) {
            const int i0 = srt[e];
            const u16x4 v0 = *(const u16x4*)(xhi + (long)i0 * DF + k4);
#pragma unroll
            for (int c = 0; c < 4; ++c) a0[c] += bf16f((short)v0[c]);
        }
        const float inv = 1.0f / fmaxf((float)(s1 - s0), 1.0f);
        u16x4 o;
#pragma unroll
        for (int c = 0; c < 4; ++c)
            o[c] = (unsigned short)bf16rn(((a0[c] + a1[c]) + (a2[c] + a3[c])) * inv);
        *(u16x4*)(mean16 + (long)n * DF + k4) = o;
    }
}

// ---------------- dual-plane aggregation: 16-lane subgroup per node ----------------
__global__ __launch_bounds__(256) void aggc2_k(const unsigned short* __restrict__ xp,
                                               const unsigned short* __restrict__ hp,
                                               const int* __restrict__ start,
                                               const int* __restrict__ srt,
                                               unsigned short* __restrict__ mx,
                                               unsigned short* __restrict__ mh, int n_nodes) {
    const int sgid = (blockIdx.x * blockDim.x + threadIdx.x) >> 4;
    const int nsg = (gridDim.x * blockDim.x) >> 4;
    const int k4 = (threadIdx.x & 15) * 4;
    for (int n = sgid; n < n_nodes; n += nsg) {
        const int s0 = start[n], s1 = start[n + 1];
        f32x4 ax0 = {0.f, 0.f, 0.f, 0.f}, ah0 = {0.f, 0.f, 0.f, 0.f};
        f32x4 ax1 = {0.f, 0.f, 0.f, 0.f}, ah1 = {0.f, 0.f, 0.f, 0.f};
        int e = s0;
        for (; e + 1 < s1; e += 2) {
            const int iA = srt[e], iB = srt[e + 1];
            const u16x4 vxA = *(const u16x4*)(xp + (long)iA * DF + k4);
            const u16x4 vhA = *(const u16x4*)(hp + (long)iA * DF + k4);
            const u16x4 vxB = *(const u16x4*)(xp + (long)iB * DF + k4);
            const u16x4 vhB = *(const u16x4*)(hp + (long)iB * DF + k4);
#pragma unroll
            for (int c = 0; c < 4; ++c) {
                ax0[c] += bf16f((short)vxA[c]);
                ah0[c] += bf16f((short)vhA[c]);
                ax1[c] += bf16f((short)vxB[c]);
                ah1[c] += bf16f((short)vhB[c]);
            }
        }
        if (e < s1) {
            const int iA = srt[e];
            const u16x4 vxA = *(const u16x4*)(xp + (long)iA * DF + k4);
            const u16x4 vhA = *(const u16x4*)(hp + (long)iA * DF + k4);
#pragma unroll
            for (int c = 0; c < 4; ++c) {
                ax0[c] += bf16f((short)vxA[c]);
                ah0[c] += bf16f((short)vhA[c]);
            }
        }
        const float inv = 1.0f / fmaxf((float)(s1 - s0), 1.0f);
        u16x4 ox, oh;
#pragma unroll
        for (int c = 0; c < 4; ++c) {
            ox[c] = (unsigned short)bf16rn((ax0[c] + ax1[c]) * inv);
            oh[c] = (unsigned short)bf16rn((ah0[c] + ah1[c]) * inv);
        }
        *(u16x4*)(mx + (long)n * DF + k4) = ox;
        *(u16x4*)(mh + (long)n * DF + k4) = oh;
    }
}

#define MFMA(a, b, c) __builtin_amdgcn_mfma_f32_16x16x32_bf16((a), (b), (c), 0, 0, 0)

#define LOAD_W(Wl, Wr, col, g, wlh, wll, wrh, wrl)          \
    do {                                                    \
        _Pragma("unroll")                                   \
        for (int q = 0; q < 2; ++q) {                       \
            f32x4 tl0, tl1, tr0, tr1;                       \
            _Pragma("unroll")                               \
            for (int b = 0; b < 4; ++b) {                   \
                int k = 32 * q + 8 * (g) + b;               \
                tl0[b] = (Wl)[k * DF + (col)];              \
                tr0[b] = (Wr)[k * DF + (col)];              \
                tl1[b] = (Wl)[(k + 4) * DF + (col)];        \
                tr1[b] = (Wr)[(k + 4) * DF + (col)];        \
            }                                               \
            split8(tl0, tl1, wlh[q], wll[q]);               \
            split8(tr0, tr1, wrh[q], wrl[q]);               \
        }                                                   \
    } while (0)

// ---------------- dense1 @ NM: hm16 = bf16(relu(mean16 @ Wl + xm16 @ Wr + b)) --------
__global__ __launch_bounds__(256) void dense1nm_k(const unsigned short* __restrict__ mean16,
                                                  const unsigned short* __restrict__ xm16,
                                                  const float* __restrict__ Wl,
                                                  const float* __restrict__ Wr,
                                                  const float* __restrict__ bias,
                                                  unsigned short* __restrict__ h16,
                                                  int n_nodes) {
    const int wglobal = (blockIdx.x * blockDim.x + threadIdx.x) >> 6;
    const int lane = threadIdx.x & 63;
    const int nwaves = (gridDim.x * blockDim.x) >> 6;
    const int ct = wglobal & 3;
    const int col = ct * 16 + (lane & 15);
    const int g = lane >> 4;

    bf16x8 wlh[2], wll[2], wrh[2], wrl[2];
    LOAD_W(Wl, Wr, col, g, wlh, wll, wrh, wrl);
    const float bv = bias[col];

    const int nrt = n_nodes >> 4;
    for (int rt = wglobal >> 2; rt < nrt; rt += nwaves >> 2) {
        const long rowA = (long)rt * 16 + (lane & 15);
        const bf16x8 m0 = *(const bf16x8*)(mean16 + rowA * DF + 8 * g);
        const bf16x8 m1 = *(const bf16x8*)(mean16 + rowA * DF + 32 + 8 * g);
        const bf16x8 x0 = *(const bf16x8*)(xm16 + rowA * DF + 8 * g);
        const bf16x8 x1 = *(const bf16x8*)(xm16 + rowA * DF + 32 + 8 * g);
        f32x4 acc = {0.f, 0.f, 0.f, 0.f};
        acc = MFMA(m0, wlh[0], acc);
        acc = MFMA(m0, wll[0], acc);
        acc = MFMA(m1, wlh[1], acc);
        acc = MFMA(m1, wll[1], acc);
        acc = MFMA(x0, wrh[0], acc);
        acc = MFMA(x0, wrl[0], acc);
        acc = MFMA(x1, wrh[1], acc);
        acc = MFMA(x1, wrl[1], acc);
#pragma unroll
        for (int r = 0; r < 4; ++r)
            h16[((long)rt * 16 + 4 * g + r) * DF + col] =
                (unsigned short)bf16rn(fmaxf(acc[r] + bv, 0.0f));
    }
}

// ---------------- fused customer dense: 2 tiles/iter, parity double-buffered --------
// barriers: 2 per 32 nodes (vs 6); h_c never hits HBM; no atomics.
__global__ __launch_bounds__(256) void densec_k(const unsigned short* __restrict__ meanx,
                                                const unsigned short* __restrict__ meanh,
                                                const unsigned short* __restrict__ xc,
                                                const float* __restrict__ Wl1,
                                                const float* __restrict__ Wr1,
                                                const float* __restrict__ b1,
                                                const float* __restrict__ Wl2,
                                                const float* __restrict__ Wr2,
                                                const float* __restrict__ b2,
                                                const float* __restrict__ Wlin,
                                                const float* __restrict__ blin,
                                                float* __restrict__ out, int n_nodes) {
    __shared__ unsigned short sH[2][2][16][72];   // [parity][tile][row][col]
    __shared__ float sOut[2][2][4][16][2];        // [parity][tile][wave][node][2]
    const int t = threadIdx.x;
    const int lane = t & 63;
    const int wv = t >> 6;
    const int col = wv * 16 + (lane & 15);
    const int g = lane >> 4;

    bf16x8 w1lh[2], w1ll[2], w1rh[2], w1rl[2];
    LOAD_W(Wl1, Wr1, col, g, w1lh, w1ll, w1rh, w1rl);
    bf16x8 w2lh[2], w2ll[2], w2rh[2], w2rl[2];
    LOAD_W(Wl2, Wr2, col, g, w2lh, w2ll, w2rh, w2rl);
    const float bv1 = b1[col];
    const float bv2 = b2[col];
    const float wl0 = Wlin[col * 2 + 0];
    const float wl1s = Wlin[col * 2 + 1];
    const float bl0 = blin[0];
    const float bl1 = blin[1];

    const int npair = n_nodes >> 5;   // 6250
    int par = 0;
    for (int pt = blockIdx.x; pt < npair; pt += gridDim.x, par ^= 1) {
        const long rowA = (long)pt * 32 + (lane & 15);
        const long rowB = rowA + 16;

        // ---- tile A: loads + layer 1 ----
        const bf16x8 mxA0 = *(const bf16x8*)(meanx + rowA * DF + 8 * g);
        const bf16x8 mxA1 = *(const bf16x8*)(meanx + rowA * DF + 32 + 8 * g);
        const bf16x8 mhA0 = *(const bf16x8*)(meanh + rowA * DF + 8 * g);
        const bf16x8 mhA1 = *(const bf16x8*)(meanh + rowA * DF + 32 + 8 * g);
        const bf16x8 xcA0 = *(const bf16x8*)(xc + rowA * DF + 8 * g);
        const bf16x8 xcA1 = *(const bf16x8*)(xc + rowA * DF + 32 + 8 * g);
        f32x4 aA = {0.f, 0.f, 0.f, 0.f};
        aA = MFMA(mxA0, w1lh[0], aA);
        aA = MFMA(mxA0, w1ll[0], aA);
        aA = MFMA(mxA1, w1lh[1], aA);
        aA = MFMA(mxA1, w1ll[1], aA);
        aA = MFMA(xcA0, w1rh[0], aA);
        aA = MFMA(xcA0, w1rl[0], aA);
        aA = MFMA(xcA1, w1rh[1], aA);
        aA = MFMA(xcA1, w1rl[1], aA);
#pragma unroll
        for (int r = 0; r < 4; ++r)
            sH[par][0][4 * g + r][col] = (unsigned short)bf16rn(fmaxf(aA[r] + bv1, 0.0f));

        // ---- tile B: loads + layer 1 (loads hidden under A's MFMAs) ----
        const bf16x8 mxB0 = *(const bf16x8*)(meanx + rowB * DF + 8 * g);
        const bf16x8 mxB1 = *(const bf16x8*)(meanx + rowB * DF + 32 + 8 * g);
        const bf16x8 mhB0 = *(const bf16x8*)(meanh + rowB * DF + 8 * g);
        const bf16x8 mhB1 = *(const bf16x8*)(meanh + rowB * DF + 32 + 8 * g);
        const bf16x8 xcB0 = *(const bf16x8*)(xc + rowB * DF + 8 * g);
        const bf16x8 xcB1 = *(const bf16x8*)(xc + rowB * DF + 32 + 8 * g);
        f32x4 aB = {0.f, 0.f, 0.f, 0.f};
        aB = MFMA(mxB0, w1lh[0], aB);
        aB = MFMA(mxB0, w1ll[0], aB);
        aB = MFMA(mxB1, w1lh[1], aB);
        aB = MFMA(mxB1, w1ll[1], aB);
        aB = MFMA(xcB0, w1rh[0], aB);
        aB = MFMA(xcB0, w1rl[0], aB);
        aB = MFMA(xcB1, w1rh[1], aB);
        aB = MFMA(xcB1, w1rl[1], aB);
#pragma unroll
        for (int r = 0; r < 4; ++r)
            sH[par][1][4 * g + r][col] = (unsigned short)bf16rn(fmaxf(aB[r] + bv1, 0.0f));
        __syncthreads();

        // ---- layer 2 both tiles ----
        const bf16x8 hcA0 = *(const bf16x8*)&sH[par][0][lane & 15][8 * g];
        const bf16x8 hcA1 = *(const bf16x8*)&sH[par][0][lane & 15][32 + 8 * g];
        const bf16x8 hcB0 = *(const bf16x8*)&sH[par][1][lane & 15][8 * g];
        const bf16x8 hcB1 = *(const bf16x8*)&sH[par][1][lane & 15][32 + 8 * g];
        f32x4 a2A = {0.f, 0.f, 0.f, 0.f};
        a2A = MFMA(mhA0, w2lh[0], a2A);
        a2A = MFMA(mhA0, w2ll[0], a2A);
        a2A = MFMA(mhA1, w2lh[1], a2A);
        a2A = MFMA(mhA1, w2ll[1], a2A);
        a2A = MFMA(hcA0, w2rh[0], a2A);
        a2A = MFMA(hcA0, w2rl[0], a2A);
        a2A = MFMA(hcA1, w2rh[1], a2A);
        a2A = MFMA(hcA1, w2rl[1], a2A);
        f32x4 a2B = {0.f, 0.f, 0.f, 0.f};
        a2B = MFMA(mhB0, w2lh[0], a2B);
        a2B = MFMA(mhB0, w2ll[0], a2B);
        a2B = MFMA(mhB1, w2lh[1], a2B);
        a2B = MFMA(mhB1, w2ll[1], a2B);
        a2B = MFMA(hcB0, w2rh[0], a2B);
        a2B = MFMA(hcB0, w2rl[0], a2B);
        a2B = MFMA(hcB1, w2rh[1], a2B);
        a2B = MFMA(hcB1, w2rl[1], a2B);

        // ---- final linear: per-wave partials -> LDS ----
#pragma unroll
        for (int r = 0; r < 4; ++r) {
            const float h2A = a2A[r] + bv2;
            const float h2B = a2B[r] + bv2;
            float pA0 = h2A * wl0, pA1 = h2A * wl1s;
            float pB0 = h2B * wl0, pB1 = h2B * wl1s;
#pragma unroll
            for (int m = 1; m < 16; m <<= 1) {
                pA0 += __shfl_xor(pA0, m);
                pA1 += __shfl_xor(pA1, m);
                pB0 += __shfl_xor(pB0, m);
                pB1 += __shfl_xor(pB1, m);
            }
            if ((lane & 15) == 0) {
                sOut[par][0][wv][4 * g + r][0] = pA0;
                sOut[par][0][wv][4 * g + r][1] = pA1;
                sOut[par][1][wv][4 * g + r][0] = pB0;
                sOut[par][1][wv][4 * g + r][1] = pB1;
            }
        }
        __syncthreads();
        if (t < 32) {
            const int tb = t >> 4;
            const int nn = t & 15;
            const long node = (long)pt * 32 + tb * 16 + nn;
            const float o0 = sOut[par][tb][0][nn][0] + sOut[par][tb][1][nn][0] +
                             sOut[par][tb][2][nn][0] + sOut[par][tb][3][nn][0] + bl0;
            const float o1 = sOut[par][tb][0][nn][1] + sOut[par][tb][1][nn][1] +
                             sOut[par][tb][2][nn][1] + sOut[par][tb][3][nn][1] + bl1;
            float2 o = {o0, o1};
            *(float2*)(out + node * 2) = o;
        }
        // no trailing barrier: next iteration uses the other parity's buffers
    }
}

extern "C" void kernel_launch(void* const* d_in, const int* in_sizes, int n_in,
                              void* d_out, int out_size, void* d_ws, size_t ws_size,
                              hipStream_t stream) {
    const float* x_c = (const float*)d_in[0];
    const float* x_m = (const float*)d_in[1];
    const int* cm_src = (const int*)d_in[2];
    const int* cm_dst = (const int*)d_in[3];
    const int* mc_src = (const int*)d_in[4];
    const int* mc_dst = (const int*)d_in[5];
    const float* Wl1_cm = (const float*)d_in[6];
    const float* Wr1_cm = (const float*)d_in[7];
    const float* b1_cm = (const float*)d_in[8];
    const float* Wl1_mc = (const float*)d_in[9];
    const float* Wr1_mc = (const float*)d_in[10];
    const float* b1_mc = (const float*)d_in[11];
    // layer-2 cm weights (d_in[12..14]) are dead: h2_m is unused in the reference
    const float* Wl2_mc = (const float*)d_in[15];
    const float* Wr2_mc = (const float*)d_in[16];
    const float* b2_mc = (const float*)d_in[17];
    const float* W_lin = (const float*)d_in[18];
    const float* b_lin = (const float*)d_in[19];
    float* out = (float*)d_out;

    // ---- workspace layout (~117 MB) ----
    unsigned short* up = (unsigned short*)d_ws;
    unsigned short* aggm16 = up;                        // NM*64
    unsigned short* hm16 = aggm16 + (long)NM * DF;      // NM*64
    unsigned short* xm16 = hm16 + (long)NM * DF;        // NM*64
    unsigned short* xc16 = xm16 + (long)NM * DF;        // NC*64
    unsigned short* meanx16 = xc16 + (long)NC * DF;     // NC*64
    unsigned short* meanh16 = meanx16 + (long)NC * DF;  // NC*64
    int* ip = (int*)(meanh16 + (long)NC * DF);

    int* startM = ip;                   // NM+1 (written by bp22)
    int* startC = startM + (NM + 1);    // NC+1 (written by bp22)
    int* cstartM = startC + (NC + 1);   // NBM+1
    int* cstartC = cstartM + (NBM + 1); // NBC+1
    int* ccurM = cstartC + (NBC + 1);   // NBM
    int* ccurC = ccurM + NBM;           // NBC
    int* pmM = ccurC + NBC;             // NSB*NBM
    int* pmC = pmM + NSB * NBM;         // NSB*NBC
    int* srt_cm = pmC + NSB * NBC;      // NE
    int* srt_mc = srt_cm + NE;          // NE
    int* bktM = srt_mc + NE;            // NE
    int* bktC = bktM + NE;              // NE

    // coarse hist + presplit (merged, independent work) -> coarse scan -> sort
    prep_k<<<2 * NSB + PSB, 256, 0, stream>>>(cm_dst, mc_dst, pmM, pmC,
                                              x_c, x_m, (u16x4*)xc16, (u16x4*)xm16);
    cscan2_k<<<1, 256, 0, stream>>>(pmM, pmC, cstartM, cstartC, ccurM, ccurC);
    bsort2_k<<<2 * NSB, 256, 0, stream>>>(cm_src, cm_dst, mc_src, mc_dst,
                                          ccurM, ccurC, bktM, bktC);
    bp22_k<<<NBM + NBC, 256, 0, stream>>>(bktM, cstartM, startM, srt_cm,
                                          bktC, cstartC, startC, srt_mc);

    // layer 1 @ merchants: m-mean (bf16) then dense -> hm16
    agg16_k<<<NM / 16, 256, 0, stream>>>(xc16, startM, srt_cm, aggm16, NM);
    dense1nm_k<<<1024, 256, 0, stream>>>(aggm16, xm16, Wl1_cm, Wr1_cm, b1_cm, hm16, NM);

    // customers: fused dual aggregation (x_m-mean + h_m-mean in one edge sweep)
    aggc2_k<<<NC / 16, 256, 0, stream>>>(xm16, hm16, startC, srt_mc,
                                         meanx16, meanh16, NC);

    // customers: fused layer1 + layer2 + final linear (2 tiles/iter)
    densec_k<<<2048, 256, 0, stream>>>(meanx16, meanh16, xc16,
                                       Wl1_mc, Wr1_mc, b1_mc,
                                       Wl2_mc, Wr2_mc, b2_mc,
                                       W_lin, b_lin, out, NC);
}